// Round 2
// baseline (21568.777 us; speedup 1.0000x reference)
//
#include <hip/hip_runtime.h>
#include <math.h>

// Problem dims
static constexpr int Bd = 4, Ld = 16, Cd = 64, Hd = 64, Wd = 64, Fd = 128;
static constexpr int NBLK = 2, NHEAD = 2;
static constexpr int HW = 4096;                 // Hd*Wd
static constexpr float TWO_PI = 6.28318530717958647692f;

// Chunking: process 16 frames (one batch for LRU) at a time.
static constexpr int CHUNK_FRAMES = 16;
static constexpr size_t CHUNK_C64 = (size_t)CHUNK_FRAMES * Cd * HW;   // 4,194,304 floats
static constexpr size_t CHUNK_F128 = (size_t)CHUNK_FRAMES * Fd * HW;  // 8,388,608 floats

__device__ __forceinline__ float gelu_f(float v) {
    return 0.5f * v * (1.f + erff(v * 0.7071067811865476f));
}

// ---------------------------------------------------------------------------
// FFT2 (64x64) of a real frame -> complex. One workgroup per frame (l,c).
// ---------------------------------------------------------------------------
__global__ __launch_bounds__(256) void k_fft2(const float* __restrict__ x,
                                              float2* __restrict__ out) {
    __shared__ float re[64][65];
    __shared__ float re2[64][65];
    __shared__ float im2[64][65];
    __shared__ float twc[64], tws[64];
    int f = blockIdx.x;
    int t = threadIdx.x;
    if (t < 64) {
        float ang = -TWO_PI * (float)t / 64.f;
        twc[t] = __cosf(ang);
        tws[t] = __sinf(ang);
    }
    const float* src = x + (size_t)f * HW;
    for (int j = t; j < HW; j += 256) re[j >> 6][j & 63] = src[j];
    __syncthreads();

    int k = t & 63;
    float cb, sb;
    __sincosf(-TWO_PI * (float)k / 64.f, &sb, &cb);   // e^{-2pi i k/64}
    for (int ch = 0; ch < 16; ++ch) {
        int r = (t >> 6) + 4 * ch;
        float ar = 0.f, ai = 0.f, c = 1.f, s = 0.f;
        for (int n = 0; n < 64; ++n) {
            float xr = re[r][n];
            ar += xr * c;
            ai += xr * s;
            float c2 = c * cb - s * sb;
            s = c * sb + s * cb;
            c = c2;
        }
        re2[r][k] = ar;
        im2[r][k] = ai;
    }
    __syncthreads();

    int w = t & 63;
    float2* dst = out + (size_t)f * HW;
    for (int ch = 0; ch < 16; ++ch) {
        int h = (t >> 6) + 4 * ch;
        float ar = 0.f, ai = 0.f;
        for (int u = 0; u < 64; ++u) {
            int idx = (h * u) & 63;
            float c = twc[idx], s = tws[idx];
            float xr = re2[u][w], xi = im2[u][w];
            ar += xr * c - xi * s;
            ai += xr * s + xi * c;
        }
        dst[(size_t)h * 64 + w] = make_float2(ar, ai);
    }
}

// ---------------------------------------------------------------------------
// Complex channel mix in frequency domain (in-place safe: full input tile is
// staged in LDS before any write; blocks touch disjoint (frame,row) regions).
//   out[o,p] = (sum_c in[c,p] * W[o,c] + bias) * gamma   (bias/gamma optional)
// Weights pre-transposed in global: wt[c*64+o]. One block per (frame, h-row).
// ---------------------------------------------------------------------------
__global__ __launch_bounds__(256) void k_cmix(const float2* __restrict__ in,
                                              float2* __restrict__ out,
                                              const float* __restrict__ wtr_g,
                                              const float* __restrict__ wti_g,
                                              const float* __restrict__ br_g,
                                              const float* __restrict__ bi_g,
                                              const float* __restrict__ gl_g,
                                              int use_gamma) {
    __shared__ float inr[64][64], ini[64][64], wtr[64][64], wti[64][64];
    int blk = blockIdx.x;
    int fr = blk >> 6;     // local frame (l)
    int row = blk & 63;    // freq-h row
    int t = threadIdx.x;
    const float2* src = in + (size_t)fr * Cd * HW + row * 64;
    for (int j = t; j < 4096; j += 256) {
        int c = j >> 6, p = j & 63;
        float2 v = src[(size_t)c * HW + p];
        inr[c][p] = v.x;
        ini[c][p] = v.y;
        wtr[c][p] = wtr_g[j];   // already [c][o]
        wti[c][p] = wti_g[j];
    }
    __syncthreads();
    int pid = t & 15, oid = t >> 4;
    int p0 = pid * 4, o0 = oid * 4;
    float ar[4][4] = {}, ai[4][4] = {};
    for (int c = 0; c < 64; ++c) {
        float4 xr4 = *(const float4*)&inr[c][p0];
        float4 xi4 = *(const float4*)&ini[c][p0];
        float4 wr4 = *(const float4*)&wtr[c][o0];
        float4 wi4 = *(const float4*)&wti[c][o0];
        float xr[4] = {xr4.x, xr4.y, xr4.z, xr4.w};
        float xi[4] = {xi4.x, xi4.y, xi4.z, xi4.w};
        float wr[4] = {wr4.x, wr4.y, wr4.z, wr4.w};
        float wi[4] = {wi4.x, wi4.y, wi4.z, wi4.w};
#pragma unroll
        for (int oo = 0; oo < 4; ++oo)
#pragma unroll
            for (int pp = 0; pp < 4; ++pp) {
                ar[oo][pp] += xr[pp] * wr[oo] - xi[pp] * wi[oo];
                ai[oo][pp] += xr[pp] * wi[oo] + xi[pp] * wr[oo];
            }
    }
#pragma unroll
    for (int oo = 0; oo < 4; ++oo) {
        int o = o0 + oo;
        float br = 0.f, bi = 0.f, g = 1.f;
        if (use_gamma) {
            br = br_g[o];
            bi = bi_g[o];
            g = __expf(gl_g[o * 64 + row]);
        }
        float v0r = (ar[oo][0] + br) * g, v0i = (ai[oo][0] + bi) * g;
        float v1r = (ar[oo][1] + br) * g, v1i = (ai[oo][1] + bi) * g;
        float v2r = (ar[oo][2] + br) * g, v2i = (ai[oo][2] + bi) * g;
        float v3r = (ar[oo][3] + br) * g, v3i = (ai[oo][3] + bi) * g;
        float2* dstrow = out + ((size_t)fr * Cd + o) * HW + row * 64 + p0;
        *(float4*)(dstrow) = make_float4(v0r, v0i, v1r, v1i);
        *(float4*)(dstrow + 2) = make_float4(v2r, v2i, v3r, v3i);
    }
}

// ---------------------------------------------------------------------------
// Linear recurrence over L (one batch chunk): h[t] = lamb(c,h)*h[t-1] + h[t].
// In-place; hbuf layout [L][C][HW]. 1024 blocks x 256 threads = C*HW threads.
// ---------------------------------------------------------------------------
__global__ __launch_bounds__(256) void k_scan(float2* __restrict__ hbuf,
                                              const float* __restrict__ pl) {
    int g = blockIdx.x * 256 + threadIdx.x;   // over (c,h,w) = 2^18
    int c = g >> 12;
    int hw = g & 4095;
    int h = hw >> 6;
    float nu = expf(pl[c * 64 + h]);
    float th = expf(pl[4096 + c * 64 + h]);
    float mag = expf(-nu);
    float sth, cth;
    sincosf(th, &sth, &cth);
    float lr = mag * cth, li = mag * sth;
    size_t base = (size_t)c * HW + hw;
    float2 acc = hbuf[base];
    for (int tt = 1; tt < Ld; ++tt) {
        size_t idx = base + (size_t)tt * Cd * HW;
        float2 v = hbuf[idx];
        float nr = lr * acc.x - li * acc.y + v.x;
        float ni = lr * acc.y + li * acc.x + v.y;
        acc = make_float2(nr, ni);
        hbuf[idx] = acc;
    }
}

// ---------------------------------------------------------------------------
// IFFT2 (complex->real) + Re(Cb) + LayerNorm(H,W) + residual. One wg per frame.
// ---------------------------------------------------------------------------
__global__ __launch_bounds__(256) void k_ifft_ln(const float2* __restrict__ Xf,
                                                 const float* __restrict__ cbr,
                                                 const float* __restrict__ lnw,
                                                 const float* __restrict__ lnb,
                                                 const float* __restrict__ xprev,
                                                 float* __restrict__ xout) {
    __shared__ float re[64][65], im[64][65], re2[64][65], im2[64][65];
    __shared__ float twc[64], tws[64];
    __shared__ float red[8];
    int fidx = blockIdx.x;      // local (l,c)
    int o = fidx & 63;          // channel
    int t = threadIdx.x;
    if (t < 64) {
        float ang = TWO_PI * (float)t / 64.f;
        twc[t] = __cosf(ang);
        tws[t] = __sinf(ang);
    }
    const float2* src = Xf + (size_t)fidx * HW;
    for (int j = t; j < HW; j += 256) {
        float2 v = src[j];
        re[j >> 6][j & 63] = v.x;
        im[j >> 6][j & 63] = v.y;
    }
    __syncthreads();

    int k = t & 63;
    float cb, sb;
    __sincosf(TWO_PI * (float)k / 64.f, &sb, &cb);    // e^{+2pi i k/64}
    for (int ch = 0; ch < 16; ++ch) {
        int r = (t >> 6) + 4 * ch;
        float ar = 0.f, ai = 0.f, c = 1.f, s = 0.f;
        for (int n = 0; n < 64; ++n) {
            float xr = re[r][n], xi = im[r][n];
            ar += xr * c - xi * s;
            ai += xr * s + xi * c;
            float c2 = c * cb - s * sb;
            s = c * sb + s * cb;
            c = c2;
        }
        re2[r][k] = ar;
        im2[r][k] = ai;
    }
    __syncthreads();

    int w = t & 63;
    float bias = cbr[o];
    float vals[16];
    float sum = 0.f, sumsq = 0.f;
#pragma unroll
    for (int ch = 0; ch < 16; ++ch) {
        int hh = (t >> 6) + 4 * ch;
        float ar = 0.f;
        for (int u = 0; u < 64; ++u) {
            int idx = (hh * u) & 63;
            ar += re2[u][w] * twc[idx] - im2[u][w] * tws[idx];
        }
        ar = ar * (1.f / 4096.f) + bias;
        vals[ch] = ar;
        sum += ar;
        sumsq += ar * ar;
    }
    for (int off = 32; off; off >>= 1) {
        sum += __shfl_down(sum, off);
        sumsq += __shfl_down(sumsq, off);
    }
    int wid = t >> 6;
    if ((t & 63) == 0) { red[wid] = sum; red[4 + wid] = sumsq; }
    __syncthreads();
    sum = red[0] + red[1] + red[2] + red[3];
    sumsq = red[4] + red[5] + red[6] + red[7];
    float m = sum * (1.f / 4096.f);
    float var = sumsq * (1.f / 4096.f) - m * m;
    float rs = rsqrtf(var + 1e-5f);
    const float* xp = xprev + (size_t)fidx * HW;
    float* xo = xout + (size_t)fidx * HW;
#pragma unroll
    for (int ch = 0; ch < 16; ++ch) {
        int hh = (t >> 6) + 4 * ch;
        int p = hh * 64 + w;
        xo[p] = (vals[ch] - m) * rs * lnw[p] + lnb[p] + xp[p];
    }
}

// ---------------------------------------------------------------------------
// Weight transpose: w[Fo][K] -> wt[K][Fo]
// ---------------------------------------------------------------------------
__global__ void k_transpose_w(const float* __restrict__ w, float* __restrict__ wt,
                              int Fo, int K) {
    int idx = blockIdx.x * 256 + threadIdx.x;
    if (idx < Fo * K) {
        int f = idx / K, kk = idx - f * K;
        wt[(size_t)kk * Fo + f] = w[idx];
    }
}

// ---------------------------------------------------------------------------
// 7x7 conv (Cin=64 -> F=128), SAME pad, + bias + GELU.
// wt layout: [c][tap][f]. Block: (n local, y, fg half of F). Grid 2048/chunk.
// ---------------------------------------------------------------------------
__global__ __launch_bounds__(256) void k_conv7(const float* __restrict__ in,
                                               const float* __restrict__ wt,
                                               const float* __restrict__ bias,
                                               float* __restrict__ out) {
    __shared__ float inL[4][7][72];
    __shared__ float wL[4][49][64];
    int blk = blockIdx.x;
    int fg = blk & 1, y = (blk >> 1) & 63, n = blk >> 7;
    int t = threadIdx.x;
    int x = t & 63, fq = t >> 6;
    float acc[16];
#pragma unroll
    for (int i2 = 0; i2 < 16; ++i2) acc[i2] = 0.f;
    const float* inf = in + (size_t)n * Cd * HW;
    for (int cc = 0; cc < Cd; cc += 4) {
        for (int j = t; j < 4 * 7 * 70; j += 256) {
            int c = j / 490;
            int r2 = j - c * 490;
            int rr = r2 / 70;
            int col = r2 - rr * 70;
            int gy = y + rr - 3, gx = col - 3;
            float v = 0.f;
            if ((unsigned)gy < 64u && (unsigned)gx < 64u)
                v = inf[(size_t)(cc + c) * HW + gy * 64 + gx];
            inL[c][rr][col] = v;
        }
        for (int j = t; j < 4 * 49 * 64; j += 256) {
            int f = j & 63;
            int ct = j >> 6;
            int c = ct / 49;
            int tap = ct - c * 49;
            wL[c][tap][f] = wt[((size_t)(cc + c) * 49 + tap) * Fd + fg * 64 + f];
        }
        __syncthreads();
        for (int c = 0; c < 4; ++c) {
            for (int ky = 0; ky < 7; ++ky) {
                float iv[7];
#pragma unroll
                for (int q = 0; q < 7; ++q) iv[q] = inL[c][ky][x + q];
#pragma unroll
                for (int kx = 0; kx < 7; ++kx) {
                    const float* wp = &wL[c][ky * 7 + kx][fq * 16];
                    float wv[16];
                    *(float4*)&wv[0] = *(const float4*)(wp);
                    *(float4*)&wv[4] = *(const float4*)(wp + 4);
                    *(float4*)&wv[8] = *(const float4*)(wp + 8);
                    *(float4*)&wv[12] = *(const float4*)(wp + 12);
                    float v = iv[kx];
#pragma unroll
                    for (int ff = 0; ff < 16; ++ff) acc[ff] += v * wv[ff];
                }
            }
        }
        __syncthreads();
    }
    int fbase = fg * 64 + fq * 16;
    float* of = out + ((size_t)n * Fd + fbase) * HW + y * 64 + x;
#pragma unroll
    for (int ff = 0; ff < 16; ++ff) {
        float v = acc[ff] + bias[fbase + ff];
        of[(size_t)ff * HW] = gelu_f(v);
    }
}

// ---------------------------------------------------------------------------
// 3x3 conv (F=128 -> F=128), SAME pad, + bias + GELU. wt: [c][tap][f].
// ---------------------------------------------------------------------------
__global__ __launch_bounds__(256) void k_conv3(const float* __restrict__ in,
                                               const float* __restrict__ wt,
                                               const float* __restrict__ bias,
                                               float* __restrict__ out) {
    __shared__ float inL[8][3][72];
    __shared__ float wL[8][9][64];
    int blk = blockIdx.x;
    int fg = blk & 1, y = (blk >> 1) & 63, n = blk >> 7;
    int t = threadIdx.x;
    int x = t & 63, fq = t >> 6;
    float acc[16];
#pragma unroll
    for (int i2 = 0; i2 < 16; ++i2) acc[i2] = 0.f;
    const float* inf = in + (size_t)n * Fd * HW;
    for (int cc = 0; cc < Fd; cc += 8) {
        for (int j = t; j < 8 * 3 * 66; j += 256) {
            int c = j / 198;
            int r2 = j - c * 198;
            int rr = r2 / 66;
            int col = r2 - rr * 66;
            int gy = y + rr - 1, gx = col - 1;
            float v = 0.f;
            if ((unsigned)gy < 64u && (unsigned)gx < 64u)
                v = inf[(size_t)(cc + c) * HW + gy * 64 + gx];
            inL[c][rr][col] = v;
        }
        for (int j = t; j < 8 * 9 * 64; j += 256) {
            int f = j & 63;
            int ct = j >> 6;
            int c = ct / 9;
            int tap = ct - c * 9;
            wL[c][tap][f] = wt[((size_t)(cc + c) * 9 + tap) * Fd + fg * 64 + f];
        }
        __syncthreads();
        for (int c = 0; c < 8; ++c) {
#pragma unroll
            for (int ky = 0; ky < 3; ++ky) {
                float iv[3];
                iv[0] = inL[c][ky][x];
                iv[1] = inL[c][ky][x + 1];
                iv[2] = inL[c][ky][x + 2];
#pragma unroll
                for (int kx = 0; kx < 3; ++kx) {
                    const float* wp = &wL[c][ky * 3 + kx][fq * 16];
                    float wv[16];
                    *(float4*)&wv[0] = *(const float4*)(wp);
                    *(float4*)&wv[4] = *(const float4*)(wp + 4);
                    *(float4*)&wv[8] = *(const float4*)(wp + 8);
                    *(float4*)&wv[12] = *(const float4*)(wp + 12);
                    float v = iv[kx];
#pragma unroll
                    for (int ff = 0; ff < 16; ++ff) acc[ff] += v * wv[ff];
                }
            }
        }
        __syncthreads();
    }
    int fbase = fg * 64 + fq * 16;
    float* of = out + ((size_t)n * Fd + fbase) * HW + y * 64 + x;
#pragma unroll
    for (int ff = 0; ff < 16; ++ff) {
        float v = acc[ff] + bias[fbase + ff];
        of[(size_t)ff * HW] = gelu_f(v);
    }
}

// ---------------------------------------------------------------------------
// 1x1 conv (channel matmul), Fin=128 fixed, FOUT outputs per block-row.
// One block per (n, row) computes ALL FOUT outputs -> in-place safe when
// FOUT==Fin (full input tile staged in LDS before writes; disjoint regions).
// wt pre-transposed: [f][o].
// ---------------------------------------------------------------------------
template <int FOUT>
__global__ __launch_bounds__(256) void k_1x1_ip(const float* __restrict__ in,
                                                const float* __restrict__ wt,
                                                const float* __restrict__ bias,
                                                float* __restrict__ out,
                                                int do_gelu) {
    __shared__ float inL[128][64];
    __shared__ float wLt[128][FOUT];
    int blk = blockIdx.x;
    int row = blk & 63;
    int n = blk >> 6;
    int t = threadIdx.x;
    const float* src = in + (size_t)n * 128 * HW + row * 64;
    for (int j = t; j < 128 * 64; j += 256) {
        int f = j >> 6, p = j & 63;
        inL[f][p] = src[(size_t)f * HW + p];
    }
    for (int j = t; j < 128 * FOUT; j += 256) {
        int f = j / FOUT, o = j - f * FOUT;
        wLt[f][o] = wt[(size_t)f * FOUT + o];
    }
    __syncthreads();
    constexpr int OT = FOUT / 16;          // outputs per thread (o-dim)
    int pid = t & 15, oid = t >> 4;
    int p0 = pid * 4, o0 = oid * OT;
    float acc[OT][4];
#pragma unroll
    for (int oo = 0; oo < OT; ++oo)
#pragma unroll
        for (int pp = 0; pp < 4; ++pp) acc[oo][pp] = 0.f;
    for (int f = 0; f < 128; ++f) {
        float4 a4 = *(const float4*)&inL[f][p0];
        float av[4] = {a4.x, a4.y, a4.z, a4.w};
#pragma unroll
        for (int og = 0; og < OT / 4; ++og) {
            float4 w4 = *(const float4*)&wLt[f][o0 + og * 4];
            float wv[4] = {w4.x, w4.y, w4.z, w4.w};
#pragma unroll
            for (int q = 0; q < 4; ++q)
#pragma unroll
                for (int pp = 0; pp < 4; ++pp)
                    acc[og * 4 + q][pp] += av[pp] * wv[q];
        }
    }
#pragma unroll
    for (int oo = 0; oo < OT; ++oo) {
        int o = o0 + oo;
        float b = bias[o];
        float4 v = make_float4(acc[oo][0] + b, acc[oo][1] + b, acc[oo][2] + b,
                               acc[oo][3] + b);
        if (do_gelu) {
            v.x = gelu_f(v.x);
            v.y = gelu_f(v.y);
            v.z = gelu_f(v.z);
            v.w = gelu_f(v.w);
        }
        *(float4*)(out + ((size_t)n * FOUT + o) * HW + row * 64 + p0) = v;
    }
}

// ---------------------------------------------------------------------------
// LayerNorm(H,W) of t_in frame + residual-accumulate into dst:
//   dst += LN(t_in)*w + b.  One workgroup per (n, ch) frame.
// ---------------------------------------------------------------------------
__global__ __launch_bounds__(256) void k_ln_res(const float* __restrict__ t_in,
                                                const float* __restrict__ w,
                                                const float* __restrict__ b,
                                                float* __restrict__ dst) {
    __shared__ float red[8];
    int fr = blockIdx.x;
    const float* src = t_in + (size_t)fr * HW;
    float* d = dst + (size_t)fr * HW;
    int t = threadIdx.x;
    float vals[16];
    float s = 0.f, sq = 0.f;
#pragma unroll
    for (int j = 0; j < 16; ++j) {
        float v = src[t + 256 * j];
        vals[j] = v;
        s += v;
        sq += v * v;
    }
    for (int off = 32; off; off >>= 1) {
        s += __shfl_down(s, off);
        sq += __shfl_down(sq, off);
    }
    int wid = t >> 6;
    if ((t & 63) == 0) { red[wid] = s; red[4 + wid] = sq; }
    __syncthreads();
    s = red[0] + red[1] + red[2] + red[3];
    sq = red[4] + red[5] + red[6] + red[7];
    float m = s * (1.f / 4096.f);
    float var = sq * (1.f / 4096.f) - m * m;
    float rs = rsqrtf(var + 1e-5f);
#pragma unroll
    for (int j = 0; j < 16; ++j) {
        int p = t + 256 * j;
        d[p] += (vals[j] - m) * rs * w[p] + b[p];
    }
}

// ---------------------------------------------------------------------------
extern "C" void kernel_launch(void* const* d_in, const int* in_sizes, int n_in,
                              void* d_out, int out_size, void* d_ws, size_t ws_size,
                              hipStream_t stream) {
    (void)in_sizes; (void)n_in; (void)out_size; (void)ws_size;
    const float* x_in  = (const float*)d_in[0];
    const float* pl    = (const float*)d_in[1];
    const float* pBw_r = (const float*)d_in[2];
    const float* pBw_i = (const float*)d_in[3];
    const float* pBb_r = (const float*)d_in[4];
    const float* pBb_i = (const float*)d_in[5];
    const float* pCw_r = (const float*)d_in[6];
    const float* pCw_i = (const float*)d_in[7];
    const float* pCb_r = (const float*)d_in[8];
    const float* pCb_i = (const float*)d_in[9];
    const float* lruw  = (const float*)d_in[10];
    const float* lrub  = (const float*)d_in[11];
    const float* cinw  = (const float*)d_in[12];
    const float* cinb  = (const float*)d_in[13];
    const float* h3w   = (const float*)d_in[14];
    const float* h3b   = (const float*)d_in[15];
    const float* h1w   = (const float*)d_in[16];
    const float* h1b   = (const float*)d_in[17];
    const float* hlnw  = (const float*)d_in[18];
    const float* hlnb  = (const float*)d_in[19];
    const float* coutw = (const float*)d_in[20];
    const float* coutb = (const float*)d_in[21];
    const float* flnw  = (const float*)d_in[22];
    const float* flnb  = (const float*)d_in[23];
    float* out = (float*)d_out;

    // Workspace layout (floats), total ~70 MB:
    //   bufA: 8,388,608 (complex LRU chunk, also FFN y_ chunk)
    //   bufB: 8,388,608 (conv3 / cout outputs)
    //   wtb : 737,280   (all transposed weights for current block i)
    float* bufA = (float*)d_ws;
    float* bufB = bufA + CHUNK_F128;
    float* wtb  = bufB + CHUNK_F128;
    // wtb offsets (floats)
    const size_t WT_CIN = 0;          // 128*3136 = 401,408
    const size_t WT_H3_0 = 401408;    // 147,456 each
    const size_t WT_H3_1 = 548864;
    const size_t WT_H1_0 = 696320;    // 16,384 each
    const size_t WT_H1_1 = 712704;
    const size_t WT_COUT = 729088;    // 8,192

    for (int i = 0; i < NBLK; ++i) {
        const float* xsrc = (i == 0) ? x_in : out;

        // ---------------- ConvLRULayer (chunked by batch) ----------------
        k_transpose_w<<<16, 256, 0, stream>>>(pBw_r + (size_t)i * 4096, wtb, 64, 64);
        k_transpose_w<<<16, 256, 0, stream>>>(pBw_i + (size_t)i * 4096, wtb + 4096, 64, 64);
        k_transpose_w<<<16, 256, 0, stream>>>(pCw_r + (size_t)i * 4096, wtb + 8192, 64, 64);
        k_transpose_w<<<16, 256, 0, stream>>>(pCw_i + (size_t)i * 4096, wtb + 12288, 64, 64);
        for (int bc = 0; bc < Bd; ++bc) {
            size_t boff = (size_t)bc * CHUNK_C64;
            k_fft2<<<1024, 256, 0, stream>>>(xsrc + boff, (float2*)bufA);
            k_cmix<<<1024, 256, 0, stream>>>((const float2*)bufA, (float2*)bufA,
                                             wtb, wtb + 4096,
                                             pBb_r + (size_t)i * 64,
                                             pBb_i + (size_t)i * 64,
                                             pl + (size_t)i * 12288 + 8192, 1);
            k_scan<<<1024, 256, 0, stream>>>((float2*)bufA, pl + (size_t)i * 12288);
            k_cmix<<<1024, 256, 0, stream>>>((const float2*)bufA, (float2*)bufA,
                                             wtb + 8192, wtb + 12288,
                                             nullptr, nullptr, nullptr, 0);
            k_ifft_ln<<<1024, 256, 0, stream>>>((const float2*)bufA,
                                                pCb_r + (size_t)i * 64,
                                                lruw + (size_t)i * 4096,
                                                lrub + (size_t)i * 4096,
                                                xsrc + boff, out + boff);
        }

        // ---------------- FeedForward (chunked by 16 frames) ----------------
        k_transpose_w<<<(128 * 3136 + 255) / 256, 256, 0, stream>>>(
            cinw + (size_t)i * 128 * 3136, wtb + WT_CIN, 128, 3136);
        k_transpose_w<<<(128 * 1152 + 255) / 256, 256, 0, stream>>>(
            h3w + (size_t)(i * 2 + 0) * 147456, wtb + WT_H3_0, 128, 1152);
        k_transpose_w<<<(128 * 1152 + 255) / 256, 256, 0, stream>>>(
            h3w + (size_t)(i * 2 + 1) * 147456, wtb + WT_H3_1, 128, 1152);
        k_transpose_w<<<64, 256, 0, stream>>>(h1w + (size_t)(i * 2 + 0) * 16384,
                                              wtb + WT_H1_0, 128, 128);
        k_transpose_w<<<64, 256, 0, stream>>>(h1w + (size_t)(i * 2 + 1) * 16384,
                                              wtb + WT_H1_1, 128, 128);
        k_transpose_w<<<32, 256, 0, stream>>>(coutw + (size_t)i * 8192,
                                              wtb + WT_COUT, 64, 128);
        const size_t wt_h3[2] = {WT_H3_0, WT_H3_1};
        const size_t wt_h1[2] = {WT_H1_0, WT_H1_1};

        for (int bc = 0; bc < Bd; ++bc) {
            size_t boff = (size_t)bc * CHUNK_C64;
            // y_ = gelu(conv7(x)) -> bufA
            k_conv7<<<2048, 256, 0, stream>>>(out + boff, wtb + WT_CIN,
                                              cinb + (size_t)i * 128, bufA);
            for (int j = 0; j < NHEAD; ++j) {
                // t = gelu(conv3(y_)) -> bufB
                k_conv3<<<2048, 256, 0, stream>>>(bufA, wtb + wt_h3[j],
                                                  h3b + (size_t)(i * 2 + j) * 128,
                                                  bufB);
                // t = gelu(1x1(t)) in-place in bufB
                k_1x1_ip<128><<<1024, 256, 0, stream>>>(
                    bufB, wtb + wt_h1[j], h1b + (size_t)(i * 2 + j) * 128, bufB, 1);
                // y_ += LN(t)
                k_ln_res<<<2048, 256, 0, stream>>>(
                    bufB, hlnw + (size_t)(i * 2 + j) * 4096,
                    hlnb + (size_t)(i * 2 + j) * 4096, bufA);
            }
            // cout 1x1 (128->64) -> bufB
            k_1x1_ip<64><<<1024, 256, 0, stream>>>(
                bufA, wtb + WT_COUT, coutb + (size_t)i * 64, bufB, 0);
            // x += LN(cout)
            k_ln_res<<<1024, 256, 0, stream>>>(bufB, flnw + (size_t)i * 4096,
                                               flnb + (size_t)i * 4096, out + boff);
        }
    }
}

// Round 3
// 7680.468 us; speedup vs baseline: 2.8083x; 2.8083x over previous
//
#include <hip/hip_runtime.h>
#include <math.h>

// Problem dims
static constexpr int Bd = 4, Ld = 16, Cd = 64, Hd = 64, Wd = 64, Fd = 128;
static constexpr int NBLK = 2, NHEAD = 2;
static constexpr int HW = 4096;                 // Hd*Wd
static constexpr float TWO_PI = 6.28318530717958647692f;

// LRU chunk: 16 frames (one batch). FFN sub-chunk: 8 frames.
static constexpr int SCF = 8;
static constexpr size_t CHUNK_C64 = (size_t)16 * Cd * HW;   // floats per LRU chunk

typedef __attribute__((ext_vector_type(8))) short bf16x8;
typedef __attribute__((ext_vector_type(4))) float f32x4;

__device__ __forceinline__ float gelu_f(float v) {
    return 0.5f * v * (1.f + erff(v * 0.7071067811865476f));
}

__device__ __forceinline__ unsigned short bf16c(float f) {
    unsigned int u = __float_as_uint(f);
    unsigned int r = (u + 0x7fffu + ((u >> 16) & 1u)) >> 16;
    return (unsigned short)r;
}

// async global->LDS, 16 bytes per lane. lds dest = wave-uniform base + lane*16.
__device__ __forceinline__ void gl2lds16(const void* g, void* l) {
    __builtin_amdgcn_global_load_lds(
        (const __attribute__((address_space(1))) void*)g,
        (__attribute__((address_space(3))) void*)l, 16, 0, 0);
}

// ===========================================================================
// LRU path kernels (unchanged from round 2)
// ===========================================================================
__global__ __launch_bounds__(256) void k_fft2(const float* __restrict__ x,
                                              float2* __restrict__ out) {
    __shared__ float re[64][65];
    __shared__ float re2[64][65];
    __shared__ float im2[64][65];
    __shared__ float twc[64], tws[64];
    int f = blockIdx.x;
    int t = threadIdx.x;
    if (t < 64) {
        float ang = -TWO_PI * (float)t / 64.f;
        twc[t] = __cosf(ang);
        tws[t] = __sinf(ang);
    }
    const float* src = x + (size_t)f * HW;
    for (int j = t; j < HW; j += 256) re[j >> 6][j & 63] = src[j];
    __syncthreads();

    int k = t & 63;
    float cb, sb;
    __sincosf(-TWO_PI * (float)k / 64.f, &sb, &cb);
    for (int ch = 0; ch < 16; ++ch) {
        int r = (t >> 6) + 4 * ch;
        float ar = 0.f, ai = 0.f, c = 1.f, s = 0.f;
        for (int n = 0; n < 64; ++n) {
            float xr = re[r][n];
            ar += xr * c;
            ai += xr * s;
            float c2 = c * cb - s * sb;
            s = c * sb + s * cb;
            c = c2;
        }
        re2[r][k] = ar;
        im2[r][k] = ai;
    }
    __syncthreads();

    int w = t & 63;
    float2* dst = out + (size_t)f * HW;
    for (int ch = 0; ch < 16; ++ch) {
        int h = (t >> 6) + 4 * ch;
        float ar = 0.f, ai = 0.f;
        for (int u = 0; u < 64; ++u) {
            int idx = (h * u) & 63;
            float c = twc[idx], s = tws[idx];
            float xr = re2[u][w], xi = im2[u][w];
            ar += xr * c - xi * s;
            ai += xr * s + xi * c;
        }
        dst[(size_t)h * 64 + w] = make_float2(ar, ai);
    }
}

__global__ __launch_bounds__(256) void k_cmix(const float2* __restrict__ in,
                                              float2* __restrict__ out,
                                              const float* __restrict__ wtr_g,
                                              const float* __restrict__ wti_g,
                                              const float* __restrict__ br_g,
                                              const float* __restrict__ bi_g,
                                              const float* __restrict__ gl_g,
                                              int use_gamma) {
    __shared__ float inr[64][64], ini[64][64], wtr[64][64], wti[64][64];
    int blk = blockIdx.x;
    int fr = blk >> 6;
    int row = blk & 63;
    int t = threadIdx.x;
    const float2* src = in + (size_t)fr * Cd * HW + row * 64;
    for (int j = t; j < 4096; j += 256) {
        int c = j >> 6, p = j & 63;
        float2 v = src[(size_t)c * HW + p];
        inr[c][p] = v.x;
        ini[c][p] = v.y;
        wtr[c][p] = wtr_g[j];
        wti[c][p] = wti_g[j];
    }
    __syncthreads();
    int pid = t & 15, oid = t >> 4;
    int p0 = pid * 4, o0 = oid * 4;
    float ar[4][4] = {}, ai[4][4] = {};
    for (int c = 0; c < 64; ++c) {
        float4 xr4 = *(const float4*)&inr[c][p0];
        float4 xi4 = *(const float4*)&ini[c][p0];
        float4 wr4 = *(const float4*)&wtr[c][o0];
        float4 wi4 = *(const float4*)&wti[c][o0];
        float xr[4] = {xr4.x, xr4.y, xr4.z, xr4.w};
        float xi[4] = {xi4.x, xi4.y, xi4.z, xi4.w};
        float wr[4] = {wr4.x, wr4.y, wr4.z, wr4.w};
        float wi[4] = {wi4.x, wi4.y, wi4.z, wi4.w};
#pragma unroll
        for (int oo = 0; oo < 4; ++oo)
#pragma unroll
            for (int pp = 0; pp < 4; ++pp) {
                ar[oo][pp] += xr[pp] * wr[oo] - xi[pp] * wi[oo];
                ai[oo][pp] += xr[pp] * wi[oo] + xi[pp] * wr[oo];
            }
    }
#pragma unroll
    for (int oo = 0; oo < 4; ++oo) {
        int o = o0 + oo;
        float br = 0.f, bi = 0.f, g = 1.f;
        if (use_gamma) {
            br = br_g[o];
            bi = bi_g[o];
            g = __expf(gl_g[o * 64 + row]);
        }
        float v0r = (ar[oo][0] + br) * g, v0i = (ai[oo][0] + bi) * g;
        float v1r = (ar[oo][1] + br) * g, v1i = (ai[oo][1] + bi) * g;
        float v2r = (ar[oo][2] + br) * g, v2i = (ai[oo][2] + bi) * g;
        float v3r = (ar[oo][3] + br) * g, v3i = (ai[oo][3] + bi) * g;
        float2* dstrow = out + ((size_t)fr * Cd + o) * HW + row * 64 + p0;
        *(float4*)(dstrow) = make_float4(v0r, v0i, v1r, v1i);
        *(float4*)(dstrow + 2) = make_float4(v2r, v2i, v3r, v3i);
    }
}

__global__ __launch_bounds__(256) void k_scan(float2* __restrict__ hbuf,
                                              const float* __restrict__ pl) {
    int g = blockIdx.x * 256 + threadIdx.x;
    int c = g >> 12;
    int hw = g & 4095;
    int h = hw >> 6;
    float nu = expf(pl[c * 64 + h]);
    float th = expf(pl[4096 + c * 64 + h]);
    float mag = expf(-nu);
    float sth, cth;
    sincosf(th, &sth, &cth);
    float lr = mag * cth, li = mag * sth;
    size_t base = (size_t)c * HW + hw;
    float2 acc = hbuf[base];
    for (int tt = 1; tt < Ld; ++tt) {
        size_t idx = base + (size_t)tt * Cd * HW;
        float2 v = hbuf[idx];
        float nr = lr * acc.x - li * acc.y + v.x;
        float ni = lr * acc.y + li * acc.x + v.y;
        acc = make_float2(nr, ni);
        hbuf[idx] = acc;
    }
}

__global__ __launch_bounds__(256) void k_ifft_ln(const float2* __restrict__ Xf,
                                                 const float* __restrict__ cbr,
                                                 const float* __restrict__ lnw,
                                                 const float* __restrict__ lnb,
                                                 const float* __restrict__ xprev,
                                                 float* __restrict__ xout) {
    __shared__ float re[64][65], im[64][65], re2[64][65], im2[64][65];
    __shared__ float twc[64], tws[64];
    __shared__ float red[8];
    int fidx = blockIdx.x;
    int o = fidx & 63;
    int t = threadIdx.x;
    if (t < 64) {
        float ang = TWO_PI * (float)t / 64.f;
        twc[t] = __cosf(ang);
        tws[t] = __sinf(ang);
    }
    const float2* src = Xf + (size_t)fidx * HW;
    for (int j = t; j < HW; j += 256) {
        float2 v = src[j];
        re[j >> 6][j & 63] = v.x;
        im[j >> 6][j & 63] = v.y;
    }
    __syncthreads();

    int k = t & 63;
    float cb, sb;
    __sincosf(TWO_PI * (float)k / 64.f, &sb, &cb);
    for (int ch = 0; ch < 16; ++ch) {
        int r = (t >> 6) + 4 * ch;
        float ar = 0.f, ai = 0.f, c = 1.f, s = 0.f;
        for (int n = 0; n < 64; ++n) {
            float xr = re[r][n], xi = im[r][n];
            ar += xr * c - xi * s;
            ai += xr * s + xi * c;
            float c2 = c * cb - s * sb;
            s = c * sb + s * cb;
            c = c2;
        }
        re2[r][k] = ar;
        im2[r][k] = ai;
    }
    __syncthreads();

    int w = t & 63;
    float bias = cbr[o];
    float vals[16];
    float sum = 0.f, sumsq = 0.f;
#pragma unroll
    for (int ch = 0; ch < 16; ++ch) {
        int hh = (t >> 6) + 4 * ch;
        float ar = 0.f;
        for (int u = 0; u < 64; ++u) {
            int idx = (hh * u) & 63;
            ar += re2[u][w] * twc[idx] - im2[u][w] * tws[idx];
        }
        ar = ar * (1.f / 4096.f) + bias;
        vals[ch] = ar;
        sum += ar;
        sumsq += ar * ar;
    }
    for (int off = 32; off; off >>= 1) {
        sum += __shfl_down(sum, off);
        sumsq += __shfl_down(sumsq, off);
    }
    int wid = t >> 6;
    if ((t & 63) == 0) { red[wid] = sum; red[4 + wid] = sumsq; }
    __syncthreads();
    sum = red[0] + red[1] + red[2] + red[3];
    sumsq = red[4] + red[5] + red[6] + red[7];
    float m = sum * (1.f / 4096.f);
    float var = sumsq * (1.f / 4096.f) - m * m;
    float rs = rsqrtf(var + 1e-5f);
    const float* xp = xprev + (size_t)fidx * HW;
    float* xo = xout + (size_t)fidx * HW;
#pragma unroll
    for (int ch = 0; ch < 16; ++ch) {
        int hh = (t >> 6) + 4 * ch;
        int p = hh * 64 + w;
        xo[p] = (vals[ch] - m) * rs * lnw[p] + lnb[p] + xp[p];
    }
}

__global__ void k_transpose_w(const float* __restrict__ w, float* __restrict__ wt,
                              int Fo, int K) {
    int idx = blockIdx.x * 256 + threadIdx.x;
    if (idx < Fo * K) {
        int f = idx / K, kk = idx - f * K;
        wt[(size_t)kk * Fo + f] = w[idx];
    }
}

// LN(H,W) + residual accumulate, channel-planar (final ffn_ln)
__global__ __launch_bounds__(256) void k_ln_res(const float* __restrict__ t_in,
                                                const float* __restrict__ w,
                                                const float* __restrict__ b,
                                                float* __restrict__ dst) {
    __shared__ float red[8];
    int fr = blockIdx.x;
    const float* src = t_in + (size_t)fr * HW;
    float* d = dst + (size_t)fr * HW;
    int t = threadIdx.x;
    float vals[16];
    float s = 0.f, sq = 0.f;
#pragma unroll
    for (int j = 0; j < 16; ++j) {
        float v = src[t + 256 * j];
        vals[j] = v;
        s += v;
        sq += v * v;
    }
    for (int off = 32; off; off >>= 1) {
        s += __shfl_down(s, off);
        sq += __shfl_down(sq, off);
    }
    int wid = t >> 6;
    if ((t & 63) == 0) { red[wid] = s; red[4 + wid] = sq; }
    __syncthreads();
    s = red[0] + red[1] + red[2] + red[3];
    sq = red[4] + red[5] + red[6] + red[7];
    float m = s * (1.f / 4096.f);
    float var = sq * (1.f / 4096.f) - m * m;
    float rs = rsqrtf(var + 1e-5f);
#pragma unroll
    for (int j = 0; j < 16; ++j) {
        int p = t + 256 * j;
        d[p] += (vals[j] - m) * rs * w[p] + b[p];
    }
}

// ===========================================================================
// Weight prep (fp32 -> bf16, MFMA-friendly layouts)
// ===========================================================================
__global__ void k_prep7(const float* __restrict__ w, unsigned short* __restrict__ o) {
    int idx = blockIdx.x * 256 + threadIdx.x;     // tap*8192 + f*64 + c
    if (idx < 49 * 128 * 64) {
        int tap = idx >> 13, rem = idx & 8191, f = rem >> 6, c = rem & 63;
        o[idx] = bf16c(w[(size_t)(f * 64 + c) * 49 + tap]);
    }
}
__global__ void k_prep3(const float* __restrict__ w, unsigned short* __restrict__ o) {
    int idx = blockIdx.x * 256 + threadIdx.x;     // tap*16384 + f*128 + c
    if (idx < 9 * 128 * 128) {
        int tap = idx >> 14, rem = idx & 16383, f = rem >> 7, c = rem & 127;
        o[idx] = bf16c(w[(size_t)(f * 128 + c) * 9 + tap]);
    }
}
__global__ void k_prepcvt(const float* __restrict__ w, unsigned short* __restrict__ o, int n) {
    int idx = blockIdx.x * 256 + threadIdx.x;
    if (idx < n) o[idx] = bf16c(w[idx]);
}

// Channel-planar fp32 -> position-major bf16  ([c][HW] -> [pos][64])
__global__ __launch_bounds__(256) void k_t2p(const float* __restrict__ x,
                                             unsigned short* __restrict__ xT) {
    __shared__ float tile[64][65];
    int blk = blockIdx.x;
    int f = blk >> 6;
    int p0 = (blk & 63) * 64;
    int t = threadIdx.x;
    const float* src = x + (size_t)f * Cd * HW;
    for (int j = t; j < 4096; j += 256) {
        int c = j >> 6, p = j & 63;
        tile[c][p] = src[(size_t)c * HW + p0 + p];
    }
    __syncthreads();
    unsigned short* dst = xT + ((size_t)f * HW + p0) * 64;
    for (int j = t; j < 4096; j += 256) {
        int p = j >> 6, c = j & 63;
        dst[(size_t)p * 64 + c] = bf16c(tile[c][p]);
    }
}

// ===========================================================================
// 7x7 conv, MFMA. in: xT bf16 [fi][4096][64]; wt: wb7 [49][128 f][64 c] bf16.
// out: y_ fp32 [fi][4096][128] = gelu(conv + bias). WG: 2 rows x 128 f.
// ===========================================================================
__global__ __launch_bounds__(256) void k_conv7m(const unsigned short* __restrict__ xT,
                                                const unsigned short* __restrict__ wb,
                                                const float* __restrict__ bias,
                                                float* __restrict__ yout) {
    __shared__ __align__(16) unsigned char smm[104448];   // inT 8*70*64*2 + 2*16384
    unsigned char* inT = smm;
    unsigned char* wt0 = smm + 71680;
    int blk = blockIdx.x;
    int fi = blk >> 5;
    int y0 = (blk & 31) * 2;
    int t = threadIdx.x, lane = t & 63, wv = t >> 6;

    const unsigned short* xf = xT + (size_t)fi * HW * 64;
    float4 z4 = make_float4(0.f, 0.f, 0.f, 0.f);
    // stage input rows y0-3 .. y0+4 into [8][70][64] (xp 3..66 = x 0..63)
    for (int idx = wv; idx < 64; idx += 4) {
        int r = idx >> 3, sg = idx & 7;
        int srow = y0 + r - 3;
        unsigned char* dst = inT + r * 8960 + 3 * 128 + sg * 1024;
        if (srow >= 0 && srow < 64) {
            gl2lds16(xf + (size_t)srow * 4096 + sg * 512 + lane * 8, dst);
        } else {
            *(float4*)(dst + lane * 16) = z4;
        }
    }
    // zero x-pads (xp 0..2, 67..69)
    for (int j = t; j < 8 * 6 * 8; j += 256) {
        int r = j / 48, k = j % 48;
        int xp = (k < 24) ? (k >> 3) : 67 + ((k - 24) >> 3);
        *(float4*)(inT + r * 8960 + xp * 128 + (k & 7) * 16) = z4;
    }
    // prologue: weights tap 0
    for (int q = 0; q < 4; ++q)
        gl2lds16(wb + (wv * 4 + q) * 512 + lane * 8, wt0 + (wv * 4 + q) * 1024);
    __syncthreads();

    int wm = wv & 1, wn = wv >> 1;
    f32x4 acc[4][4];
#pragma unroll
    for (int m = 0; m < 4; ++m)
#pragma unroll
        for (int n = 0; n < 4; ++n) acc[m][n] = (f32x4)0.f;
    int kgo = (lane >> 4) * 16, pl = lane & 15;
    int cur = 0;
    for (int tap = 0; tap < 49; ++tap) {
        if (tap + 1 < 49) {
            const unsigned short* g = wb + (size_t)(tap + 1) * 8192;
            unsigned char* wdst = wt0 + (cur ^ 1) * 16384;
            for (int q = 0; q < 4; ++q)
                gl2lds16(g + (wv * 4 + q) * 512 + lane * 8, wdst + (wv * 4 + q) * 1024);
        }
        unsigned char* wcur = wt0 + cur * 16384;
        int ky = tap / 7, kx = tap % 7;
        int rbase = (wm + ky) * 8960;
#pragma unroll
        for (int ks = 0; ks < 2; ++ks) {
            bf16x8 a[4], b[4];
#pragma unroll
            for (int m = 0; m < 4; ++m) {
                int xp = m * 16 + pl + kx;
                a[m] = *(const bf16x8*)(inT + rbase + xp * 128 + ks * 64 + kgo);
            }
#pragma unroll
            for (int n = 0; n < 4; ++n)
                b[n] = *(const bf16x8*)(wcur + (wn * 64 + n * 16 + pl) * 128 + ks * 64 + kgo);
#pragma unroll
            for (int m = 0; m < 4; ++m)
#pragma unroll
                for (int n = 0; n < 4; ++n)
                    acc[m][n] = __builtin_amdgcn_mfma_f32_16x16x32_bf16(a[m], b[n], acc[m][n], 0, 0, 0);
        }
        __syncthreads();
        cur ^= 1;
    }
    // epilogue: bias + gelu -> y_ [pos][128] fp32
    float* yo = yout + ((size_t)fi * HW + (size_t)(y0 + wm) * 64) * 128;
#pragma unroll
    for (int m = 0; m < 4; ++m)
#pragma unroll
        for (int n = 0; n < 4; ++n) {
            int f = wn * 64 + n * 16 + pl;
            float bs = bias[f];
#pragma unroll
            for (int r = 0; r < 4; ++r) {
                int x = m * 16 + (lane >> 4) * 4 + r;
                yo[(size_t)x * 128 + f] = gelu_f(acc[m][n][r] + bs);
            }
        }
}

// ===========================================================================
// 3x3 conv, MFMA. in: y_ fp32 [fi][4096][128]; wt: wb3[j] [9][128 f][128 c].
// out: t bf16 [fi][4096][128] = gelu(conv + bias). WG: 2 rows x 128 f.
// ===========================================================================
__global__ __launch_bounds__(256) void k_conv3m(const float* __restrict__ yin,
                                                const unsigned short* __restrict__ wb,
                                                const float* __restrict__ bias,
                                                unsigned short* __restrict__ tout) {
    __shared__ __align__(16) unsigned char smm[133120];   // inT 4*66*128*2 + 2*32768
    unsigned char* inT = smm;
    unsigned char* wt0 = smm + 67584;
    int blk = blockIdx.x;
    int fi = blk >> 5;
    int y0 = (blk & 31) * 2;
    int t = threadIdx.x, lane = t & 63, wv = t >> 6;
    const float* yf = yin + (size_t)fi * HW * 128;
    float4 z4 = make_float4(0.f, 0.f, 0.f, 0.f);
    // stage-convert input rows y0-1 .. y0+2 into [4][66][128] (xp 1..64)
    for (int r = 0; r < 4; ++r) {
        int srow = y0 + r - 1;
        bool valid = (srow >= 0 && srow < 64);
        const float* rsrc = yf + (size_t)(valid ? srow : 0) * 64 * 128;
        for (int q = t; q < 2048; q += 256) {
            int x = q >> 5, c4 = q & 31;
            float4 v = valid ? *(const float4*)(rsrc + (size_t)x * 128 + c4 * 4) : z4;
            ushort4 h;
            h.x = bf16c(v.x); h.y = bf16c(v.y); h.z = bf16c(v.z); h.w = bf16c(v.w);
            *(ushort4*)(inT + (size_t)(r * 66 + x + 1) * 256 + c4 * 8) = h;
        }
    }
    // x-edge zeros (xp 0, 65)
    for (int j = t; j < 128; j += 256) {
        int r = j >> 5, k = j & 31;
        int xp = (k < 16) ? 0 : 65;
        *(float4*)(inT + (size_t)(r * 66 + xp) * 256 + (k & 15) * 16) = z4;
    }
    // prologue: weights tap 0
    for (int sg = wv; sg < 32; sg += 4)
        gl2lds16(wb + sg * 512 + lane * 8, wt0 + sg * 1024);
    __syncthreads();

    int wm = wv & 1, wn = wv >> 1;
    f32x4 acc[4][4];
#pragma unroll
    for (int m = 0; m < 4; ++m)
#pragma unroll
        for (int n = 0; n < 4; ++n) acc[m][n] = (f32x4)0.f;
    int kgo = (lane >> 4) * 16, pl = lane & 15;
    int cur = 0;
    for (int tap = 0; tap < 9; ++tap) {
        if (tap + 1 < 9) {
            const unsigned short* g = wb + (size_t)(tap + 1) * 16384;
            unsigned char* wdst = wt0 + (cur ^ 1) * 32768;
            for (int sg = wv; sg < 32; sg += 4)
                gl2lds16(g + sg * 512 + lane * 8, wdst + sg * 1024);
        }
        unsigned char* wcur = wt0 + cur * 32768;
        int ky = tap / 3, kx = tap % 3;
        int rbase = (wm + ky) * 16896;
#pragma unroll
        for (int ks = 0; ks < 4; ++ks) {
            bf16x8 a[4], b[4];
#pragma unroll
            for (int m = 0; m < 4; ++m) {
                int xp = m * 16 + pl + kx;
                a[m] = *(const bf16x8*)(inT + rbase + (size_t)xp * 256 + ks * 64 + kgo);
            }
#pragma unroll
            for (int n = 0; n < 4; ++n)
                b[n] = *(const bf16x8*)(wcur + (size_t)(wn * 64 + n * 16 + pl) * 256 + ks * 64 + kgo);
#pragma unroll
            for (int m = 0; m < 4; ++m)
#pragma unroll
                for (int n = 0; n < 4; ++n)
                    acc[m][n] = __builtin_amdgcn_mfma_f32_16x16x32_bf16(a[m], b[n], acc[m][n], 0, 0, 0);
        }
        __syncthreads();
        cur ^= 1;
    }
    unsigned short* o = tout + ((size_t)fi * HW + (size_t)(y0 + wm) * 64) * 128;
#pragma unroll
    for (int m = 0; m < 4; ++m)
#pragma unroll
        for (int n = 0; n < 4; ++n) {
            int f = wn * 64 + n * 16 + pl;
            float bs = bias[f];
#pragma unroll
            for (int r = 0; r < 4; ++r) {
                int x = m * 16 + (lane >> 4) * 4 + r;
                o[(size_t)x * 128 + f] = bf16c(gelu_f(acc[m][n][r] + bs));
            }
        }
}

// ===========================================================================
// 1x1 (128->128) + gelu, MFMA. in: t bf16 [pos][128]; wt: wb1[j] [128 o][128 f];
// out: t2 fp32 [pos][128]. WG: 128 pos x 128 o.
// ===========================================================================
__global__ __launch_bounds__(256) void k_fc128(const unsigned short* __restrict__ tin,
                                               const unsigned short* __restrict__ wt,
                                               const float* __restrict__ bias,
                                               float* __restrict__ outp) {
    __shared__ __align__(16) unsigned char smm[65536];
    unsigned char* inL = smm;
    unsigned char* wL = smm + 32768;
    int blk = blockIdx.x;
    int fi = blk >> 5;
    int p0 = (blk & 31) * 128;
    int t = threadIdx.x, lane = t & 63, wv = t >> 6;
    const unsigned short* g = tin + ((size_t)fi * HW + p0) * 128;
    for (int sg = wv; sg < 32; sg += 4) gl2lds16(g + sg * 512 + lane * 8, inL + sg * 1024);
    for (int sg = wv; sg < 32; sg += 4) gl2lds16(wt + sg * 512 + lane * 8, wL + sg * 1024);
    __syncthreads();
    int wm = wv & 1, wn = wv >> 1;
    f32x4 acc[4][4];
#pragma unroll
    for (int m = 0; m < 4; ++m)
#pragma unroll
        for (int n = 0; n < 4; ++n) acc[m][n] = (f32x4)0.f;
    int kgo = (lane >> 4) * 16, pl = lane & 15;
#pragma unroll
    for (int ks = 0; ks < 4; ++ks) {
        bf16x8 a[4], b[4];
#pragma unroll
        for (int m = 0; m < 4; ++m)
            a[m] = *(const bf16x8*)(inL + (size_t)(wm * 64 + m * 16 + pl) * 256 + ks * 64 + kgo);
#pragma unroll
        for (int n = 0; n < 4; ++n)
            b[n] = *(const bf16x8*)(wL + (size_t)(wn * 64 + n * 16 + pl) * 256 + ks * 64 + kgo);
#pragma unroll
        for (int m = 0; m < 4; ++m)
#pragma unroll
            for (int n = 0; n < 4; ++n)
                acc[m][n] = __builtin_amdgcn_mfma_f32_16x16x32_bf16(a[m], b[n], acc[m][n], 0, 0, 0);
    }
    float* o = outp + ((size_t)fi * HW + p0) * 128;
#pragma unroll
    for (int m = 0; m < 4; ++m)
#pragma unroll
        for (int n = 0; n < 4; ++n) {
            int f = wn * 64 + n * 16 + pl;
            float bs = bias[f];
#pragma unroll
            for (int r = 0; r < 4; ++r) {
                int x = wm * 64 + m * 16 + (lane >> 4) * 4 + r;
                o[(size_t)x * 128 + f] = gelu_f(acc[m][n][r] + bs);
            }
        }
}

// ===========================================================================
// 1x1 cout (128->64), MFMA, A=weights so output is channel-planar fp32.
// in: y_ fp32 [pos][128]; wt: wbco [64 o][128 f]; out: [fi][64][4096].
// ===========================================================================
__global__ __launch_bounds__(256) void k_coutm(const float* __restrict__ yin,
                                               const unsigned short* __restrict__ wt,
                                               const float* __restrict__ bias,
                                               float* __restrict__ outp) {
    __shared__ __align__(16) unsigned char smm[49152];
    unsigned char* inL = smm;              // [128 pos][128 f] bf16
    unsigned char* wL = smm + 32768;       // [64 o][128 f] bf16
    int blk = blockIdx.x;
    int fi = blk >> 5;
    int p0 = (blk & 31) * 128;
    int t = threadIdx.x, lane = t & 63, wv = t >> 6;
    for (int sg = wv; sg < 16; sg += 4) gl2lds16(wt + sg * 512 + lane * 8, wL + sg * 1024);
    const float* src = yin + ((size_t)fi * HW + p0) * 128;
    for (int q = t; q < 4096; q += 256) {
        float4 v = *(const float4*)(src + (size_t)q * 4);
        ushort4 h;
        h.x = bf16c(v.x); h.y = bf16c(v.y); h.z = bf16c(v.z); h.w = bf16c(v.w);
        *(ushort4*)(inL + (size_t)q * 8) = h;
    }
    __syncthreads();
    int wm = wv & 1, wn = wv >> 1;      // wm: c-half(32), wn: pos-half(64)
    f32x4 acc[2][4];
#pragma unroll
    for (int m = 0; m < 2; ++m)
#pragma unroll
        for (int n = 0; n < 4; ++n) acc[m][n] = (f32x4)0.f;
    int kgo = (lane >> 4) * 16, pl = lane & 15;
#pragma unroll
    for (int ks = 0; ks < 4; ++ks) {
        bf16x8 a[2], b[4];
#pragma unroll
        for (int m = 0; m < 2; ++m)
            a[m] = *(const bf16x8*)(wL + (size_t)(wm * 32 + m * 16 + pl) * 256 + ks * 64 + kgo);
#pragma unroll
        for (int n = 0; n < 4; ++n)
            b[n] = *(const bf16x8*)(inL + (size_t)(wn * 64 + n * 16 + pl) * 256 + ks * 64 + kgo);
#pragma unroll
        for (int m = 0; m < 2; ++m)
#pragma unroll
            for (int n = 0; n < 4; ++n)
                acc[m][n] = __builtin_amdgcn_mfma_f32_16x16x32_bf16(a[m], b[n], acc[m][n], 0, 0, 0);
    }
#pragma unroll
    for (int m = 0; m < 2; ++m)
#pragma unroll
        for (int n = 0; n < 4; ++n) {
            int pos = p0 + wn * 64 + n * 16 + pl;
#pragma unroll
            for (int r = 0; r < 4; ++r) {
                int c = wm * 32 + m * 16 + (lane >> 4) * 4 + r;
                outp[((size_t)fi * 64 + c) * HW + pos] = acc[m][n][r] + bias[c];
            }
        }
}

// ===========================================================================
// LayerNorm(H,W) per (frame,f), position-major, 3-stage. y_ += LN(t2)*w + b.
// ===========================================================================
__global__ __launch_bounds__(256) void k_lnstat(const float* __restrict__ t2,
                                                float* __restrict__ part) {
    __shared__ float rs[128], rq[128];
    int blk = blockIdx.x;                  // SCF*16
    int fi = blk >> 4, slab = blk & 15;
    int t = threadIdx.x;
    int f = t & 127, half = t >> 7;
    const float* src = t2 + ((size_t)fi * HW + slab * 256 + half * 128) * 128 + f;
    float s = 0.f, sq = 0.f;
    for (int k = 0; k < 128; ++k) {
        float v = src[(size_t)k * 128];
        s += v; sq += v * v;
    }
    if (half == 1) { rs[f] = s; rq[f] = sq; }
    __syncthreads();
    if (half == 0) {
        s += rs[f]; sq += rq[f];
        float* p = part + ((size_t)blk * 128 + f) * 2;
        p[0] = s; p[1] = sq;
    }
}

__global__ void k_lnfin(const float* __restrict__ part, float* __restrict__ stat) {
    int fi = blockIdx.x, f = threadIdx.x;   // grid SCF, 128 thr
    float s = 0.f, sq = 0.f;
    for (int sl = 0; sl < 16; ++sl) {
        const float* p = part + (((size_t)fi * 16 + sl) * 128 + f) * 2;
        s += p[0]; sq += p[1];
    }
    float m = s * (1.f / 4096.f);
    float var = sq * (1.f / 4096.f) - m * m;
    stat[((size_t)fi * 128 + f) * 2] = m;
    stat[((size_t)fi * 128 + f) * 2 + 1] = rsqrtf(var + 1e-5f);
}

__global__ __launch_bounds__(256) void k_lnapply(const float* __restrict__ t2,
                                                 const float* __restrict__ stat,
                                                 const float* __restrict__ w,
                                                 const float* __restrict__ b,
                                                 float* __restrict__ y) {
    __shared__ float sm_m[128], sm_r[128];
    int blk = blockIdx.x;                  // SCF*32: 128 pos per block
    int fi = blk >> 5, p0 = (blk & 31) * 128;
    int t = threadIdx.x;
    int f = t & 127, ph = t >> 7;
    if (t < 128) {
        sm_m[t] = stat[((size_t)fi * 128 + t) * 2];
        sm_r[t] = stat[((size_t)fi * 128 + t) * 2 + 1];
    }
    __syncthreads();
    for (int k = ph; k < 128; k += 2) {
        int p = p0 + k;
        size_t idx = ((size_t)fi * HW + p) * 128 + f;
        float v = t2[idx];
        y[idx] += (v - sm_m[f]) * sm_r[f] * w[p] + b[p];
    }
}

// ===========================================================================
extern "C" void kernel_launch(void* const* d_in, const int* in_sizes, int n_in,
                              void* d_out, int out_size, void* d_ws, size_t ws_size,
                              hipStream_t stream) {
    (void)in_sizes; (void)n_in; (void)out_size; (void)ws_size;
    const float* x_in  = (const float*)d_in[0];
    const float* pl    = (const float*)d_in[1];
    const float* pBw_r = (const float*)d_in[2];
    const float* pBw_i = (const float*)d_in[3];
    const float* pBb_r = (const float*)d_in[4];
    const float* pBb_i = (const float*)d_in[5];
    const float* pCw_r = (const float*)d_in[6];
    const float* pCw_i = (const float*)d_in[7];
    const float* pCb_r = (const float*)d_in[8];
    const float* pCb_i = (const float*)d_in[9];
    const float* lruw  = (const float*)d_in[10];
    const float* lrub  = (const float*)d_in[11];
    const float* cinw  = (const float*)d_in[12];
    const float* cinb  = (const float*)d_in[13];
    const float* h3w   = (const float*)d_in[14];
    const float* h3b   = (const float*)d_in[15];
    const float* h1w   = (const float*)d_in[16];
    const float* h1b   = (const float*)d_in[17];
    const float* hlnw  = (const float*)d_in[18];
    const float* hlnb  = (const float*)d_in[19];
    const float* coutw = (const float*)d_in[20];
    const float* coutb = (const float*)d_in[21];
    const float* flnw  = (const float*)d_in[22];
    const float* flnb  = (const float*)d_in[23];
    float* out = (float*)d_out;

    unsigned char* ws = (unsigned char*)d_ws;
    // Region 1 (33.5 MB): LRU complex chunk | FFN {t2, t, xT}
    float2* cbuf = (float2*)ws;
    float* t2buf = (float*)ws;                                   // 16,777,216 B
    unsigned short* tb = (unsigned short*)(ws + 16777216);       //  8,388,608 B
    unsigned short* xT = (unsigned short*)(ws + 25165824);       //  4,194,304 B
    // Region 2: y_ + cout buffer
    float* ybuf  = (float*)(ws + 33554432);                      // 16,777,216 B
    float* cobuf = (float*)(ws + 50331648);                      //  8,388,608 B
    // Weights / small buffers
    unsigned short* wb7  = (unsigned short*)(ws + 58720256);     //   802,816 B
    unsigned short* wb3  = (unsigned short*)(ws + 59523072);     //   589,824 B (2 heads)
    unsigned short* wb1  = (unsigned short*)(ws + 60112896);     //    65,536 B
    unsigned short* wbco = (unsigned short*)(ws + 60178432);     //    16,384 B
    float* wtc    = (float*)(ws + 60194816);                     //    65,536 B
    float* lnpart = (float*)(ws + 60260352);                     //   131,072 B
    float* lnstat = (float*)(ws + 60391424);                     //     8,192 B

    for (int i = 0; i < NBLK; ++i) {
        const float* xsrc = (i == 0) ? x_in : out;

        // ---------------- ConvLRULayer (chunked by batch) ----------------
        k_transpose_w<<<16, 256, 0, stream>>>(pBw_r + (size_t)i * 4096, wtc, 64, 64);
        k_transpose_w<<<16, 256, 0, stream>>>(pBw_i + (size_t)i * 4096, wtc + 4096, 64, 64);
        k_transpose_w<<<16, 256, 0, stream>>>(pCw_r + (size_t)i * 4096, wtc + 8192, 64, 64);
        k_transpose_w<<<16, 256, 0, stream>>>(pCw_i + (size_t)i * 4096, wtc + 12288, 64, 64);
        for (int bc = 0; bc < Bd; ++bc) {
            size_t boff = (size_t)bc * CHUNK_C64;
            k_fft2<<<1024, 256, 0, stream>>>(xsrc + boff, cbuf);
            k_cmix<<<1024, 256, 0, stream>>>(cbuf, cbuf, wtc, wtc + 4096,
                                             pBb_r + (size_t)i * 64,
                                             pBb_i + (size_t)i * 64,
                                             pl + (size_t)i * 12288 + 8192, 1);
            k_scan<<<1024, 256, 0, stream>>>(cbuf, pl + (size_t)i * 12288);
            k_cmix<<<1024, 256, 0, stream>>>(cbuf, cbuf, wtc + 8192, wtc + 12288,
                                             nullptr, nullptr, nullptr, 0);
            k_ifft_ln<<<1024, 256, 0, stream>>>(cbuf, pCb_r + (size_t)i * 64,
                                                lruw + (size_t)i * 4096,
                                                lrub + (size_t)i * 4096,
                                                xsrc + boff, out + boff);
        }

        // ---------------- FFN weight prep ----------------
        k_prep7<<<1568, 256, 0, stream>>>(cinw + (size_t)i * 401408, wb7);
        k_prep3<<<576, 256, 0, stream>>>(h3w + (size_t)(i * 2 + 0) * 147456, wb3);
        k_prep3<<<576, 256, 0, stream>>>(h3w + (size_t)(i * 2 + 1) * 147456, wb3 + 147456);
        k_prepcvt<<<64, 256, 0, stream>>>(h1w + (size_t)(i * 2 + 0) * 16384, wb1, 16384);
        k_prepcvt<<<64, 256, 0, stream>>>(h1w + (size_t)(i * 2 + 1) * 16384, wb1 + 16384, 16384);
        k_prepcvt<<<32, 256, 0, stream>>>(coutw + (size_t)i * 8192, wbco, 8192);

        // ---------------- FeedForward (8-frame sub-chunks) ----------------
        for (int sc = 0; sc < 8; ++sc) {
            float* xb = out + (size_t)sc * SCF * Cd * HW;
            k_t2p<<<512, 256, 0, stream>>>(xb, xT);
            k_conv7m<<<256, 256, 0, stream>>>(xT, wb7, cinb + (size_t)i * 128, ybuf);
            for (int j = 0; j < NHEAD; ++j) {
                k_conv3m<<<256, 256, 0, stream>>>(ybuf, wb3 + (size_t)j * 147456,
                                                  h3b + (size_t)(i * 2 + j) * 128, tb);
                k_fc128<<<256, 256, 0, stream>>>(tb, wb1 + (size_t)j * 16384,
                                                 h1b + (size_t)(i * 2 + j) * 128, t2buf);
                k_lnstat<<<128, 256, 0, stream>>>(t2buf, lnpart);
                k_lnfin<<<SCF, 128, 0, stream>>>(lnpart, lnstat);
                k_lnapply<<<256, 256, 0, stream>>>(t2buf, lnstat,
                                                   hlnw + (size_t)(i * 2 + j) * 4096,
                                                   hlnb + (size_t)(i * 2 + j) * 4096, ybuf);
            }
            k_coutm<<<256, 256, 0, stream>>>(ybuf, wbco, coutb + (size_t)i * 64, cobuf);
            k_ln_res<<<512, 256, 0, stream>>>(cobuf, flnw + (size_t)i * 4096,
                                              flnb + (size_t)i * 4096, xb);
        }
    }
}

// Round 4
// 4589.969 us; speedup vs baseline: 4.6991x; 1.6733x over previous
//
#include <hip/hip_runtime.h>
#include <math.h>

// Problem dims
static constexpr int Bd = 4, Ld = 16, Cd = 64, Hd = 64, Wd = 64, Fd = 128;
static constexpr int NBLK = 2, NHEAD = 2;
static constexpr int HW = 4096;                 // Hd*Wd
static constexpr float TWO_PI = 6.28318530717958647692f;

// LRU chunk: 16 frames (one batch). FFN sub-chunk: 8 frames.
static constexpr int SCF = 8;
static constexpr size_t CHUNK_C64 = (size_t)16 * Cd * HW;   // floats per LRU chunk

typedef __attribute__((ext_vector_type(8))) short bf16x8;
typedef __attribute__((ext_vector_type(4))) float f32x4;

__device__ __forceinline__ float gelu_f(float v) {
    return 0.5f * v * (1.f + erff(v * 0.7071067811865476f));
}

__device__ __forceinline__ unsigned short bf16c(float f) {
    unsigned int u = __float_as_uint(f);
    unsigned int r = (u + 0x7fffu + ((u >> 16) & 1u)) >> 16;
    return (unsigned short)r;
}

// async global->LDS, 16 bytes per lane. lds dest = wave-uniform base + lane*16.
__device__ __forceinline__ void gl2lds16(const void* g, void* l) {
    __builtin_amdgcn_global_load_lds(
        (const __attribute__((address_space(1))) void*)g,
        (__attribute__((address_space(3))) void*)l, 16, 0, 0);
}

// ===========================================================================
// DFT along h only (the w-axis FFT cancels against its inverse: all ops in
// between are pointwise & fw-independent). Real in -> complex out.
// X1[fh,w] = sum_h x[h,w] * e^{-2pi i fh h/64}. One block per (l,c) frame.
// ===========================================================================
__global__ __launch_bounds__(256) void k_dfth(const float* __restrict__ x,
                                              float* __restrict__ out) {
    __shared__ float X[64][65];
    __shared__ float Tc[64][68], Ts[64][68];   // [h][fh]
    int f = blockIdx.x;
    int t = threadIdx.x;
    const float* src = x + (size_t)f * HW;
    for (int j = t; j < HW; j += 256) X[j >> 6][j & 63] = src[j];
    for (int j = t; j < 4096; j += 256) {
        int h = j >> 6, fh = j & 63;
        float ang = -(TWO_PI / 64.f) * (float)((h * fh) & 63);
        float sv, cv;
        __sincosf(ang, &sv, &cv);
        Tc[h][fh] = cv;
        Ts[h][fh] = sv;
    }
    __syncthreads();
    int pid = t & 15, oid = t >> 4;
    int p0 = pid * 4, fh0 = oid * 4;
    float cr[4][4] = {}, ci[4][4] = {};
    for (int h = 0; h < 64; ++h) {
        float4 xv = *(const float4*)&X[h][p0];
        float4 tc = *(const float4*)&Tc[h][fh0];
        float4 ts = *(const float4*)&Ts[h][fh0];
        float xa[4] = {xv.x, xv.y, xv.z, xv.w};
        float ca[4] = {tc.x, tc.y, tc.z, tc.w};
        float sa[4] = {ts.x, ts.y, ts.z, ts.w};
#pragma unroll
        for (int o = 0; o < 4; ++o)
#pragma unroll
            for (int p = 0; p < 4; ++p) {
                cr[o][p] += ca[o] * xa[p];
                ci[o][p] += sa[o] * xa[p];
            }
    }
#pragma unroll
    for (int o = 0; o < 4; ++o) {
        float* drow = out + ((size_t)f * HW + (size_t)(fh0 + o) * 64 + p0) * 2;
        *(float4*)(drow) = make_float4(cr[o][0], ci[o][0], cr[o][1], ci[o][1]);
        *(float4*)(drow + 4) = make_float4(cr[o][2], ci[o][2], cr[o][3], ci[o][3]);
    }
}

// ===========================================================================
// Complex channel mix (in-place safe). out[o,p] = (sum_c in[c,p]*W[o,c]
//   [+ bias at w==0 only]) * gamma(o,fh).  One block per (frame, fh-row).
// ===========================================================================
__global__ __launch_bounds__(256) void k_cmix(const float2* __restrict__ in,
                                              float2* __restrict__ out,
                                              const float* __restrict__ wtr_g,
                                              const float* __restrict__ wti_g,
                                              const float* __restrict__ br_g,
                                              const float* __restrict__ bi_g,
                                              const float* __restrict__ gl_g,
                                              int use_gamma) {
    __shared__ float inr[64][64], ini[64][64], wtr[64][64], wti[64][64];
    int blk = blockIdx.x;
    int fr = blk >> 6;
    int row = blk & 63;
    int t = threadIdx.x;
    const float2* src = in + (size_t)fr * Cd * HW + row * 64;
    for (int j = t; j < 4096; j += 256) {
        int c = j >> 6, p = j & 63;
        float2 v = src[(size_t)c * HW + p];
        inr[c][p] = v.x;
        ini[c][p] = v.y;
        wtr[c][p] = wtr_g[j];
        wti[c][p] = wti_g[j];
    }
    __syncthreads();
    int pid = t & 15, oid = t >> 4;
    int p0 = pid * 4, o0 = oid * 4;
    float ar[4][4] = {}, ai[4][4] = {};
    for (int c = 0; c < 64; ++c) {
        float4 xr4 = *(const float4*)&inr[c][p0];
        float4 xi4 = *(const float4*)&ini[c][p0];
        float4 wr4 = *(const float4*)&wtr[c][o0];
        float4 wi4 = *(const float4*)&wti[c][o0];
        float xr[4] = {xr4.x, xr4.y, xr4.z, xr4.w};
        float xi[4] = {xi4.x, xi4.y, xi4.z, xi4.w};
        float wr[4] = {wr4.x, wr4.y, wr4.z, wr4.w};
        float wi[4] = {wi4.x, wi4.y, wi4.z, wi4.w};
#pragma unroll
        for (int oo = 0; oo < 4; ++oo)
#pragma unroll
            for (int pp = 0; pp < 4; ++pp) {
                ar[oo][pp] += xr[pp] * wr[oo] - xi[pp] * wi[oo];
                ai[oo][pp] += xr[pp] * wi[oo] + xi[pp] * wr[oo];
            }
    }
#pragma unroll
    for (int oo = 0; oo < 4; ++oo) {
        int o = o0 + oo;
        float g = 1.f;
        if (use_gamma) {
            g = __expf(gl_g[o * 64 + row]);
            if (p0 == 0) {               // bias lives only at w==0 in half-domain
                ar[oo][0] += br_g[o];
                ai[oo][0] += bi_g[o];
            }
        }
        float v0r = ar[oo][0] * g, v0i = ai[oo][0] * g;
        float v1r = ar[oo][1] * g, v1i = ai[oo][1] * g;
        float v2r = ar[oo][2] * g, v2i = ai[oo][2] * g;
        float v3r = ar[oo][3] * g, v3i = ai[oo][3] * g;
        float2* dstrow = out + ((size_t)fr * Cd + o) * HW + row * 64 + p0;
        *(float4*)(dstrow) = make_float4(v0r, v0i, v1r, v1i);
        *(float4*)(dstrow + 2) = make_float4(v2r, v2i, v3r, v3i);
    }
}

// ===========================================================================
// Linear recurrence over L: h[t] = lamb(c,fh)*h[t-1] + h[t]. In-place.
// ===========================================================================
__global__ __launch_bounds__(256) void k_scan(float2* __restrict__ hbuf,
                                              const float* __restrict__ pl) {
    int g = blockIdx.x * 256 + threadIdx.x;
    int c = g >> 12;
    int hw = g & 4095;
    int h = hw >> 6;
    float nu = expf(pl[c * 64 + h]);
    float th = expf(pl[4096 + c * 64 + h]);
    float mag = expf(-nu);
    float sth, cth;
    sincosf(th, &sth, &cth);
    float lr = mag * cth, li = mag * sth;
    size_t base = (size_t)c * HW + hw;
    float2 acc = hbuf[base];
    for (int tt = 1; tt < Ld; ++tt) {
        size_t idx = base + (size_t)tt * Cd * HW;
        float2 v = hbuf[idx];
        float nr = lr * acc.x - li * acc.y + v.x;
        float ni = lr * acc.y + li * acc.x + v.y;
        acc = make_float2(nr, ni);
        hbuf[idx] = acc;
    }
}

// ===========================================================================
// Inverse DFT along h (complex->real) + Cb + LayerNorm(H,W) + residual.
// y[h,w] = Re((1/64) sum_fh S[fh,w] e^{+2pi i fh h/64}). One block per frame.
// ===========================================================================
__global__ __launch_bounds__(256) void k_idfth_ln(const float2* __restrict__ Xf,
                                                  const float* __restrict__ cbr,
                                                  const float* __restrict__ lnw,
                                                  const float* __restrict__ lnb,
                                                  const float* __restrict__ xprev,
                                                  float* __restrict__ xout) {
    __shared__ float Sr[64][65], Si[64][65];
    __shared__ float Tc[64][68], Ts[64][68];   // [fh][h], scaled by 1/64
    __shared__ float red[8];
    int fidx = blockIdx.x;
    int c = fidx & 63;
    int t = threadIdx.x;
    const float2* src = Xf + (size_t)fidx * HW;
    for (int j = t; j < HW; j += 256) {
        float2 v = src[j];
        Sr[j >> 6][j & 63] = v.x;
        Si[j >> 6][j & 63] = v.y;
    }
    for (int j = t; j < 4096; j += 256) {
        int fh = j >> 6, h = j & 63;
        float ang = (TWO_PI / 64.f) * (float)((fh * h) & 63);
        float sv, cv;
        __sincosf(ang, &sv, &cv);
        Tc[fh][h] = cv * (1.f / 64.f);
        Ts[fh][h] = sv * (1.f / 64.f);
    }
    __syncthreads();
    int pid = t & 15, oid = t >> 4;
    int p0 = pid * 4, h0 = oid * 4;
    float y[4][4] = {};
    for (int fh = 0; fh < 64; ++fh) {
        float4 sr4 = *(const float4*)&Sr[fh][p0];
        float4 si4 = *(const float4*)&Si[fh][p0];
        float4 tc4 = *(const float4*)&Tc[fh][h0];
        float4 ts4 = *(const float4*)&Ts[fh][h0];
        float sr[4] = {sr4.x, sr4.y, sr4.z, sr4.w};
        float si[4] = {si4.x, si4.y, si4.z, si4.w};
        float tc[4] = {tc4.x, tc4.y, tc4.z, tc4.w};
        float ts[4] = {ts4.x, ts4.y, ts4.z, ts4.w};
#pragma unroll
        for (int ho = 0; ho < 4; ++ho)
#pragma unroll
            for (int wp = 0; wp < 4; ++wp)
                y[ho][wp] += tc[ho] * sr[wp] - ts[ho] * si[wp];
    }
    float cb = cbr[c];
    float sum = 0.f, sumsq = 0.f;
#pragma unroll
    for (int ho = 0; ho < 4; ++ho)
#pragma unroll
        for (int wp = 0; wp < 4; ++wp) {
            float v = y[ho][wp] + cb;
            y[ho][wp] = v;
            sum += v;
            sumsq += v * v;
        }
    for (int off = 32; off; off >>= 1) {
        sum += __shfl_down(sum, off);
        sumsq += __shfl_down(sumsq, off);
    }
    int wid = t >> 6;
    if ((t & 63) == 0) { red[wid] = sum; red[4 + wid] = sumsq; }
    __syncthreads();
    sum = red[0] + red[1] + red[2] + red[3];
    sumsq = red[4] + red[5] + red[6] + red[7];
    float m = sum * (1.f / 4096.f);
    float var = sumsq * (1.f / 4096.f) - m * m;
    float rs = rsqrtf(var + 1e-5f);
    const float* xp = xprev + (size_t)fidx * HW;
    float* xo = xout + (size_t)fidx * HW;
#pragma unroll
    for (int ho = 0; ho < 4; ++ho) {
        int p = (h0 + ho) * 64 + p0;
        float4 wv = *(const float4*)(lnw + p);
        float4 bv = *(const float4*)(lnb + p);
        float4 xv = *(const float4*)(xp + p);
        float4 o4;
        o4.x = (y[ho][0] - m) * rs * wv.x + bv.x + xv.x;
        o4.y = (y[ho][1] - m) * rs * wv.y + bv.y + xv.y;
        o4.z = (y[ho][2] - m) * rs * wv.z + bv.z + xv.z;
        o4.w = (y[ho][3] - m) * rs * wv.w + bv.w + xv.w;
        *(float4*)(xo + p) = o4;
    }
}

__global__ void k_transpose_w(const float* __restrict__ w, float* __restrict__ wt,
                              int Fo, int K) {
    int idx = blockIdx.x * 256 + threadIdx.x;
    if (idx < Fo * K) {
        int f = idx / K, kk = idx - f * K;
        wt[(size_t)kk * Fo + f] = w[idx];
    }
}

// LN(H,W) + residual accumulate, channel-planar (final ffn_ln)
__global__ __launch_bounds__(256) void k_ln_res(const float* __restrict__ t_in,
                                                const float* __restrict__ w,
                                                const float* __restrict__ b,
                                                float* __restrict__ dst) {
    __shared__ float red[8];
    int fr = blockIdx.x;
    const float* src = t_in + (size_t)fr * HW;
    float* d = dst + (size_t)fr * HW;
    int t = threadIdx.x;
    float vals[16];
    float s = 0.f, sq = 0.f;
#pragma unroll
    for (int j = 0; j < 16; ++j) {
        float v = src[t + 256 * j];
        vals[j] = v;
        s += v;
        sq += v * v;
    }
    for (int off = 32; off; off >>= 1) {
        s += __shfl_down(s, off);
        sq += __shfl_down(sq, off);
    }
    int wid = t >> 6;
    if ((t & 63) == 0) { red[wid] = s; red[4 + wid] = sq; }
    __syncthreads();
    s = red[0] + red[1] + red[2] + red[3];
    sq = red[4] + red[5] + red[6] + red[7];
    float m = s * (1.f / 4096.f);
    float var = sq * (1.f / 4096.f) - m * m;
    float rs = rsqrtf(var + 1e-5f);
#pragma unroll
    for (int j = 0; j < 16; ++j) {
        int p = t + 256 * j;
        d[p] += (vals[j] - m) * rs * w[p] + b[p];
    }
}

// ===========================================================================
// Weight prep (fp32 -> bf16, MFMA-friendly layouts)
// ===========================================================================
__global__ void k_prep7(const float* __restrict__ w, unsigned short* __restrict__ o) {
    int idx = blockIdx.x * 256 + threadIdx.x;     // tap*8192 + f*64 + c
    if (idx < 49 * 128 * 64) {
        int tap = idx >> 13, rem = idx & 8191, f = rem >> 6, c = rem & 63;
        o[idx] = bf16c(w[(size_t)(f * 64 + c) * 49 + tap]);
    }
}
__global__ void k_prep3(const float* __restrict__ w, unsigned short* __restrict__ o) {
    int idx = blockIdx.x * 256 + threadIdx.x;     // tap*16384 + f*128 + c
    if (idx < 9 * 128 * 128) {
        int tap = idx >> 14, rem = idx & 16383, f = rem >> 7, c = rem & 127;
        o[idx] = bf16c(w[(size_t)(f * 128 + c) * 9 + tap]);
    }
}
__global__ void k_prepcvt(const float* __restrict__ w, unsigned short* __restrict__ o, int n) {
    int idx = blockIdx.x * 256 + threadIdx.x;
    if (idx < n) o[idx] = bf16c(w[idx]);
}

// Channel-planar fp32 -> position-major bf16  ([c][HW] -> [pos][64])
__global__ __launch_bounds__(256) void k_t2p(const float* __restrict__ x,
                                             unsigned short* __restrict__ xT) {
    __shared__ float tile[64][65];
    int blk = blockIdx.x;
    int f = blk >> 6;
    int p0 = (blk & 63) * 64;
    int t = threadIdx.x;
    const float* src = x + (size_t)f * Cd * HW;
    for (int j = t; j < 4096; j += 256) {
        int c = j >> 6, p = j & 63;
        tile[c][p] = src[(size_t)c * HW + p0 + p];
    }
    __syncthreads();
    unsigned short* dst = xT + ((size_t)f * HW + p0) * 64;
    for (int j = t; j < 4096; j += 256) {
        int p = j >> 6, c = j & 63;
        dst[(size_t)p * 64 + c] = bf16c(tile[c][p]);
    }
}

// ===========================================================================
// 7x7 conv, MFMA, XOR-swizzled LDS (rows are 128B=8 granules; granule index is
// XORed with (row&7); global_load_lds dests stay linear, global SOURCE addrs
// are pre-permuted; full-row zero fills are permutation-invariant).
// ===========================================================================
__global__ __launch_bounds__(256) void k_conv7m(const unsigned short* __restrict__ xT,
                                                const unsigned short* __restrict__ wb,
                                                const float* __restrict__ bias,
                                                float* __restrict__ yout) {
    __shared__ __align__(16) unsigned char smm[104448];   // inT 8*70*128 + 2*16384
    unsigned char* inT = smm;
    unsigned char* wt0 = smm + 71680;
    int blk = blockIdx.x;
    int fi = blk >> 5;
    int y0 = (blk & 31) * 2;
    int t = threadIdx.x, lane = t & 63, wv = t >> 6;
    int l3 = lane >> 3, l7 = lane & 7;

    const unsigned short* xf = xT + (size_t)fi * HW * 64;
    float4 z4 = make_float4(0.f, 0.f, 0.f, 0.f);
    // stage input rows y0-3 .. y0+4 into [8][70][64ch] (xp 3..66 = x 0..63)
    int ksw_in = l7 ^ ((3 + l3) & 7);           // xp&7 = (3 + l3)&7
    for (int idx = wv; idx < 64; idx += 4) {
        int r = idx >> 3, sg = idx & 7;
        int srow = y0 + r - 3;
        unsigned char* dst = inT + r * 8960 + 3 * 128 + sg * 1024;
        if (srow >= 0 && srow < 64) {
            gl2lds16(xf + (size_t)srow * 4096 + (sg * 8 + l3) * 64 + ksw_in * 8, dst);
        } else {
            *(float4*)(dst + lane * 16) = z4;
        }
    }
    // zero x-pads (full rows xp 0..2, 67..69 -> swizzle-invariant)
    for (int j = t; j < 8 * 6 * 8; j += 256) {
        int r = j / 48, k = j % 48;
        int xp = (k < 24) ? (k >> 3) : 67 + ((k - 24) >> 3);
        *(float4*)(inT + r * 8960 + xp * 128 + (k & 7) * 16) = z4;
    }
    // prologue: weights tap 0 (rows f: f&7 == l3)
    int ksw_w = l7 ^ l3;
    for (int q = 0; q < 4; ++q) {
        int f = (wv * 4 + q) * 8 + l3;
        gl2lds16(wb + (size_t)f * 64 + ksw_w * 8, wt0 + (wv * 4 + q) * 1024);
    }
    __syncthreads();

    int wm = wv & 1, wn = wv >> 1;
    f32x4 acc[4][4];
#pragma unroll
    for (int m = 0; m < 4; ++m)
#pragma unroll
        for (int n = 0; n < 4; ++n) acc[m][n] = (f32x4)0.f;
    int kg = lane >> 4, pl = lane & 15;
    int cur = 0;
    for (int tap = 0; tap < 49; ++tap) {
        if (tap + 1 < 49) {
            const unsigned short* g = wb + (size_t)(tap + 1) * 8192;
            unsigned char* wdst = wt0 + (cur ^ 1) * 16384;
            for (int q = 0; q < 4; ++q) {
                int f = (wv * 4 + q) * 8 + l3;
                gl2lds16(g + (size_t)f * 64 + ksw_w * 8, wdst + (wv * 4 + q) * 1024);
            }
        }
        unsigned char* wcur = wt0 + cur * 16384;
        int ky = tap / 7, kx = tap % 7;
        int rbase = (wm + ky) * 8960;
#pragma unroll
        for (int ks = 0; ks < 2; ++ks) {
            bf16x8 a[4], b[4];
#pragma unroll
            for (int m = 0; m < 4; ++m) {
                int xp = m * 16 + pl + kx;
                a[m] = *(const bf16x8*)(inT + rbase + xp * 128 +
                                        (((ks * 4 + kg) ^ (xp & 7)) << 4));
            }
#pragma unroll
            for (int n = 0; n < 4; ++n) {
                int row = wn * 64 + n * 16 + pl;
                b[n] = *(const bf16x8*)(wcur + row * 128 +
                                        (((ks * 4 + kg) ^ (pl & 7)) << 4));
            }
#pragma unroll
            for (int m = 0; m < 4; ++m)
#pragma unroll
                for (int n = 0; n < 4; ++n)
                    acc[m][n] = __builtin_amdgcn_mfma_f32_16x16x32_bf16(a[m], b[n], acc[m][n], 0, 0, 0);
        }
        __syncthreads();
        cur ^= 1;
    }
    float* yo = yout + ((size_t)fi * HW + (size_t)(y0 + wm) * 64) * 128;
#pragma unroll
    for (int m = 0; m < 4; ++m)
#pragma unroll
        for (int n = 0; n < 4; ++n) {
            int f = wn * 64 + n * 16 + pl;
            float bs = bias[f];
#pragma unroll
            for (int r = 0; r < 4; ++r) {
                int x = m * 16 + (lane >> 4) * 4 + r;
                yo[(size_t)x * 128 + f] = gelu_f(acc[m][n][r] + bs);
            }
        }
}

// ===========================================================================
// 3x3 conv, MFMA, swizzled (rows are 256B = 16 granules; XOR low-3 bits).
// ===========================================================================
__global__ __launch_bounds__(256) void k_conv3m(const float* __restrict__ yin,
                                                const unsigned short* __restrict__ wb,
                                                const float* __restrict__ bias,
                                                unsigned short* __restrict__ tout) {
    __shared__ __align__(16) unsigned char smm[133120];   // inT 4*66*256 + 2*32768
    unsigned char* inT = smm;
    unsigned char* wt0 = smm + 67584;
    int blk = blockIdx.x;
    int fi = blk >> 5;
    int y0 = (blk & 31) * 2;
    int t = threadIdx.x, lane = t & 63, wv = t >> 6;
    int l4 = lane >> 4, l15 = lane & 15;
    const float* yf = yin + (size_t)fi * HW * 128;
    float4 z4 = make_float4(0.f, 0.f, 0.f, 0.f);
    // stage-convert rows y0-1 .. y0+2 into [4][66][128ch] (xp 1..64), swizzled
    for (int r = 0; r < 4; ++r) {
        int srow = y0 + r - 1;
        bool valid = (srow >= 0 && srow < 64);
        const float* rsrc = yf + (size_t)(valid ? srow : 0) * 64 * 128;
        for (int q = t; q < 2048; q += 256) {
            int x = q >> 5, c4 = q & 31;
            int xp = x + 1;
            float4 v = valid ? *(const float4*)(rsrc + (size_t)x * 128 + c4 * 4) : z4;
            ushort4 h;
            h.x = bf16c(v.x); h.y = bf16c(v.y); h.z = bf16c(v.z); h.w = bf16c(v.w);
            *(ushort4*)(inT + (size_t)(r * 66 + xp) * 256 +
                        ((c4 * 8) ^ ((xp & 7) << 4))) = h;
        }
    }
    // x-edge zeros (full rows xp 0, 65)
    for (int j = t; j < 128; j += 256) {
        int r = j >> 5, k = j & 31;
        int xp = (k < 16) ? 0 : 65;
        *(float4*)(inT + (size_t)(r * 66 + xp) * 256 + (k & 15) * 16) = z4;
    }
    // prologue: weights tap 0 (rows f 256B)
    for (int sg = wv; sg < 32; sg += 4) {
        int f = sg * 4 + l4;
        gl2lds16(wb + (size_t)f * 128 + (l15 ^ (f & 7)) * 8, wt0 + sg * 1024);
    }
    __syncthreads();

    int wm = wv & 1, wn = wv >> 1;
    f32x4 acc[4][4];
#pragma unroll
    for (int m = 0; m < 4; ++m)
#pragma unroll
        for (int n = 0; n < 4; ++n) acc[m][n] = (f32x4)0.f;
    int kg = lane >> 4, pl = lane & 15;
    int cur = 0;
    for (int tap = 0; tap < 9; ++tap) {
        if (tap + 1 < 9) {
            const unsigned short* g = wb + (size_t)(tap + 1) * 16384;
            unsigned char* wdst = wt0 + (cur ^ 1) * 32768;
            for (int sg = wv; sg < 32; sg += 4) {
                int f = sg * 4 + l4;
                gl2lds16(g + (size_t)f * 128 + (l15 ^ (f & 7)) * 8, wdst + sg * 1024);
            }
        }
        unsigned char* wcur = wt0 + cur * 32768;
        int ky = tap / 3, kx = tap % 3;
        int rbase = (wm + ky) * 16896;
#pragma unroll
        for (int ks = 0; ks < 4; ++ks) {
            bf16x8 a[4], b[4];
#pragma unroll
            for (int m = 0; m < 4; ++m) {
                int xp = m * 16 + pl + kx;
                a[m] = *(const bf16x8*)(inT + rbase + (size_t)xp * 256 +
                                        ((ks * 64 + kg * 16) ^ ((xp & 7) << 4)));
            }
#pragma unroll
            for (int n = 0; n < 4; ++n) {
                int row = wn * 64 + n * 16 + pl;
                b[n] = *(const bf16x8*)(wcur + (size_t)row * 256 +
                                        ((ks * 64 + kg * 16) ^ ((pl & 7) << 4)));
            }
#pragma unroll
            for (int m = 0; m < 4; ++m)
#pragma unroll
                for (int n = 0; n < 4; ++n)
                    acc[m][n] = __builtin_amdgcn_mfma_f32_16x16x32_bf16(a[m], b[n], acc[m][n], 0, 0, 0);
        }
        __syncthreads();
        cur ^= 1;
    }
    unsigned short* o = tout + ((size_t)fi * HW + (size_t)(y0 + wm) * 64) * 128;
#pragma unroll
    for (int m = 0; m < 4; ++m)
#pragma unroll
        for (int n = 0; n < 4; ++n) {
            int f = wn * 64 + n * 16 + pl;
            float bs = bias[f];
#pragma unroll
            for (int r = 0; r < 4; ++r) {
                int x = m * 16 + (lane >> 4) * 4 + r;
                o[(size_t)x * 128 + f] = bf16c(gelu_f(acc[m][n][r] + bs));
            }
        }
}

// ===========================================================================
// 1x1 (128->128) + gelu, MFMA, swizzled.
// ===========================================================================
__global__ __launch_bounds__(256) void k_fc128(const unsigned short* __restrict__ tin,
                                               const unsigned short* __restrict__ wt,
                                               const float* __restrict__ bias,
                                               float* __restrict__ outp) {
    __shared__ __align__(16) unsigned char smm[65536];
    unsigned char* inL = smm;
    unsigned char* wL = smm + 32768;
    int blk = blockIdx.x;
    int fi = blk >> 5;
    int p0 = (blk & 31) * 128;
    int t = threadIdx.x, lane = t & 63, wv = t >> 6;
    int l4 = lane >> 4, l15 = lane & 15;
    const unsigned short* g = tin + ((size_t)fi * HW + p0) * 128;
    for (int sg = wv; sg < 32; sg += 4) {
        int r = sg * 4 + l4;
        gl2lds16(g + (size_t)r * 128 + (l15 ^ (r & 7)) * 8, inL + sg * 1024);
    }
    for (int sg = wv; sg < 32; sg += 4) {
        int r = sg * 4 + l4;
        gl2lds16(wt + (size_t)r * 128 + (l15 ^ (r & 7)) * 8, wL + sg * 1024);
    }
    __syncthreads();
    int wm = wv & 1, wn = wv >> 1;
    f32x4 acc[4][4];
#pragma unroll
    for (int m = 0; m < 4; ++m)
#pragma unroll
        for (int n = 0; n < 4; ++n) acc[m][n] = (f32x4)0.f;
    int kg = lane >> 4, pl = lane & 15;
#pragma unroll
    for (int ks = 0; ks < 4; ++ks) {
        bf16x8 a[4], b[4];
#pragma unroll
        for (int m = 0; m < 4; ++m) {
            int row = wm * 64 + m * 16 + pl;
            a[m] = *(const bf16x8*)(inL + (size_t)row * 256 +
                                    ((ks * 64 + kg * 16) ^ ((pl & 7) << 4)));
        }
#pragma unroll
        for (int n = 0; n < 4; ++n) {
            int row = wn * 64 + n * 16 + pl;
            b[n] = *(const bf16x8*)(wL + (size_t)row * 256 +
                                    ((ks * 64 + kg * 16) ^ ((pl & 7) << 4)));
        }
#pragma unroll
        for (int m = 0; m < 4; ++m)
#pragma unroll
            for (int n = 0; n < 4; ++n)
                acc[m][n] = __builtin_amdgcn_mfma_f32_16x16x32_bf16(a[m], b[n], acc[m][n], 0, 0, 0);
    }
    float* o = outp + ((size_t)fi * HW + p0) * 128;
#pragma unroll
    for (int m = 0; m < 4; ++m)
#pragma unroll
        for (int n = 0; n < 4; ++n) {
            int f = wn * 64 + n * 16 + pl;
            float bs = bias[f];
#pragma unroll
            for (int r = 0; r < 4; ++r) {
                int x = wm * 64 + m * 16 + (lane >> 4) * 4 + r;
                o[(size_t)x * 128 + f] = gelu_f(acc[m][n][r] + bs);
            }
        }
}

// ===========================================================================
// 1x1 cout (128->64), MFMA, A=weights -> channel-planar fp32 out. Swizzled.
// ===========================================================================
__global__ __launch_bounds__(256) void k_coutm(const float* __restrict__ yin,
                                               const unsigned short* __restrict__ wt,
                                               const float* __restrict__ bias,
                                               float* __restrict__ outp) {
    __shared__ __align__(16) unsigned char smm[49152];
    unsigned char* inL = smm;              // [128 pos][128 f] bf16, swizzled
    unsigned char* wL = smm + 32768;       // [64 o][128 f] bf16, swizzled
    int blk = blockIdx.x;
    int fi = blk >> 5;
    int p0 = (blk & 31) * 128;
    int t = threadIdx.x, lane = t & 63, wv = t >> 6;
    int l4 = lane >> 4, l15 = lane & 15;
    for (int sg = wv; sg < 16; sg += 4) {
        int r = sg * 4 + l4;
        gl2lds16(wt + (size_t)r * 128 + (l15 ^ (r & 7)) * 8, wL + sg * 1024);
    }
    const float* src = yin + ((size_t)fi * HW + p0) * 128;
    for (int q = t; q < 4096; q += 256) {
        int pos = q >> 5, c4 = q & 31;
        float4 v = *(const float4*)(src + (size_t)q * 4);
        ushort4 h;
        h.x = bf16c(v.x); h.y = bf16c(v.y); h.z = bf16c(v.z); h.w = bf16c(v.w);
        *(ushort4*)(inL + (size_t)pos * 256 + ((c4 * 8) ^ ((pos & 7) << 4))) = h;
    }
    __syncthreads();
    int wm = wv & 1, wn = wv >> 1;      // wm: c-half(32), wn: pos-half(64)
    f32x4 acc[2][4];
#pragma unroll
    for (int m = 0; m < 2; ++m)
#pragma unroll
        for (int n = 0; n < 4; ++n) acc[m][n] = (f32x4)0.f;
    int kg = lane >> 4, pl = lane & 15;
#pragma unroll
    for (int ks = 0; ks < 4; ++ks) {
        bf16x8 a[2], b[4];
#pragma unroll
        for (int m = 0; m < 2; ++m) {
            int row = wm * 32 + m * 16 + pl;
            a[m] = *(const bf16x8*)(wL + (size_t)row * 256 +
                                    ((ks * 64 + kg * 16) ^ ((pl & 7) << 4)));
        }
#pragma unroll
        for (int n = 0; n < 4; ++n) {
            int row = wn * 64 + n * 16 + pl;
            b[n] = *(const bf16x8*)(inL + (size_t)row * 256 +
                                    ((ks * 64 + kg * 16) ^ ((pl & 7) << 4)));
        }
#pragma unroll
        for (int m = 0; m < 2; ++m)
#pragma unroll
            for (int n = 0; n < 4; ++n)
                acc[m][n] = __builtin_amdgcn_mfma_f32_16x16x32_bf16(a[m], b[n], acc[m][n], 0, 0, 0);
    }
#pragma unroll
    for (int m = 0; m < 2; ++m)
#pragma unroll
        for (int n = 0; n < 4; ++n) {
            int pos = p0 + wn * 64 + n * 16 + pl;
#pragma unroll
            for (int r = 0; r < 4; ++r) {
                int c = wm * 32 + m * 16 + (lane >> 4) * 4 + r;
                outp[((size_t)fi * 64 + c) * HW + pos] = acc[m][n][r] + bias[c];
            }
        }
}

// ===========================================================================
// LayerNorm(H,W) per (frame,f), position-major, 3-stage. y_ += LN(t2)*w + b.
// ===========================================================================
__global__ __launch_bounds__(256) void k_lnstat(const float* __restrict__ t2,
                                                float* __restrict__ part) {
    __shared__ float rs[128], rq[128];
    int blk = blockIdx.x;                  // SCF*16
    int fi = blk >> 4, slab = blk & 15;
    int t = threadIdx.x;
    int f = t & 127, half = t >> 7;
    const float* src = t2 + ((size_t)fi * HW + slab * 256 + half * 128) * 128 + f;
    float s = 0.f, sq = 0.f;
    for (int k = 0; k < 128; ++k) {
        float v = src[(size_t)k * 128];
        s += v; sq += v * v;
    }
    if (half == 1) { rs[f] = s; rq[f] = sq; }
    __syncthreads();
    if (half == 0) {
        s += rs[f]; sq += rq[f];
        float* p = part + ((size_t)blk * 128 + f) * 2;
        p[0] = s; p[1] = sq;
    }
}

__global__ void k_lnfin(const float* __restrict__ part, float* __restrict__ stat) {
    int fi = blockIdx.x, f = threadIdx.x;   // grid SCF, 128 thr
    float s = 0.f, sq = 0.f;
    for (int sl = 0; sl < 16; ++sl) {
        const float* p = part + (((size_t)fi * 16 + sl) * 128 + f) * 2;
        s += p[0]; sq += p[1];
    }
    float m = s * (1.f / 4096.f);
    float var = sq * (1.f / 4096.f) - m * m;
    stat[((size_t)fi * 128 + f) * 2] = m;
    stat[((size_t)fi * 128 + f) * 2 + 1] = rsqrtf(var + 1e-5f);
}

__global__ __launch_bounds__(256) void k_lnapply(const float* __restrict__ t2,
                                                 const float* __restrict__ stat,
                                                 const float* __restrict__ w,
                                                 const float* __restrict__ b,
                                                 float* __restrict__ y) {
    __shared__ float sm_m[128], sm_r[128];
    int blk = blockIdx.x;                  // SCF*32: 128 pos per block
    int fi = blk >> 5, p0 = (blk & 31) * 128;
    int t = threadIdx.x;
    int f = t & 127, ph = t >> 7;
    if (t < 128) {
        sm_m[t] = stat[((size_t)fi * 128 + t) * 2];
        sm_r[t] = stat[((size_t)fi * 128 + t) * 2 + 1];
    }
    __syncthreads();
    for (int k = ph; k < 128; k += 2) {
        int p = p0 + k;
        size_t idx = ((size_t)fi * HW + p) * 128 + f;
        float v = t2[idx];
        y[idx] += (v - sm_m[f]) * sm_r[f] * w[p] + b[p];
    }
}

// ===========================================================================
extern "C" void kernel_launch(void* const* d_in, const int* in_sizes, int n_in,
                              void* d_out, int out_size, void* d_ws, size_t ws_size,
                              hipStream_t stream) {
    (void)in_sizes; (void)n_in; (void)out_size; (void)ws_size;
    const float* x_in  = (const float*)d_in[0];
    const float* pl    = (const float*)d_in[1];
    const float* pBw_r = (const float*)d_in[2];
    const float* pBw_i = (const float*)d_in[3];
    const float* pBb_r = (const float*)d_in[4];
    const float* pBb_i = (const float*)d_in[5];
    const float* pCw_r = (const float*)d_in[6];
    const float* pCw_i = (const float*)d_in[7];
    const float* pCb_r = (const float*)d_in[8];
    const float* pCb_i = (const float*)d_in[9];
    const float* lruw  = (const float*)d_in[10];
    const float* lrub  = (const float*)d_in[11];
    const float* cinw  = (const float*)d_in[12];
    const float* cinb  = (const float*)d_in[13];
    const float* h3w   = (const float*)d_in[14];
    const float* h3b   = (const float*)d_in[15];
    const float* h1w   = (const float*)d_in[16];
    const float* h1b   = (const float*)d_in[17];
    const float* hlnw  = (const float*)d_in[18];
    const float* hlnb  = (const float*)d_in[19];
    const float* coutw = (const float*)d_in[20];
    const float* coutb = (const float*)d_in[21];
    const float* flnw  = (const float*)d_in[22];
    const float* flnb  = (const float*)d_in[23];
    float* out = (float*)d_out;

    unsigned char* ws = (unsigned char*)d_ws;
    float2* cbuf = (float2*)ws;
    float* t2buf = (float*)ws;                                   // 16,777,216 B
    unsigned short* tb = (unsigned short*)(ws + 16777216);       //  8,388,608 B
    unsigned short* xT = (unsigned short*)(ws + 25165824);       //  4,194,304 B
    float* ybuf  = (float*)(ws + 33554432);                      // 16,777,216 B
    float* cobuf = (float*)(ws + 50331648);                      //  8,388,608 B
    unsigned short* wb7  = (unsigned short*)(ws + 58720256);     //   802,816 B
    unsigned short* wb3  = (unsigned short*)(ws + 59523072);     //   589,824 B
    unsigned short* wb1  = (unsigned short*)(ws + 60112896);     //    65,536 B
    unsigned short* wbco = (unsigned short*)(ws + 60178432);     //    16,384 B
    float* wtc    = (float*)(ws + 60194816);                     //    65,536 B
    float* lnpart = (float*)(ws + 60260352);                     //   131,072 B
    float* lnstat = (float*)(ws + 60391424);                     //     8,192 B

    for (int i = 0; i < NBLK; ++i) {
        const float* xsrc = (i == 0) ? x_in : out;

        // ---------------- ConvLRULayer (half-domain: DFT along h only) ------
        k_transpose_w<<<16, 256, 0, stream>>>(pBw_r + (size_t)i * 4096, wtc, 64, 64);
        k_transpose_w<<<16, 256, 0, stream>>>(pBw_i + (size_t)i * 4096, wtc + 4096, 64, 64);
        k_transpose_w<<<16, 256, 0, stream>>>(pCw_r + (size_t)i * 4096, wtc + 8192, 64, 64);
        k_transpose_w<<<16, 256, 0, stream>>>(pCw_i + (size_t)i * 4096, wtc + 12288, 64, 64);
        for (int bc = 0; bc < Bd; ++bc) {
            size_t boff = (size_t)bc * CHUNK_C64;
            k_dfth<<<1024, 256, 0, stream>>>(xsrc + boff, (float*)cbuf);
            k_cmix<<<1024, 256, 0, stream>>>(cbuf, cbuf, wtc, wtc + 4096,
                                             pBb_r + (size_t)i * 64,
                                             pBb_i + (size_t)i * 64,
                                             pl + (size_t)i * 12288 + 8192, 1);
            k_scan<<<1024, 256, 0, stream>>>(cbuf, pl + (size_t)i * 12288);
            k_cmix<<<1024, 256, 0, stream>>>(cbuf, cbuf, wtc + 8192, wtc + 12288,
                                             nullptr, nullptr, nullptr, 0);
            k_idfth_ln<<<1024, 256, 0, stream>>>(cbuf, pCb_r + (size_t)i * 64,
                                                 lruw + (size_t)i * 4096,
                                                 lrub + (size_t)i * 4096,
                                                 xsrc + boff, out + boff);
        }

        // ---------------- FFN weight prep ----------------
        k_prep7<<<1568, 256, 0, stream>>>(cinw + (size_t)i * 401408, wb7);
        k_prep3<<<576, 256, 0, stream>>>(h3w + (size_t)(i * 2 + 0) * 147456, wb3);
        k_prep3<<<576, 256, 0, stream>>>(h3w + (size_t)(i * 2 + 1) * 147456, wb3 + 147456);
        k_prepcvt<<<64, 256, 0, stream>>>(h1w + (size_t)(i * 2 + 0) * 16384, wb1, 16384);
        k_prepcvt<<<64, 256, 0, stream>>>(h1w + (size_t)(i * 2 + 1) * 16384, wb1 + 16384, 16384);
        k_prepcvt<<<32, 256, 0, stream>>>(coutw + (size_t)i * 8192, wbco, 8192);

        // ---------------- FeedForward (8-frame sub-chunks) ----------------
        for (int sc = 0; sc < 8; ++sc) {
            float* xb = out + (size_t)sc * SCF * Cd * HW;
            k_t2p<<<512, 256, 0, stream>>>(xb, xT);
            k_conv7m<<<256, 256, 0, stream>>>(xT, wb7, cinb + (size_t)i * 128, ybuf);
            for (int j = 0; j < NHEAD; ++j) {
                k_conv3m<<<256, 256, 0, stream>>>(ybuf, wb3 + (size_t)j * 147456,
                                                  h3b + (size_t)(i * 2 + j) * 128, tb);
                k_fc128<<<256, 256, 0, stream>>>(tb, wb1 + (size_t)j * 16384,
                                                 h1b + (size_t)(i * 2 + j) * 128, t2buf);
                k_lnstat<<<128, 256, 0, stream>>>(t2buf, lnpart);
                k_lnfin<<<SCF, 128, 0, stream>>>(lnpart, lnstat);
                k_lnapply<<<256, 256, 0, stream>>>(t2buf, lnstat,
                                                   hlnw + (size_t)(i * 2 + j) * 4096,
                                                   hlnb + (size_t)(i * 2 + j) * 4096, ybuf);
            }
            k_coutm<<<256, 256, 0, stream>>>(ybuf, wbco, coutb + (size_t)i * 64, cobuf);
            k_ln_res<<<512, 256, 0, stream>>>(cobuf, flnw + (size_t)i * 4096,
                                              flnb + (size_t)i * 4096, xb);
        }
    }
}

// Round 5
// 3529.537 us; speedup vs baseline: 6.1109x; 1.3004x over previous
//
#include <hip/hip_runtime.h>
#include <math.h>

// Problem dims
static constexpr int Bd = 4, Ld = 16, Cd = 64, Hd = 64, Wd = 64, Fd = 128;
static constexpr int NBLK = 2, NHEAD = 2;
static constexpr int HW = 4096;                 // Hd*Wd
static constexpr float TWO_PI = 6.28318530717958647692f;

typedef __attribute__((ext_vector_type(8))) short bf16x8;
typedef __attribute__((ext_vector_type(4))) float f32x4;

__device__ __forceinline__ float gelu_f(float v) {
    return 0.5f * v * (1.f + erff(v * 0.7071067811865476f));
}

__device__ __forceinline__ unsigned short bf16c(float f) {
    unsigned int u = __float_as_uint(f);
    unsigned int r = (u + 0x7fffu + ((u >> 16) & 1u)) >> 16;
    return (unsigned short)r;
}
__device__ __forceinline__ float bf2f(unsigned short u) {
    return __uint_as_float((unsigned int)u << 16);
}

// async global->LDS, 16 bytes per lane. lds dest = wave-uniform base + lane*16.
__device__ __forceinline__ void gl2lds16(const void* g, void* l) {
    __builtin_amdgcn_global_load_lds(
        (const __attribute__((address_space(1))) void*)g,
        (__attribute__((address_space(3))) void*)l, 16, 0, 0);
}

// ===========================================================================
// DFT along h only (w-axis FFT cancels against its inverse; everything in
// between is pointwise & fw-independent). Real in -> complex out.
// ===========================================================================
__global__ __launch_bounds__(256) void k_dfth(const float* __restrict__ x,
                                              float* __restrict__ out) {
    __shared__ float X[64][65];
    __shared__ float Tc[64][68], Ts[64][68];   // [h][fh]
    int f = blockIdx.x;
    int t = threadIdx.x;
    const float* src = x + (size_t)f * HW;
    for (int j = t; j < HW; j += 256) X[j >> 6][j & 63] = src[j];
    for (int j = t; j < 4096; j += 256) {
        int h = j >> 6, fh = j & 63;
        float ang = -(TWO_PI / 64.f) * (float)((h * fh) & 63);
        float sv, cv;
        __sincosf(ang, &sv, &cv);
        Tc[h][fh] = cv;
        Ts[h][fh] = sv;
    }
    __syncthreads();
    int pid = t & 15, oid = t >> 4;
    int p0 = pid * 4, fh0 = oid * 4;
    float cr[4][4] = {}, ci[4][4] = {};
    for (int h = 0; h < 64; ++h) {
        float4 xv = *(const float4*)&X[h][p0];
        float4 tc = *(const float4*)&Tc[h][fh0];
        float4 ts = *(const float4*)&Ts[h][fh0];
        float xa[4] = {xv.x, xv.y, xv.z, xv.w};
        float ca[4] = {tc.x, tc.y, tc.z, tc.w};
        float sa[4] = {ts.x, ts.y, ts.z, ts.w};
#pragma unroll
        for (int o = 0; o < 4; ++o)
#pragma unroll
            for (int p = 0; p < 4; ++p) {
                cr[o][p] += ca[o] * xa[p];
                ci[o][p] += sa[o] * xa[p];
            }
    }
#pragma unroll
    for (int o = 0; o < 4; ++o) {
        float* drow = out + ((size_t)f * HW + (size_t)(fh0 + o) * 64 + p0) * 2;
        *(float4*)(drow) = make_float4(cr[o][0], ci[o][0], cr[o][1], ci[o][1]);
        *(float4*)(drow + 4) = make_float4(cr[o][2], ci[o][2], cr[o][3], ci[o][3]);
    }
}

// ===========================================================================
// Complex channel mix (in-place safe). One block per (frame, fh-row).
// ===========================================================================
__global__ __launch_bounds__(256) void k_cmix(const float2* __restrict__ in,
                                              float2* __restrict__ out,
                                              const float* __restrict__ wtr_g,
                                              const float* __restrict__ wti_g,
                                              const float* __restrict__ br_g,
                                              const float* __restrict__ bi_g,
                                              const float* __restrict__ gl_g,
                                              int use_gamma) {
    __shared__ float inr[64][64], ini[64][64], wtr[64][64], wti[64][64];
    int blk = blockIdx.x;
    int fr = blk >> 6;
    int row = blk & 63;
    int t = threadIdx.x;
    const float2* src = in + (size_t)fr * Cd * HW + row * 64;
    for (int j = t; j < 4096; j += 256) {
        int c = j >> 6, p = j & 63;
        float2 v = src[(size_t)c * HW + p];
        inr[c][p] = v.x;
        ini[c][p] = v.y;
        wtr[c][p] = wtr_g[j];
        wti[c][p] = wti_g[j];
    }
    __syncthreads();
    int pid = t & 15, oid = t >> 4;
    int p0 = pid * 4, o0 = oid * 4;
    float ar[4][4] = {}, ai[4][4] = {};
    for (int c = 0; c < 64; ++c) {
        float4 xr4 = *(const float4*)&inr[c][p0];
        float4 xi4 = *(const float4*)&ini[c][p0];
        float4 wr4 = *(const float4*)&wtr[c][o0];
        float4 wi4 = *(const float4*)&wti[c][o0];
        float xr[4] = {xr4.x, xr4.y, xr4.z, xr4.w};
        float xi[4] = {xi4.x, xi4.y, xi4.z, xi4.w};
        float wr[4] = {wr4.x, wr4.y, wr4.z, wr4.w};
        float wi[4] = {wi4.x, wi4.y, wi4.z, wi4.w};
#pragma unroll
        for (int oo = 0; oo < 4; ++oo)
#pragma unroll
            for (int pp = 0; pp < 4; ++pp) {
                ar[oo][pp] += xr[pp] * wr[oo] - xi[pp] * wi[oo];
                ai[oo][pp] += xr[pp] * wi[oo] + xi[pp] * wr[oo];
            }
    }
#pragma unroll
    for (int oo = 0; oo < 4; ++oo) {
        int o = o0 + oo;
        float g = 1.f;
        if (use_gamma) {
            g = __expf(gl_g[o * 64 + row]);
            if (p0 == 0) {               // bias lives only at w==0 in half-domain
                ar[oo][0] += br_g[o];
                ai[oo][0] += bi_g[o];
            }
        }
        float v0r = ar[oo][0] * g, v0i = ai[oo][0] * g;
        float v1r = ar[oo][1] * g, v1i = ai[oo][1] * g;
        float v2r = ar[oo][2] * g, v2i = ai[oo][2] * g;
        float v3r = ar[oo][3] * g, v3i = ai[oo][3] * g;
        float2* dstrow = out + ((size_t)fr * Cd + o) * HW + row * 64 + p0;
        *(float4*)(dstrow) = make_float4(v0r, v0i, v1r, v1i);
        *(float4*)(dstrow + 2) = make_float4(v2r, v2i, v3r, v3i);
    }
}

// ===========================================================================
// Linear recurrence over L for LB batches: h[t] = lamb*h[t-1] + h[t]. In-place.
// Grid = LB*1024 blocks; layout [b][L][C][HW].
// ===========================================================================
__global__ __launch_bounds__(256) void k_scan(float2* __restrict__ hbuf,
                                              const float* __restrict__ pl) {
    int g = blockIdx.x * 256 + threadIdx.x;
    int b = g >> 18;
    int rem = g & 262143;
    int c = rem >> 12;
    int hw = rem & 4095;
    int h = hw >> 6;
    float nu = expf(pl[c * 64 + h]);
    float th = expf(pl[4096 + c * 64 + h]);
    float mag = expf(-nu);
    float sth, cth;
    sincosf(th, &sth, &cth);
    float lr = mag * cth, li = mag * sth;
    size_t base = ((size_t)b * Ld * Cd + c) * HW + hw;
    float2 acc = hbuf[base];
    for (int tt = 1; tt < Ld; ++tt) {
        size_t idx = base + (size_t)tt * Cd * HW;
        float2 v = hbuf[idx];
        float nr = lr * acc.x - li * acc.y + v.x;
        float ni = lr * acc.y + li * acc.x + v.y;
        acc = make_float2(nr, ni);
        hbuf[idx] = acc;
    }
}

// ===========================================================================
// Inverse DFT along h (complex->real) + Cb + LayerNorm(H,W) + residual.
// ===========================================================================
__global__ __launch_bounds__(256) void k_idfth_ln(const float2* __restrict__ Xf,
                                                  const float* __restrict__ cbr,
                                                  const float* __restrict__ lnw,
                                                  const float* __restrict__ lnb,
                                                  const float* __restrict__ xprev,
                                                  float* __restrict__ xout) {
    __shared__ float Sr[64][65], Si[64][65];
    __shared__ float Tc[64][68], Ts[64][68];   // [fh][h], scaled by 1/64
    __shared__ float red[8];
    int fidx = blockIdx.x;
    int c = fidx & 63;
    int t = threadIdx.x;
    const float2* src = Xf + (size_t)fidx * HW;
    for (int j = t; j < HW; j += 256) {
        float2 v = src[j];
        Sr[j >> 6][j & 63] = v.x;
        Si[j >> 6][j & 63] = v.y;
    }
    for (int j = t; j < 4096; j += 256) {
        int fh = j >> 6, h = j & 63;
        float ang = (TWO_PI / 64.f) * (float)((fh * h) & 63);
        float sv, cv;
        __sincosf(ang, &sv, &cv);
        Tc[fh][h] = cv * (1.f / 64.f);
        Ts[fh][h] = sv * (1.f / 64.f);
    }
    __syncthreads();
    int pid = t & 15, oid = t >> 4;
    int p0 = pid * 4, h0 = oid * 4;
    float y[4][4] = {};
    for (int fh = 0; fh < 64; ++fh) {
        float4 sr4 = *(const float4*)&Sr[fh][p0];
        float4 si4 = *(const float4*)&Si[fh][p0];
        float4 tc4 = *(const float4*)&Tc[fh][h0];
        float4 ts4 = *(const float4*)&Ts[fh][h0];
        float sr[4] = {sr4.x, sr4.y, sr4.z, sr4.w};
        float si[4] = {si4.x, si4.y, si4.z, si4.w};
        float tc[4] = {tc4.x, tc4.y, tc4.z, tc4.w};
        float ts[4] = {ts4.x, ts4.y, ts4.z, ts4.w};
#pragma unroll
        for (int ho = 0; ho < 4; ++ho)
#pragma unroll
            for (int wp = 0; wp < 4; ++wp)
                y[ho][wp] += tc[ho] * sr[wp] - ts[ho] * si[wp];
    }
    float cb = cbr[c];
    float sum = 0.f, sumsq = 0.f;
#pragma unroll
    for (int ho = 0; ho < 4; ++ho)
#pragma unroll
        for (int wp = 0; wp < 4; ++wp) {
            float v = y[ho][wp] + cb;
            y[ho][wp] = v;
            sum += v;
            sumsq += v * v;
        }
    for (int off = 32; off; off >>= 1) {
        sum += __shfl_down(sum, off);
        sumsq += __shfl_down(sumsq, off);
    }
    int wid = t >> 6;
    if ((t & 63) == 0) { red[wid] = sum; red[4 + wid] = sumsq; }
    __syncthreads();
    sum = red[0] + red[1] + red[2] + red[3];
    sumsq = red[4] + red[5] + red[6] + red[7];
    float m = sum * (1.f / 4096.f);
    float var = sumsq * (1.f / 4096.f) - m * m;
    float rs = rsqrtf(var + 1e-5f);
    const float* xp = xprev + (size_t)fidx * HW;
    float* xo = xout + (size_t)fidx * HW;
#pragma unroll
    for (int ho = 0; ho < 4; ++ho) {
        int p = (h0 + ho) * 64 + p0;
        float4 wv = *(const float4*)(lnw + p);
        float4 bv = *(const float4*)(lnb + p);
        float4 xv = *(const float4*)(xp + p);
        float4 o4;
        o4.x = (y[ho][0] - m) * rs * wv.x + bv.x + xv.x;
        o4.y = (y[ho][1] - m) * rs * wv.y + bv.y + xv.y;
        o4.z = (y[ho][2] - m) * rs * wv.z + bv.z + xv.z;
        o4.w = (y[ho][3] - m) * rs * wv.w + bv.w + xv.w;
        *(float4*)(xo + p) = o4;
    }
}

// All four complex-mix weight transposes in one dispatch (grid 64).
__global__ void k_transpose_w4(const float* __restrict__ a, const float* __restrict__ b,
                               const float* __restrict__ c, const float* __restrict__ d,
                               float* __restrict__ wt) {
    int idx = blockIdx.x * 256 + threadIdx.x;     // 0..16383
    int sec = idx >> 12, r = idx & 4095;
    const float* s = (sec == 0) ? a : (sec == 1) ? b : (sec == 2) ? c : d;
    int f = r >> 6, k = r & 63;
    wt[sec * 4096 + k * 64 + f] = s[f * 64 + k];
}

// LN(H,W) + residual accumulate, channel-planar (final ffn_ln)
__global__ __launch_bounds__(256) void k_ln_res(const float* __restrict__ t_in,
                                                const float* __restrict__ w,
                                                const float* __restrict__ b,
                                                float* __restrict__ dst) {
    __shared__ float red[8];
    int fr = blockIdx.x;
    const float* src = t_in + (size_t)fr * HW;
    float* d = dst + (size_t)fr * HW;
    int t = threadIdx.x;
    float vals[16];
    float s = 0.f, sq = 0.f;
#pragma unroll
    for (int j = 0; j < 16; ++j) {
        float v = src[t + 256 * j];
        vals[j] = v;
        s += v;
        sq += v * v;
    }
    for (int off = 32; off; off >>= 1) {
        s += __shfl_down(s, off);
        sq += __shfl_down(sq, off);
    }
    int wid = t >> 6;
    if ((t & 63) == 0) { red[wid] = s; red[4 + wid] = sq; }
    __syncthreads();
    s = red[0] + red[1] + red[2] + red[3];
    sq = red[4] + red[5] + red[6] + red[7];
    float m = s * (1.f / 4096.f);
    float var = sq * (1.f / 4096.f) - m * m;
    float rs = rsqrtf(var + 1e-5f);
#pragma unroll
    for (int j = 0; j < 16; ++j) {
        int p = t + 256 * j;
        d[p] += (vals[j] - m) * rs * w[p] + b[p];
    }
}

// ===========================================================================
// Weight prep (fp32 -> bf16, MFMA-friendly layouts)
// ===========================================================================
__global__ void k_prep7(const float* __restrict__ w, unsigned short* __restrict__ o) {
    int idx = blockIdx.x * 256 + threadIdx.x;     // tap*8192 + f*64 + c
    if (idx < 49 * 128 * 64) {
        int tap = idx >> 13, rem = idx & 8191, f = rem >> 6, c = rem & 63;
        o[idx] = bf16c(w[(size_t)(f * 64 + c) * 49 + tap]);
    }
}
__global__ void k_prep3(const float* __restrict__ w, unsigned short* __restrict__ o,
                        int nh) {
    int idx = blockIdx.x * 256 + threadIdx.x;     // head*147456 + tap*16384 + f*128 + c
    if (idx < nh * 147456) {
        int head = idx / 147456;
        int rem = idx - head * 147456;
        int tap = rem >> 14, r2 = rem & 16383, f = r2 >> 7, c = r2 & 127;
        o[idx] = bf16c(w[(size_t)head * 147456 + (size_t)(f * 128 + c) * 9 + tap]);
    }
}
__global__ void k_prepcvt(const float* __restrict__ w, unsigned short* __restrict__ o, int n) {
    int idx = blockIdx.x * 256 + threadIdx.x;
    if (idx < n) o[idx] = bf16c(w[idx]);
}

// Channel-planar fp32 -> position-major bf16  ([c][HW] -> [pos][64])
__global__ __launch_bounds__(256) void k_t2p(const float* __restrict__ x,
                                             unsigned short* __restrict__ xT) {
    __shared__ float tile[64][65];
    int blk = blockIdx.x;
    int f = blk >> 6;
    int p0 = (blk & 63) * 64;
    int t = threadIdx.x;
    const float* src = x + (size_t)f * Cd * HW;
    for (int j = t; j < 4096; j += 256) {
        int c = j >> 6, p = j & 63;
        tile[c][p] = src[(size_t)c * HW + p0 + p];
    }
    __syncthreads();
    unsigned short* dst = xT + ((size_t)f * HW + p0) * 64;
    for (int j = t; j < 4096; j += 256) {
        int p = j >> 6, c = j & 63;
        dst[(size_t)p * 64 + c] = bf16c(tile[c][p]);
    }
}

// ===========================================================================
// 7x7 conv, MFMA, XOR-swizzled LDS.
// ===========================================================================
__global__ __launch_bounds__(256) void k_conv7m(const unsigned short* __restrict__ xT,
                                                const unsigned short* __restrict__ wb,
                                                const float* __restrict__ bias,
                                                float* __restrict__ yout) {
    __shared__ __align__(16) unsigned char smm[104448];   // inT 8*70*128 + 2*16384
    unsigned char* inT = smm;
    unsigned char* wt0 = smm + 71680;
    int blk = blockIdx.x;
    int fi = blk >> 5;
    int y0 = (blk & 31) * 2;
    int t = threadIdx.x, lane = t & 63, wv = t >> 6;
    int l3 = lane >> 3, l7 = lane & 7;

    const unsigned short* xf = xT + (size_t)fi * HW * 64;
    float4 z4 = make_float4(0.f, 0.f, 0.f, 0.f);
    int ksw_in = l7 ^ ((3 + l3) & 7);           // xp&7 = (3 + l3)&7
    for (int idx = wv; idx < 64; idx += 4) {
        int r = idx >> 3, sg = idx & 7;
        int srow = y0 + r - 3;
        unsigned char* dst = inT + r * 8960 + 3 * 128 + sg * 1024;
        if (srow >= 0 && srow < 64) {
            gl2lds16(xf + (size_t)srow * 4096 + (sg * 8 + l3) * 64 + ksw_in * 8, dst);
        } else {
            *(float4*)(dst + lane * 16) = z4;
        }
    }
    for (int j = t; j < 8 * 6 * 8; j += 256) {
        int r = j / 48, k = j % 48;
        int xp = (k < 24) ? (k >> 3) : 67 + ((k - 24) >> 3);
        *(float4*)(inT + r * 8960 + xp * 128 + (k & 7) * 16) = z4;
    }
    int ksw_w = l7 ^ l3;
    for (int q = 0; q < 4; ++q) {
        int f = (wv * 4 + q) * 8 + l3;
        gl2lds16(wb + (size_t)f * 64 + ksw_w * 8, wt0 + (wv * 4 + q) * 1024);
    }
    __syncthreads();

    int wm = wv & 1, wn = wv >> 1;
    f32x4 acc[4][4];
#pragma unroll
    for (int m = 0; m < 4; ++m)
#pragma unroll
        for (int n = 0; n < 4; ++n) acc[m][n] = (f32x4)0.f;
    int kg = lane >> 4, pl = lane & 15;
    int cur = 0;
    for (int tap = 0; tap < 49; ++tap) {
        if (tap + 1 < 49) {
            const unsigned short* g = wb + (size_t)(tap + 1) * 8192;
            unsigned char* wdst = wt0 + (cur ^ 1) * 16384;
            for (int q = 0; q < 4; ++q) {
                int f = (wv * 4 + q) * 8 + l3;
                gl2lds16(g + (size_t)f * 64 + ksw_w * 8, wdst + (wv * 4 + q) * 1024);
            }
        }
        unsigned char* wcur = wt0 + cur * 16384;
        int ky = tap / 7, kx = tap % 7;
        int rbase = (wm + ky) * 8960;
#pragma unroll
        for (int ks = 0; ks < 2; ++ks) {
            bf16x8 a[4], b[4];
#pragma unroll
            for (int m = 0; m < 4; ++m) {
                int xp = m * 16 + pl + kx;
                a[m] = *(const bf16x8*)(inT + rbase + xp * 128 +
                                        (((ks * 4 + kg) ^ (xp & 7)) << 4));
            }
#pragma unroll
            for (int n = 0; n < 4; ++n) {
                int row = wn * 64 + n * 16 + pl;
                b[n] = *(const bf16x8*)(wcur + row * 128 +
                                        (((ks * 4 + kg) ^ (pl & 7)) << 4));
            }
#pragma unroll
            for (int m = 0; m < 4; ++m)
#pragma unroll
                for (int n = 0; n < 4; ++n)
                    acc[m][n] = __builtin_amdgcn_mfma_f32_16x16x32_bf16(a[m], b[n], acc[m][n], 0, 0, 0);
        }
        __syncthreads();
        cur ^= 1;
    }
    float* yo = yout + ((size_t)fi * HW + (size_t)(y0 + wm) * 64) * 128;
#pragma unroll
    for (int m = 0; m < 4; ++m)
#pragma unroll
        for (int n = 0; n < 4; ++n) {
            int f = wn * 64 + n * 16 + pl;
            float bs = bias[f];
#pragma unroll
            for (int r = 0; r < 4; ++r) {
                int x = m * 16 + (lane >> 4) * 4 + r;
                yo[(size_t)x * 128 + f] = gelu_f(acc[m][n][r] + bs);
            }
        }
}

// ===========================================================================
// 3x3 conv, MFMA, swizzled.
// ===========================================================================
__global__ __launch_bounds__(256) void k_conv3m(const float* __restrict__ yin,
                                                const unsigned short* __restrict__ wb,
                                                const float* __restrict__ bias,
                                                unsigned short* __restrict__ tout) {
    __shared__ __align__(16) unsigned char smm[133120];   // inT 4*66*256 + 2*32768
    unsigned char* inT = smm;
    unsigned char* wt0 = smm + 67584;
    int blk = blockIdx.x;
    int fi = blk >> 5;
    int y0 = (blk & 31) * 2;
    int t = threadIdx.x, lane = t & 63, wv = t >> 6;
    int l4 = lane >> 4, l15 = lane & 15;
    const float* yf = yin + (size_t)fi * HW * 128;
    float4 z4 = make_float4(0.f, 0.f, 0.f, 0.f);
    for (int r = 0; r < 4; ++r) {
        int srow = y0 + r - 1;
        bool valid = (srow >= 0 && srow < 64);
        const float* rsrc = yf + (size_t)(valid ? srow : 0) * 64 * 128;
        for (int q = t; q < 2048; q += 256) {
            int x = q >> 5, c4 = q & 31;
            int xp = x + 1;
            float4 v = valid ? *(const float4*)(rsrc + (size_t)x * 128 + c4 * 4) : z4;
            ushort4 h;
            h.x = bf16c(v.x); h.y = bf16c(v.y); h.z = bf16c(v.z); h.w = bf16c(v.w);
            *(ushort4*)(inT + (size_t)(r * 66 + xp) * 256 +
                        ((c4 * 8) ^ ((xp & 7) << 4))) = h;
        }
    }
    for (int j = t; j < 128; j += 256) {
        int r = j >> 5, k = j & 31;
        int xp = (k < 16) ? 0 : 65;
        *(float4*)(inT + (size_t)(r * 66 + xp) * 256 + (k & 15) * 16) = z4;
    }
    for (int sg = wv; sg < 32; sg += 4) {
        int f = sg * 4 + l4;
        gl2lds16(wb + (size_t)f * 128 + (l15 ^ (f & 7)) * 8, wt0 + sg * 1024);
    }
    __syncthreads();

    int wm = wv & 1, wn = wv >> 1;
    f32x4 acc[4][4];
#pragma unroll
    for (int m = 0; m < 4; ++m)
#pragma unroll
        for (int n = 0; n < 4; ++n) acc[m][n] = (f32x4)0.f;
    int kg = lane >> 4, pl = lane & 15;
    int cur = 0;
    for (int tap = 0; tap < 9; ++tap) {
        if (tap + 1 < 9) {
            const unsigned short* g = wb + (size_t)(tap + 1) * 16384;
            unsigned char* wdst = wt0 + (cur ^ 1) * 32768;
            for (int sg = wv; sg < 32; sg += 4) {
                int f = sg * 4 + l4;
                gl2lds16(g + (size_t)f * 128 + (l15 ^ (f & 7)) * 8, wdst + sg * 1024);
            }
        }
        unsigned char* wcur = wt0 + cur * 32768;
        int ky = tap / 3, kx = tap % 3;
        int rbase = (wm + ky) * 16896;
#pragma unroll
        for (int ks = 0; ks < 4; ++ks) {
            bf16x8 a[4], b[4];
#pragma unroll
            for (int m = 0; m < 4; ++m) {
                int xp = m * 16 + pl + kx;
                a[m] = *(const bf16x8*)(inT + rbase + (size_t)xp * 256 +
                                        ((ks * 64 + kg * 16) ^ ((xp & 7) << 4)));
            }
#pragma unroll
            for (int n = 0; n < 4; ++n) {
                int row = wn * 64 + n * 16 + pl;
                b[n] = *(const bf16x8*)(wcur + (size_t)row * 256 +
                                        ((ks * 64 + kg * 16) ^ ((pl & 7) << 4)));
            }
#pragma unroll
            for (int m = 0; m < 4; ++m)
#pragma unroll
                for (int n = 0; n < 4; ++n)
                    acc[m][n] = __builtin_amdgcn_mfma_f32_16x16x32_bf16(a[m], b[n], acc[m][n], 0, 0, 0);
        }
        __syncthreads();
        cur ^= 1;
    }
    unsigned short* o = tout + ((size_t)fi * HW + (size_t)(y0 + wm) * 64) * 128;
#pragma unroll
    for (int m = 0; m < 4; ++m)
#pragma unroll
        for (int n = 0; n < 4; ++n) {
            int f = wn * 64 + n * 16 + pl;
            float bs = bias[f];
#pragma unroll
            for (int r = 0; r < 4; ++r) {
                int x = m * 16 + (lane >> 4) * 4 + r;
                o[(size_t)x * 128 + f] = bf16c(gelu_f(acc[m][n][r] + bs));
            }
        }
}

// ===========================================================================
// 1x1 (128->128) + gelu + fused LN partial stats. out t2 bf16 + lnpart.
// ===========================================================================
__global__ __launch_bounds__(256) void k_fc128s(const unsigned short* __restrict__ tin,
                                                const unsigned short* __restrict__ wt,
                                                const float* __restrict__ bias,
                                                unsigned short* __restrict__ outp,
                                                float* __restrict__ lnpart) {
    __shared__ __align__(16) unsigned char smm[65536];
    __shared__ float redS[4][64], redQ[4][64];
    unsigned char* inL = smm;
    unsigned char* wL = smm + 32768;
    int blk = blockIdx.x;
    int fi = blk >> 5;
    int slab = blk & 31;
    int p0 = slab * 128;
    int t = threadIdx.x, lane = t & 63, wv = t >> 6;
    int l4 = lane >> 4, l15 = lane & 15;
    const unsigned short* g = tin + ((size_t)fi * HW + p0) * 128;
    for (int sg = wv; sg < 32; sg += 4) {
        int r = sg * 4 + l4;
        gl2lds16(g + (size_t)r * 128 + (l15 ^ (r & 7)) * 8, inL + sg * 1024);
    }
    for (int sg = wv; sg < 32; sg += 4) {
        int r = sg * 4 + l4;
        gl2lds16(wt + (size_t)r * 128 + (l15 ^ (r & 7)) * 8, wL + sg * 1024);
    }
    __syncthreads();
    int wm = wv & 1, wn = wv >> 1;
    f32x4 acc[4][4];
#pragma unroll
    for (int m = 0; m < 4; ++m)
#pragma unroll
        for (int n = 0; n < 4; ++n) acc[m][n] = (f32x4)0.f;
    int kg = lane >> 4, pl = lane & 15;
#pragma unroll
    for (int ks = 0; ks < 4; ++ks) {
        bf16x8 a[4], b[4];
#pragma unroll
        for (int m = 0; m < 4; ++m) {
            int row = wm * 64 + m * 16 + pl;
            a[m] = *(const bf16x8*)(inL + (size_t)row * 256 +
                                    ((ks * 64 + kg * 16) ^ ((pl & 7) << 4)));
        }
#pragma unroll
        for (int n = 0; n < 4; ++n) {
            int row = wn * 64 + n * 16 + pl;
            b[n] = *(const bf16x8*)(wL + (size_t)row * 256 +
                                    ((ks * 64 + kg * 16) ^ ((pl & 7) << 4)));
        }
#pragma unroll
        for (int m = 0; m < 4; ++m)
#pragma unroll
            for (int n = 0; n < 4; ++n)
                acc[m][n] = __builtin_amdgcn_mfma_f32_16x16x32_bf16(a[m], b[n], acc[m][n], 0, 0, 0);
    }
    unsigned short* o = outp + ((size_t)fi * HW + p0) * 128;
#pragma unroll
    for (int n = 0; n < 4; ++n) {
        int f = wn * 64 + n * 16 + pl;
        float bs = bias[f];
        float s = 0.f, q = 0.f;
#pragma unroll
        for (int m = 0; m < 4; ++m)
#pragma unroll
            for (int r = 0; r < 4; ++r) {
                float v = gelu_f(acc[m][n][r] + bs);
                int x = wm * 64 + m * 16 + kg * 4 + r;
                o[(size_t)x * 128 + f] = bf16c(v);
                s += v;
                q += v * v;
            }
        s += __shfl_xor(s, 16); s += __shfl_xor(s, 32);
        q += __shfl_xor(q, 16); q += __shfl_xor(q, 32);
        if (kg == 0) { redS[wv][n * 16 + pl] = s; redQ[wv][n * 16 + pl] = q; }
    }
    __syncthreads();
    if (t < 128) {
        int wnn = t >> 6, j = t & 63;
        float s = redS[wnn * 2][j] + redS[wnn * 2 + 1][j];
        float q = redQ[wnn * 2][j] + redQ[wnn * 2 + 1][j];
        float* lp = lnpart + ((size_t)(fi * 32 + slab) * 128 + t) * 2;
        lp[0] = s;
        lp[1] = q;
    }
}

// ===========================================================================
// LN finalize (reduce 32 slab partials) + apply: y += LN(t2)*w + b. t2 bf16.
// ===========================================================================
__global__ __launch_bounds__(256) void k_lnapply2(const unsigned short* __restrict__ t2,
                                                  const float* __restrict__ lnpart,
                                                  const float* __restrict__ w,
                                                  const float* __restrict__ b,
                                                  float* __restrict__ y) {
    __shared__ float sm_m[128], sm_r[128];
    int blk = blockIdx.x;
    int fi = blk >> 5, p0 = (blk & 31) * 128;
    int t = threadIdx.x;
    if (t < 128) {
        float s = 0.f, q = 0.f;
        for (int sl = 0; sl < 32; ++sl) {
            const float* lp = lnpart + ((size_t)(fi * 32 + sl) * 128 + t) * 2;
            s += lp[0];
            q += lp[1];
        }
        float m = s * (1.f / 4096.f);
        float var = q * (1.f / 4096.f) - m * m;
        sm_m[t] = m;
        sm_r[t] = rsqrtf(var + 1e-5f);
    }
    __syncthreads();
    int f = t & 127, ph = t >> 7;
    for (int k = ph; k < 128; k += 2) {
        int p = p0 + k;
        size_t idx = ((size_t)fi * HW + p) * 128 + f;
        float v = bf2f(t2[idx]);
        y[idx] += (v - sm_m[f]) * sm_r[f] * w[p] + b[p];
    }
}

// ===========================================================================
// 1x1 cout (128->64), MFMA, A=weights -> channel-planar fp32 out. Swizzled.
// ===========================================================================
__global__ __launch_bounds__(256) void k_coutm(const float* __restrict__ yin,
                                               const unsigned short* __restrict__ wt,
                                               const float* __restrict__ bias,
                                               float* __restrict__ outp) {
    __shared__ __align__(16) unsigned char smm[49152];
    unsigned char* inL = smm;
    unsigned char* wL = smm + 32768;
    int blk = blockIdx.x;
    int fi = blk >> 5;
    int p0 = (blk & 31) * 128;
    int t = threadIdx.x, lane = t & 63, wv = t >> 6;
    int l4 = lane >> 4, l15 = lane & 15;
    for (int sg = wv; sg < 16; sg += 4) {
        int r = sg * 4 + l4;
        gl2lds16(wt + (size_t)r * 128 + (l15 ^ (r & 7)) * 8, wL + sg * 1024);
    }
    const float* src = yin + ((size_t)fi * HW + p0) * 128;
    for (int q = t; q < 4096; q += 256) {
        int pos = q >> 5, c4 = q & 31;
        float4 v = *(const float4*)(src + (size_t)q * 4);
        ushort4 h;
        h.x = bf16c(v.x); h.y = bf16c(v.y); h.z = bf16c(v.z); h.w = bf16c(v.w);
        *(ushort4*)(inL + (size_t)pos * 256 + ((c4 * 8) ^ ((pos & 7) << 4))) = h;
    }
    __syncthreads();
    int wm = wv & 1, wn = wv >> 1;
    f32x4 acc[2][4];
#pragma unroll
    for (int m = 0; m < 2; ++m)
#pragma unroll
        for (int n = 0; n < 4; ++n) acc[m][n] = (f32x4)0.f;
    int kg = lane >> 4, pl = lane & 15;
#pragma unroll
    for (int ks = 0; ks < 4; ++ks) {
        bf16x8 a[2], b[4];
#pragma unroll
        for (int m = 0; m < 2; ++m) {
            int row = wm * 32 + m * 16 + pl;
            a[m] = *(const bf16x8*)(wL + (size_t)row * 256 +
                                    ((ks * 64 + kg * 16) ^ ((pl & 7) << 4)));
        }
#pragma unroll
        for (int n = 0; n < 4; ++n) {
            int row = wn * 64 + n * 16 + pl;
            b[n] = *(const bf16x8*)(inL + (size_t)row * 256 +
                                    ((ks * 64 + kg * 16) ^ ((pl & 7) << 4)));
        }
#pragma unroll
        for (int m = 0; m < 2; ++m)
#pragma unroll
            for (int n = 0; n < 4; ++n)
                acc[m][n] = __builtin_amdgcn_mfma_f32_16x16x32_bf16(a[m], b[n], acc[m][n], 0, 0, 0);
    }
#pragma unroll
    for (int m = 0; m < 2; ++m)
#pragma unroll
        for (int n = 0; n < 4; ++n) {
            int pos = p0 + wn * 64 + n * 16 + pl;
#pragma unroll
            for (int r = 0; r < 4; ++r) {
                int c = wm * 32 + m * 16 + (lane >> 4) * 4 + r;
                outp[((size_t)fi * 64 + c) * HW + pos] = acc[m][n][r] + bias[c];
            }
        }
}

// ===========================================================================
extern "C" void kernel_launch(void* const* d_in, const int* in_sizes, int n_in,
                              void* d_out, int out_size, void* d_ws, size_t ws_size,
                              hipStream_t stream) {
    (void)in_sizes; (void)n_in; (void)out_size;
    const float* x_in  = (const float*)d_in[0];
    const float* pl    = (const float*)d_in[1];
    const float* pBw_r = (const float*)d_in[2];
    const float* pBw_i = (const float*)d_in[3];
    const float* pBb_r = (const float*)d_in[4];
    const float* pBb_i = (const float*)d_in[5];
    const float* pCw_r = (const float*)d_in[6];
    const float* pCw_i = (const float*)d_in[7];
    const float* pCb_r = (const float*)d_in[8];
    const float* pCb_i = (const float*)d_in[9];
    const float* lruw  = (const float*)d_in[10];
    const float* lrub  = (const float*)d_in[11];
    const float* cinw  = (const float*)d_in[12];
    const float* cinb  = (const float*)d_in[13];
    const float* h3w   = (const float*)d_in[14];
    const float* h3b   = (const float*)d_in[15];
    const float* h1w   = (const float*)d_in[16];
    const float* h1b   = (const float*)d_in[17];
    const float* hlnw  = (const float*)d_in[18];
    const float* hlnb  = (const float*)d_in[19];
    const float* coutw = (const float*)d_in[20];
    const float* coutb = (const float*)d_in[21];
    const float* flnw  = (const float*)d_in[22];
    const float* flnb  = (const float*)d_in[23];
    float* out = (float*)d_out;

    // --- adaptive chunk tier: FR = FFN frames/chunk, LB = LRU batches/chunk ---
    int FR = 8, LB = 1;
    {
        const int frs[6] = {64, 32, 16, 16, 8, 8};
        const int lbs[6] = {4, 4, 4, 2, 2, 1};
        for (int k = 0; k < 6; ++k) {
            size_t region = (size_t)lbs[k] * 33554432ULL;
            size_t ffn = (size_t)frs[k] * 5767168ULL;
            if (ffn > region) region = ffn;
            size_t needb = region + 1540096ULL + (size_t)frs[k] * 32768ULL + 65536ULL;
            if (needb <= ws_size) { FR = frs[k]; LB = lbs[k]; break; }
        }
    }
    size_t region = (size_t)LB * 33554432ULL;
    {
        size_t ffn = (size_t)FR * 5767168ULL;
        if (ffn > region) region = ffn;
    }
    unsigned char* ws = (unsigned char*)d_ws;
    // FFN-phase region layout (shares bytes with LRU cbuf):
    float2* cbuf = (float2*)ws;
    float* ybuf = (float*)ws;                                           // FR*2 MiB
    unsigned short* t2bf = (unsigned short*)(ws + (size_t)FR * 2097152); // FR*1 MiB
    unsigned short* tb   = (unsigned short*)(ws + (size_t)FR * 3145728); // FR*1 MiB
    unsigned short* xT   = (unsigned short*)(ws + (size_t)FR * 4194304); // FR*0.5 MiB
    float* cobuf         = (float*)(ws + (size_t)FR * 4718592);          // FR*1 MiB
    // weights / small
    unsigned char* wbase = ws + region;
    unsigned short* wb7  = (unsigned short*)(wbase);              //   802,816 B
    unsigned short* wb3  = (unsigned short*)(wbase + 802816);     //   589,824 B
    unsigned short* wb1  = (unsigned short*)(wbase + 1392640);    //    65,536 B
    unsigned short* wbco = (unsigned short*)(wbase + 1458176);    //    16,384 B
    float* wtc           = (float*)(wbase + 1474560);             //    65,536 B
    float* lnpart        = (float*)(wbase + 1540096);             // FR*32,768 B

    const int NCl = 4 / LB;       // LRU chunks
    const int NCf = 64 / FR;      // FFN chunks

    for (int i = 0; i < NBLK; ++i) {
        const float* xsrc = (i == 0) ? x_in : out;

        // ---------------- ConvLRULayer (half-domain DFT along h) ----------
        k_transpose_w4<<<64, 256, 0, stream>>>(pBw_r + (size_t)i * 4096,
                                               pBw_i + (size_t)i * 4096,
                                               pCw_r + (size_t)i * 4096,
                                               pCw_i + (size_t)i * 4096, wtc);
        for (int cc = 0; cc < NCl; ++cc) {
            size_t boff = (size_t)cc * LB * 4194304;   // floats
            k_dfth<<<LB * 1024, 256, 0, stream>>>(xsrc + boff, (float*)cbuf);
            k_cmix<<<LB * 1024, 256, 0, stream>>>(cbuf, cbuf, wtc, wtc + 4096,
                                                  pBb_r + (size_t)i * 64,
                                                  pBb_i + (size_t)i * 64,
                                                  pl + (size_t)i * 12288 + 8192, 1);
            k_scan<<<LB * 1024, 256, 0, stream>>>(cbuf, pl + (size_t)i * 12288);
            k_cmix<<<LB * 1024, 256, 0, stream>>>(cbuf, cbuf, wtc + 8192, wtc + 12288,
                                                  nullptr, nullptr, nullptr, 0);
            k_idfth_ln<<<LB * 1024, 256, 0, stream>>>(cbuf, pCb_r + (size_t)i * 64,
                                                      lruw + (size_t)i * 4096,
                                                      lrub + (size_t)i * 4096,
                                                      xsrc + boff, out + boff);
        }

        // ---------------- FFN weight prep ----------------
        k_prep7<<<1568, 256, 0, stream>>>(cinw + (size_t)i * 401408, wb7);
        k_prep3<<<1152, 256, 0, stream>>>(h3w + (size_t)i * 2 * 147456, wb3, 2);
        k_prepcvt<<<128, 256, 0, stream>>>(h1w + (size_t)i * 2 * 16384, wb1, 32768);
        k_prepcvt<<<32, 256, 0, stream>>>(coutw + (size_t)i * 8192, wbco, 8192);

        // ---------------- FeedForward (FR-frame chunks) ----------------
        for (int cc = 0; cc < NCf; ++cc) {
            float* xb = out + (size_t)cc * FR * 262144;
            k_t2p<<<FR * 64, 256, 0, stream>>>(xb, xT);
            k_conv7m<<<FR * 32, 256, 0, stream>>>(xT, wb7, cinb + (size_t)i * 128, ybuf);
            for (int j = 0; j < NHEAD; ++j) {
                k_conv3m<<<FR * 32, 256, 0, stream>>>(ybuf, wb3 + (size_t)j * 147456,
                                                      h3b + (size_t)(i * 2 + j) * 128, tb);
                k_fc128s<<<FR * 32, 256, 0, stream>>>(tb, wb1 + (size_t)j * 16384,
                                                      h1b + (size_t)(i * 2 + j) * 128,
                                                      t2bf, lnpart);
                k_lnapply2<<<FR * 32, 256, 0, stream>>>(t2bf, lnpart,
                                                        hlnw + (size_t)(i * 2 + j) * 4096,
                                                        hlnb + (size_t)(i * 2 + j) * 4096,
                                                        ybuf);
            }
            k_coutm<<<FR * 32, 256, 0, stream>>>(ybuf, wbco, coutb + (size_t)i * 64, cobuf);
            k_ln_res<<<FR * 64, 256, 0, stream>>>(cobuf, flnw + (size_t)i * 4096,
                                                  flnb + (size_t)i * 4096, xb);
        }
    }
}

// Round 6
// 3044.525 us; speedup vs baseline: 7.0844x; 1.1593x over previous
//
#include <hip/hip_runtime.h>
#include <math.h>

// Problem dims
static constexpr int Bd = 4, Ld = 16, Cd = 64, Hd = 64, Wd = 64, Fd = 128;
static constexpr int NBLK = 2, NHEAD = 2;
static constexpr int HW = 4096;                 // Hd*Wd
static constexpr float TWO_PI = 6.28318530717958647692f;

typedef __attribute__((ext_vector_type(8))) short bf16x8;
typedef __attribute__((ext_vector_type(4))) float f32x4;
typedef __attribute__((ext_vector_type(4))) unsigned int u32x4;

__device__ __forceinline__ float gelu_f(float v) {
    return 0.5f * v * (1.f + erff(v * 0.7071067811865476f));
}

__device__ __forceinline__ unsigned short bf16c(float f) {
    unsigned int u = __float_as_uint(f);
    unsigned int r = (u + 0x7fffu + ((u >> 16) & 1u)) >> 16;
    return (unsigned short)r;
}
__device__ __forceinline__ float bf2f(unsigned short u) {
    return __uint_as_float((unsigned int)u << 16);
}
__device__ __forceinline__ bf16x8 bneg(bf16x8 v) {
    u32x4 u = *(u32x4*)&v;
    u = u ^ 0x80008000u;
    return *(bf16x8*)&u;
}

// async global->LDS, 16 bytes per lane. lds dest = wave-uniform base + lane*16.
__device__ __forceinline__ void gl2lds16(const void* g, void* l) {
    __builtin_amdgcn_global_load_lds(
        (const __attribute__((address_space(1))) void*)g,
        (__attribute__((address_space(3))) void*)l, 16, 0, 0);
}

// ===========================================================================
// Prep: bf16 DFT twiddle tables (once per launch).
// tcb[fh][h]=cos(th), tsb[fh][h]=-sin(th); tic[h][fh]=cos/64, tis[h][fh]=-sin/64
// ===========================================================================
__global__ void k_prepdft(unsigned short* __restrict__ o) {
    int idx = blockIdx.x * 256 + threadIdx.x;
    if (idx >= 16384) return;
    int sec = idx >> 12, j = idx & 4095;
    int a = j >> 6, b = j & 63;
    float ang = (TWO_PI / 64.f) * (float)((a * b) & 63);
    float sv, cv;
    __sincosf(ang, &sv, &cv);
    float v;
    if (sec == 0) v = cv;
    else if (sec == 1) v = -sv;
    else if (sec == 2) v = cv * (1.f / 64.f);
    else v = -sv * (1.f / 64.f);
    o[idx] = bf16c(v);
}

// ===========================================================================
// Prep per model-block: bf16 Bw/Cw (r,i) [o][c] + gammaT fp32 [fh][o].
// wout: wBr|wBi|wCr|wCi each 4096 bf16. gamT: 4096 fp32.
// ===========================================================================
__global__ void k_preplru(const float* __restrict__ bwr, const float* __restrict__ bwi,
                          const float* __restrict__ cwr, const float* __restrict__ cwi,
                          const float* __restrict__ gl,
                          unsigned short* __restrict__ wout, float* __restrict__ gamT) {
    int idx = blockIdx.x * 256 + threadIdx.x;
    if (idx < 16384) {
        int sec = idx >> 12, j = idx & 4095;
        const float* s = (sec == 0) ? bwr : (sec == 1) ? bwi : (sec == 2) ? cwr : cwi;
        wout[idx] = bf16c(s[j]);
    } else if (idx < 20480) {
        int j = idx - 16384;
        int fh = j >> 6, o2 = j & 63;
        gamT[j] = __expf(gl[o2 * 64 + fh]);
    }
}

// ===========================================================================
// DFT over h, MFMA. x: [l][c][h][w] fp32 -> X: [l][w][fh][c] complex fp32.
// Block = (frame fi, wg of 4 w). A = twiddle rows [fh][h], B = xT rows
// [(w,c)][h] (transposed staging, b16 writes conflict-free).
// ===========================================================================
__global__ __launch_bounds__(256) void k_dfthm(const float* __restrict__ x,
                                               float2* __restrict__ X,
                                               const unsigned short* __restrict__ tcb,
                                               const unsigned short* __restrict__ tsb) {
    __shared__ __align__(16) unsigned char smm[49152];  // xpT 32K | tC 8K | tS 8K
    unsigned char* xpT = smm;
    unsigned char* tC = smm + 32768;
    unsigned char* tS = smm + 40960;
    int blk = blockIdx.x;
    int fi = blk >> 4;
    int w0 = (blk & 15) * 4;
    int t = threadIdx.x, lane = t & 63, wv = t >> 6;
    int pl = lane & 15, kg = lane >> 4;
    int l3 = lane >> 3, l7 = lane & 7;

    // stage twiddle tables (pre-swizzled source granule)
    for (int q = 0; q < 2; ++q) {
        int sg = q * 4 + wv;
        gl2lds16(tcb + (size_t)(sg * 8 + l3) * 64 + (l7 ^ l3) * 8, tC + sg * 1024);
        gl2lds16(tsb + (size_t)(sg * 8 + l3) * 64 + (l7 ^ l3) * 8, tS + sg * 1024);
    }
    // stage x transposed: xpT[pos=(q*64+c)][h] bf16, swizzled
    const float* xf = x + (size_t)fi * Cd * HW;
    int h = t & 63;
    for (int k = 0; k < 16; ++k) {
        int c = k * 4 + (t >> 6);
        float4 v = *(const float4*)(xf + (size_t)c * HW + h * 64 + w0);
        float vv[4] = {v.x, v.y, v.z, v.w};
#pragma unroll
        for (int q = 0; q < 4; ++q) {
            int pos = q * 64 + c;
            *(unsigned short*)(xpT + pos * 128 + ((h * 2) ^ ((c & 7) << 4))) = bf16c(vv[q]);
        }
    }
    __syncthreads();

    int w = w0 + wv;
    float2* Xw = X + (size_t)fi * 262144 + (size_t)w * 4096;
    for (int half = 0; half < 2; ++half) {
        f32x4 aR[2][4], aI[2][4];
#pragma unroll
        for (int mt = 0; mt < 2; ++mt)
#pragma unroll
            for (int nt = 0; nt < 4; ++nt) { aR[mt][nt] = (f32x4)0.f; aI[mt][nt] = (f32x4)0.f; }
#pragma unroll
        for (int ks = 0; ks < 2; ++ks) {
            int koff = (ks * 64 + kg * 16);
            bf16x8 ac[2], as_[2], b[4];
#pragma unroll
            for (int mt = 0; mt < 2; ++mt) {
                int row = half * 32 + mt * 16 + pl;
                int off = row * 128 + (koff ^ ((pl & 7) << 4));
                ac[mt] = *(const bf16x8*)(tC + off);
                as_[mt] = *(const bf16x8*)(tS + off);
            }
#pragma unroll
            for (int nt = 0; nt < 4; ++nt) {
                int pos = wv * 64 + nt * 16 + pl;
                b[nt] = *(const bf16x8*)(xpT + pos * 128 + (koff ^ ((pl & 7) << 4)));
            }
#pragma unroll
            for (int mt = 0; mt < 2; ++mt)
#pragma unroll
                for (int nt = 0; nt < 4; ++nt) {
                    aR[mt][nt] = __builtin_amdgcn_mfma_f32_16x16x32_bf16(ac[mt], b[nt], aR[mt][nt], 0, 0, 0);
                    aI[mt][nt] = __builtin_amdgcn_mfma_f32_16x16x32_bf16(as_[mt], b[nt], aI[mt][nt], 0, 0, 0);
                }
        }
#pragma unroll
        for (int mt = 0; mt < 2; ++mt)
#pragma unroll
            for (int nt = 0; nt < 4; ++nt) {
                int c = nt * 16 + pl;
#pragma unroll
                for (int r = 0; r < 4; ++r) {
                    int fh = half * 32 + mt * 16 + kg * 4 + r;
                    Xw[fh * 64 + c] = make_float2(aR[mt][nt][r], aI[mt][nt][r]);
                }
            }
    }
}

// ===========================================================================
// Complex channel mix, MFMA, in-place. X rows [pos][c] (pos = w*64+fh).
// out[pos][o] = (sum_c X[pos][c] W[o][c] [+bias if w==0]) * gamma[o][fh].
// Block = 128 rows. A = X rows (bf16 r/i), B = W rows [o][c].
// ===========================================================================
__global__ __launch_bounds__(256) void k_cmixm(const float2* __restrict__ Xin,
                                               float2* __restrict__ Xout,
                                               const unsigned short* __restrict__ wr,
                                               const unsigned short* __restrict__ wi,
                                               const float* __restrict__ gamT,
                                               const float* __restrict__ br_g,
                                               const float* __restrict__ bi_g,
                                               int use_gamma) {
    __shared__ __align__(16) unsigned char smm[65536];
    unsigned char* inr = smm;                  // [128][64c] bf16, swz
    unsigned char* ini = smm + 16384;
    unsigned char* wR = smm + 32768;           // [64o][64c] bf16, swz
    unsigned char* wI = smm + 40960;
    float* gam = (float*)(smm + 49152);        // [fh][o] fp32
    int blk = blockIdx.x;
    size_t R0 = (size_t)blk * 128;
    int t = threadIdx.x, lane = t & 63, wv = t >> 6;
    int pl = lane & 15, kg = lane >> 4;
    int l3 = lane >> 3, l7 = lane & 7;

    // stage input rows (fp32 complex -> bf16 split r/i)
    for (int k = 0; k < 16; ++k) {
        int j = k * 256 + t;
        int row = j >> 5, c2 = j & 31;
        float4 v = *(const float4*)((const float*)(Xin + (R0 + row) * 64) + c2 * 4);
        unsigned int rw = (unsigned int)bf16c(v.x) | ((unsigned int)bf16c(v.z) << 16);
        unsigned int iw = (unsigned int)bf16c(v.y) | ((unsigned int)bf16c(v.w) << 16);
        int off = row * 128 + ((c2 * 4) ^ ((row & 7) << 4));
        *(unsigned int*)(inr + off) = rw;
        *(unsigned int*)(ini + off) = iw;
    }
    // stage weights
    for (int q = 0; q < 2; ++q) {
        int sg = q * 4 + wv;
        gl2lds16(wr + (size_t)(sg * 8 + l3) * 64 + (l7 ^ l3) * 8, wR + sg * 1024);
        gl2lds16(wi + (size_t)(sg * 8 + l3) * 64 + (l7 ^ l3) * 8, wI + sg * 1024);
    }
    if (use_gamma) {
        for (int j = t; j < 4096; j += 256) gam[j] = gamT[j];
    }
    __syncthreads();

    int posbase = wv * 32;
    f32x4 cR[2][4], cI[2][4];
#pragma unroll
    for (int mt = 0; mt < 2; ++mt)
#pragma unroll
        for (int nt = 0; nt < 4; ++nt) { cR[mt][nt] = (f32x4)0.f; cI[mt][nt] = (f32x4)0.f; }
#pragma unroll
    for (int ks = 0; ks < 2; ++ks) {
        int koff = ks * 64 + kg * 16;
        bf16x8 ar[2], ai[2], an[2], brf[4], bif[4];
#pragma unroll
        for (int mt = 0; mt < 2; ++mt) {
            int row = posbase + mt * 16 + pl;
            int off = row * 128 + (koff ^ ((pl & 7) << 4));
            ar[mt] = *(const bf16x8*)(inr + off);
            ai[mt] = *(const bf16x8*)(ini + off);
            an[mt] = bneg(ai[mt]);
        }
#pragma unroll
        for (int nt = 0; nt < 4; ++nt) {
            int o = nt * 16 + pl;
            int off = o * 128 + (koff ^ ((pl & 7) << 4));
            brf[nt] = *(const bf16x8*)(wR + off);
            bif[nt] = *(const bf16x8*)(wI + off);
        }
#pragma unroll
        for (int mt = 0; mt < 2; ++mt)
#pragma unroll
            for (int nt = 0; nt < 4; ++nt) {
                cR[mt][nt] = __builtin_amdgcn_mfma_f32_16x16x32_bf16(ar[mt], brf[nt], cR[mt][nt], 0, 0, 0);
                cR[mt][nt] = __builtin_amdgcn_mfma_f32_16x16x32_bf16(an[mt], bif[nt], cR[mt][nt], 0, 0, 0);
                cI[mt][nt] = __builtin_amdgcn_mfma_f32_16x16x32_bf16(ar[mt], bif[nt], cI[mt][nt], 0, 0, 0);
                cI[mt][nt] = __builtin_amdgcn_mfma_f32_16x16x32_bf16(ai[mt], brf[nt], cI[mt][nt], 0, 0, 0);
            }
    }
    int prow_base = (blk & 31) * 128 + posbase;   // within-l position
#pragma unroll
    for (int mt = 0; mt < 2; ++mt)
#pragma unroll
        for (int nt = 0; nt < 4; ++nt) {
            int o = nt * 16 + pl;
            float bR = 0.f, bI = 0.f;
            if (use_gamma) { bR = br_g[o]; bI = bi_g[o]; }
#pragma unroll
            for (int r = 0; r < 4; ++r) {
                int lrow = posbase + mt * 16 + kg * 4 + r;
                int prow = (blk & 31) * 128 + lrow;
                float vr = cR[mt][nt][r], vi = cI[mt][nt][r];
                if (use_gamma) {
                    if (prow < 64) { vr += bR; vi += bI; }
                    float g = gam[(prow & 63) * 64 + o];
                    vr *= g; vi *= g;
                }
                Xout[(R0 + lrow) * 64 + o] = make_float2(vr, vi);
            }
        }
    (void)prow_base;
}

// ===========================================================================
// Linear recurrence over L, layout [l][w][fh][c]. In-place, LB batches.
// ===========================================================================
__global__ __launch_bounds__(256) void k_scan2(float2* __restrict__ X,
                                               const float* __restrict__ pl) {
    int g = blockIdx.x * 256 + threadIdx.x;
    int c = g & 63;
    int fh = (g >> 6) & 63;
    int w = (g >> 12) & 63;
    int b = g >> 18;
    float nu = expf(pl[c * 64 + fh]);
    float th = expf(pl[4096 + c * 64 + fh]);
    float mag = expf(-nu);
    float sth, cth;
    sincosf(th, &sth, &cth);
    float lr = mag * cth, li = mag * sth;
    size_t base = (size_t)b * 16 * 262144 + (size_t)w * 4096 + fh * 64 + c;
    float2 acc = X[base];
    for (int tt = 1; tt < Ld; ++tt) {
        size_t idx = base + (size_t)tt * 262144;
        float2 v = X[idx];
        float nr = lr * acc.x - li * acc.y + v.x;
        float ni = lr * acc.y + li * acc.x + v.y;
        acc = make_float2(nr, ni);
        X[idx] = acc;
    }
}

// ===========================================================================
// Inverse DFT over h (Re only), MFMA + Cb + LayerNorm(H,W) + residual.
// Block = (frame fi, cg of 4 c). X [l][w][fh][c] -> xout channel-planar.
// ===========================================================================
__global__ __launch_bounds__(256) void k_idfthm_ln(const float2* __restrict__ X,
                                                   const unsigned short* __restrict__ tic,
                                                   const unsigned short* __restrict__ tis,
                                                   const float* __restrict__ cbr,
                                                   const float* __restrict__ lnw,
                                                   const float* __restrict__ lnb,
                                                   const float* __restrict__ xprev,
                                                   float* __restrict__ xout) {
    __shared__ __align__(16) unsigned char smm[81920];
    unsigned char* SrT = smm;                  // [pos2=(w*4+cj)][fh] bf16 swz
    unsigned char* SiT = smm + 32768;
    unsigned char* tC = smm + 65536;           // [h][fh] bf16 swz
    unsigned char* tS = smm + 73728;
    float* y4 = (float*)smm;                   // reuse after barrier: [4][64][66]+pad8
    int blk = blockIdx.x;
    int fi = blk >> 4;
    int c0 = (blk & 15) * 4;
    int t = threadIdx.x, lane = t & 63, wv = t >> 6;
    int pl = lane & 15, kg = lane >> 4;
    int l3 = lane >> 3, l7 = lane & 7;

    for (int q = 0; q < 2; ++q) {
        int sg = q * 4 + wv;
        gl2lds16(tic + (size_t)(sg * 8 + l3) * 64 + (l7 ^ l3) * 8, tC + sg * 1024);
        gl2lds16(tis + (size_t)(sg * 8 + l3) * 64 + (l7 ^ l3) * 8, tS + sg * 1024);
    }
    const float* Xf = (const float*)(X + (size_t)fi * 262144);
    int fh = t & 63;
    for (int k = 0; k < 16; ++k) {
        int w = k * 4 + (t >> 6);
        const float* p = Xf + ((size_t)w * 4096 + fh * 64 + c0) * 2;
        float4 v0 = *(const float4*)(p);
        float4 v1 = *(const float4*)(p + 4);
        float rr[4] = {v0.x, v0.z, v1.x, v1.z};
        float ii[4] = {v0.y, v0.w, v1.y, v1.w};
#pragma unroll
        for (int cj = 0; cj < 4; ++cj) {
            int pos2 = w * 4 + cj;
            int off = pos2 * 128 + ((fh * 2) ^ ((pos2 & 7) << 4));
            *(unsigned short*)(SrT + off) = bf16c(rr[cj]);
            *(unsigned short*)(SiT + off) = bf16c(ii[cj]);
        }
    }
    __syncthreads();

    f32x4 y[4][4];
#pragma unroll
    for (int mt = 0; mt < 4; ++mt)
#pragma unroll
        for (int nt = 0; nt < 4; ++nt) y[mt][nt] = (f32x4)0.f;
#pragma unroll
    for (int ks = 0; ks < 2; ++ks) {
        int koff = ks * 64 + kg * 16;
        bf16x8 ac[4], as_[4], brf[4], bif[4];
#pragma unroll
        for (int mt = 0; mt < 4; ++mt) {
            int row = mt * 16 + pl;
            int off = row * 128 + (koff ^ ((pl & 7) << 4));
            ac[mt] = *(const bf16x8*)(tC + off);
            as_[mt] = *(const bf16x8*)(tS + off);
        }
#pragma unroll
        for (int nt = 0; nt < 4; ++nt) {
            int pos2 = wv * 64 + nt * 16 + pl;
            int off = pos2 * 128 + (koff ^ ((pl & 7) << 4));
            brf[nt] = *(const bf16x8*)(SrT + off);
            bif[nt] = *(const bf16x8*)(SiT + off);
        }
#pragma unroll
        for (int mt = 0; mt < 4; ++mt)
#pragma unroll
            for (int nt = 0; nt < 4; ++nt) {
                y[mt][nt] = __builtin_amdgcn_mfma_f32_16x16x32_bf16(ac[mt], brf[nt], y[mt][nt], 0, 0, 0);
                y[mt][nt] = __builtin_amdgcn_mfma_f32_16x16x32_bf16(as_[mt], bif[nt], y[mt][nt], 0, 0, 0);
            }
    }
    __syncthreads();   // free staging LDS for y4 reuse

    float cb4[4];
#pragma unroll
    for (int cj = 0; cj < 4; ++cj) cb4[cj] = cbr[c0 + cj];
#pragma unroll
    for (int mt = 0; mt < 4; ++mt)
#pragma unroll
        for (int nt = 0; nt < 4; ++nt) {
            int pos2 = wv * 64 + nt * 16 + pl;
            int w = pos2 >> 2, cj = pos2 & 3;
#pragma unroll
            for (int r = 0; r < 4; ++r) {
                int h = mt * 16 + kg * 4 + r;
                y4[cj * 4232 + h * 66 + w] = y[mt][nt][r] + cb4[cj];
            }
        }
    __syncthreads();

    // LN per c-frame: wave wv handles cj = wv; lane = w
    int w = lane;
    const float* yp = y4 + wv * 4232;
    float s = 0.f, q = 0.f;
    for (int h = 0; h < 64; ++h) {
        float v = yp[h * 66 + w];
        s += v;
        q += v * v;
    }
#pragma unroll
    for (int off = 32; off; off >>= 1) {
        s += __shfl_xor(s, off);
        q += __shfl_xor(q, off);
    }
    float m = s * (1.f / 4096.f);
    float var = q * (1.f / 4096.f) - m * m;
    float rs = rsqrtf(var + 1e-5f);
    int c = c0 + wv;
    const float* xp = xprev + ((size_t)fi * Cd + c) * HW;
    float* xo = xout + ((size_t)fi * Cd + c) * HW;
    for (int h = 0; h < 64; ++h) {
        int p = h * 64 + w;
        xo[p] = (yp[h * 66 + w] - m) * rs * lnw[p] + lnb[p] + xp[p];
    }
}

// ===========================================================================
// LN(H,W) + residual accumulate, channel-planar (final ffn_ln)
// ===========================================================================
__global__ __launch_bounds__(256) void k_ln_res(const float* __restrict__ t_in,
                                                const float* __restrict__ w,
                                                const float* __restrict__ b,
                                                float* __restrict__ dst) {
    __shared__ float red[8];
    int fr = blockIdx.x;
    const float* src = t_in + (size_t)fr * HW;
    float* d = dst + (size_t)fr * HW;
    int t = threadIdx.x;
    float vals[16];
    float s = 0.f, sq = 0.f;
#pragma unroll
    for (int j = 0; j < 16; ++j) {
        float v = src[t + 256 * j];
        vals[j] = v;
        s += v;
        sq += v * v;
    }
    for (int off = 32; off; off >>= 1) {
        s += __shfl_down(s, off);
        sq += __shfl_down(sq, off);
    }
    int wid = t >> 6;
    if ((t & 63) == 0) { red[wid] = s; red[4 + wid] = sq; }
    __syncthreads();
    s = red[0] + red[1] + red[2] + red[3];
    sq = red[4] + red[5] + red[6] + red[7];
    float m = s * (1.f / 4096.f);
    float var = sq * (1.f / 4096.f) - m * m;
    float rs = rsqrtf(var + 1e-5f);
#pragma unroll
    for (int j = 0; j < 16; ++j) {
        int p = t + 256 * j;
        d[p] += (vals[j] - m) * rs * w[p] + b[p];
    }
}

// ===========================================================================
// Weight prep (fp32 -> bf16, MFMA-friendly layouts)
// ===========================================================================
__global__ void k_prep7(const float* __restrict__ w, unsigned short* __restrict__ o) {
    int idx = blockIdx.x * 256 + threadIdx.x;     // tap*8192 + f*64 + c
    if (idx < 49 * 128 * 64) {
        int tap = idx >> 13, rem = idx & 8191, f = rem >> 6, c = rem & 63;
        o[idx] = bf16c(w[(size_t)(f * 64 + c) * 49 + tap]);
    }
}
__global__ void k_prep3(const float* __restrict__ w, unsigned short* __restrict__ o,
                        int nh) {
    int idx = blockIdx.x * 256 + threadIdx.x;     // head*147456 + tap*16384 + f*128 + c
    if (idx < nh * 147456) {
        int head = idx / 147456;
        int rem = idx - head * 147456;
        int tap = rem >> 14, r2 = rem & 16383, f = r2 >> 7, c = r2 & 127;
        o[idx] = bf16c(w[(size_t)head * 147456 + (size_t)(f * 128 + c) * 9 + tap]);
    }
}
__global__ void k_prepcvt(const float* __restrict__ w, unsigned short* __restrict__ o, int n) {
    int idx = blockIdx.x * 256 + threadIdx.x;
    if (idx < n) o[idx] = bf16c(w[idx]);
}

// Channel-planar fp32 -> position-major bf16  ([c][HW] -> [pos][64])
__global__ __launch_bounds__(256) void k_t2p(const float* __restrict__ x,
                                             unsigned short* __restrict__ xT) {
    __shared__ float tile[64][65];
    int blk = blockIdx.x;
    int f = blk >> 6;
    int p0 = (blk & 63) * 64;
    int t = threadIdx.x;
    const float* src = x + (size_t)f * Cd * HW;
    for (int j = t; j < 4096; j += 256) {
        int c = j >> 6, p = j & 63;
        tile[c][p] = src[(size_t)c * HW + p0 + p];
    }
    __syncthreads();
    unsigned short* dst = xT + ((size_t)f * HW + p0) * 64;
    for (int j = t; j < 4096; j += 256) {
        int p = j >> 6, c = j & 63;
        dst[(size_t)p * 64 + c] = bf16c(tile[c][p]);
    }
}

// ===========================================================================
// 7x7 conv, MFMA, XOR-swizzled LDS.
// ===========================================================================
__global__ __launch_bounds__(256) void k_conv7m(const unsigned short* __restrict__ xT,
                                                const unsigned short* __restrict__ wb,
                                                const float* __restrict__ bias,
                                                float* __restrict__ yout) {
    __shared__ __align__(16) unsigned char smm[104448];   // inT 8*70*128 + 2*16384
    unsigned char* inT = smm;
    unsigned char* wt0 = smm + 71680;
    int blk = blockIdx.x;
    int fi = blk >> 5;
    int y0 = (blk & 31) * 2;
    int t = threadIdx.x, lane = t & 63, wv = t >> 6;
    int l3 = lane >> 3, l7 = lane & 7;

    const unsigned short* xf = xT + (size_t)fi * HW * 64;
    float4 z4 = make_float4(0.f, 0.f, 0.f, 0.f);
    int ksw_in = l7 ^ ((3 + l3) & 7);           // xp&7 = (3 + l3)&7
    for (int idx = wv; idx < 64; idx += 4) {
        int r = idx >> 3, sg = idx & 7;
        int srow = y0 + r - 3;
        unsigned char* dst = inT + r * 8960 + 3 * 128 + sg * 1024;
        if (srow >= 0 && srow < 64) {
            gl2lds16(xf + (size_t)srow * 4096 + (sg * 8 + l3) * 64 + ksw_in * 8, dst);
        } else {
            *(float4*)(dst + lane * 16) = z4;
        }
    }
    for (int j = t; j < 8 * 6 * 8; j += 256) {
        int r = j / 48, k = j % 48;
        int xp = (k < 24) ? (k >> 3) : 67 + ((k - 24) >> 3);
        *(float4*)(inT + r * 8960 + xp * 128 + (k & 7) * 16) = z4;
    }
    int ksw_w = l7 ^ l3;
    for (int q = 0; q < 4; ++q) {
        int f = (wv * 4 + q) * 8 + l3;
        gl2lds16(wb + (size_t)f * 64 + ksw_w * 8, wt0 + (wv * 4 + q) * 1024);
    }
    __syncthreads();

    int wm = wv & 1, wn = wv >> 1;
    f32x4 acc[4][4];
#pragma unroll
    for (int m = 0; m < 4; ++m)
#pragma unroll
        for (int n = 0; n < 4; ++n) acc[m][n] = (f32x4)0.f;
    int kg = lane >> 4, pl = lane & 15;
    int cur = 0;
    for (int tap = 0; tap < 49; ++tap) {
        if (tap + 1 < 49) {
            const unsigned short* g = wb + (size_t)(tap + 1) * 8192;
            unsigned char* wdst = wt0 + (cur ^ 1) * 16384;
            for (int q = 0; q < 4; ++q) {
                int f = (wv * 4 + q) * 8 + l3;
                gl2lds16(g + (size_t)f * 64 + ksw_w * 8, wdst + (wv * 4 + q) * 1024);
            }
        }
        unsigned char* wcur = wt0 + cur * 16384;
        int ky = tap / 7, kx = tap % 7;
        int rbase = (wm + ky) * 8960;
#pragma unroll
        for (int ks = 0; ks < 2; ++ks) {
            bf16x8 a[4], b[4];
#pragma unroll
            for (int m = 0; m < 4; ++m) {
                int xp = m * 16 + pl + kx;
                a[m] = *(const bf16x8*)(inT + rbase + xp * 128 +
                                        (((ks * 4 + kg) ^ (xp & 7)) << 4));
            }
#pragma unroll
            for (int n = 0; n < 4; ++n) {
                int row = wn * 64 + n * 16 + pl;
                b[n] = *(const bf16x8*)(wcur + row * 128 +
                                        (((ks * 4 + kg) ^ (pl & 7)) << 4));
            }
#pragma unroll
            for (int m = 0; m < 4; ++m)
#pragma unroll
                for (int n = 0; n < 4; ++n)
                    acc[m][n] = __builtin_amdgcn_mfma_f32_16x16x32_bf16(a[m], b[n], acc[m][n], 0, 0, 0);
        }
        __syncthreads();
        cur ^= 1;
    }
    float* yo = yout + ((size_t)fi * HW + (size_t)(y0 + wm) * 64) * 128;
#pragma unroll
    for (int m = 0; m < 4; ++m)
#pragma unroll
        for (int n = 0; n < 4; ++n) {
            int f = wn * 64 + n * 16 + pl;
            float bs = bias[f];
#pragma unroll
            for (int r = 0; r < 4; ++r) {
                int x = m * 16 + (lane >> 4) * 4 + r;
                yo[(size_t)x * 128 + f] = gelu_f(acc[m][n][r] + bs);
            }
        }
}

// ===========================================================================
// 3x3 conv, MFMA, swizzled.
// ===========================================================================
__global__ __launch_bounds__(256) void k_conv3m(const float* __restrict__ yin,
                                                const unsigned short* __restrict__ wb,
                                                const float* __restrict__ bias,
                                                unsigned short* __restrict__ tout) {
    __shared__ __align__(16) unsigned char smm[133120];   // inT 4*66*256 + 2*32768
    unsigned char* inT = smm;
    unsigned char* wt0 = smm + 67584;
    int blk = blockIdx.x;
    int fi = blk >> 5;
    int y0 = (blk & 31) * 2;
    int t = threadIdx.x, lane = t & 63, wv = t >> 6;
    int l4 = lane >> 4, l15 = lane & 15;
    const float* yf = yin + (size_t)fi * HW * 128;
    float4 z4 = make_float4(0.f, 0.f, 0.f, 0.f);
    for (int r = 0; r < 4; ++r) {
        int srow = y0 + r - 1;
        bool valid = (srow >= 0 && srow < 64);
        const float* rsrc = yf + (size_t)(valid ? srow : 0) * 64 * 128;
        for (int q = t; q < 2048; q += 256) {
            int x = q >> 5, c4 = q & 31;
            int xp = x + 1;
            float4 v = valid ? *(const float4*)(rsrc + (size_t)x * 128 + c4 * 4) : z4;
            ushort4 h;
            h.x = bf16c(v.x); h.y = bf16c(v.y); h.z = bf16c(v.z); h.w = bf16c(v.w);
            *(ushort4*)(inT + (size_t)(r * 66 + xp) * 256 +
                        ((c4 * 8) ^ ((xp & 7) << 4))) = h;
        }
    }
    for (int j = t; j < 128; j += 256) {
        int r = j >> 5, k = j & 31;
        int xp = (k < 16) ? 0 : 65;
        *(float4*)(inT + (size_t)(r * 66 + xp) * 256 + (k & 15) * 16) = z4;
    }
    for (int sg = wv; sg < 32; sg += 4) {
        int f = sg * 4 + l4;
        gl2lds16(wb + (size_t)f * 128 + (l15 ^ (f & 7)) * 8, wt0 + sg * 1024);
    }
    __syncthreads();

    int wm = wv & 1, wn = wv >> 1;
    f32x4 acc[4][4];
#pragma unroll
    for (int m = 0; m < 4; ++m)
#pragma unroll
        for (int n = 0; n < 4; ++n) acc[m][n] = (f32x4)0.f;
    int kg = lane >> 4, pl = lane & 15;
    int cur = 0;
    for (int tap = 0; tap < 9; ++tap) {
        if (tap + 1 < 9) {
            const unsigned short* g = wb + (size_t)(tap + 1) * 16384;
            unsigned char* wdst = wt0 + (cur ^ 1) * 32768;
            for (int sg = wv; sg < 32; sg += 4) {
                int f = sg * 4 + l4;
                gl2lds16(g + (size_t)f * 128 + (l15 ^ (f & 7)) * 8, wdst + sg * 1024);
            }
        }
        unsigned char* wcur = wt0 + cur * 32768;
        int ky = tap / 3, kx = tap % 3;
        int rbase = (wm + ky) * 16896;
#pragma unroll
        for (int ks = 0; ks < 4; ++ks) {
            bf16x8 a[4], b[4];
#pragma unroll
            for (int m = 0; m < 4; ++m) {
                int xp = m * 16 + pl + kx;
                a[m] = *(const bf16x8*)(inT + rbase + (size_t)xp * 256 +
                                        ((ks * 64 + kg * 16) ^ ((xp & 7) << 4)));
            }
#pragma unroll
            for (int n = 0; n < 4; ++n) {
                int row = wn * 64 + n * 16 + pl;
                b[n] = *(const bf16x8*)(wcur + (size_t)row * 256 +
                                        ((ks * 64 + kg * 16) ^ ((pl & 7) << 4)));
            }
#pragma unroll
            for (int m = 0; m < 4; ++m)
#pragma unroll
                for (int n = 0; n < 4; ++n)
                    acc[m][n] = __builtin_amdgcn_mfma_f32_16x16x32_bf16(a[m], b[n], acc[m][n], 0, 0, 0);
        }
        __syncthreads();
        cur ^= 1;
    }
    unsigned short* o = tout + ((size_t)fi * HW + (size_t)(y0 + wm) * 64) * 128;
#pragma unroll
    for (int m = 0; m < 4; ++m)
#pragma unroll
        for (int n = 0; n < 4; ++n) {
            int f = wn * 64 + n * 16 + pl;
            float bs = bias[f];
#pragma unroll
            for (int r = 0; r < 4; ++r) {
                int x = m * 16 + (lane >> 4) * 4 + r;
                o[(size_t)x * 128 + f] = bf16c(gelu_f(acc[m][n][r] + bs));
            }
        }
}

// ===========================================================================
// 1x1 (128->128) + gelu + fused LN partial stats. out t2 bf16 + lnpart.
// ===========================================================================
__global__ __launch_bounds__(256) void k_fc128s(const unsigned short* __restrict__ tin,
                                                const unsigned short* __restrict__ wt,
                                                const float* __restrict__ bias,
                                                unsigned short* __restrict__ outp,
                                                float* __restrict__ lnpart) {
    __shared__ __align__(16) unsigned char smm[65536];
    __shared__ float redS[4][64], redQ[4][64];
    unsigned char* inL = smm;
    unsigned char* wL = smm + 32768;
    int blk = blockIdx.x;
    int fi = blk >> 5;
    int slab = blk & 31;
    int p0 = slab * 128;
    int t = threadIdx.x, lane = t & 63, wv = t >> 6;
    int l4 = lane >> 4, l15 = lane & 15;
    const unsigned short* g = tin + ((size_t)fi * HW + p0) * 128;
    for (int sg = wv; sg < 32; sg += 4) {
        int r = sg * 4 + l4;
        gl2lds16(g + (size_t)r * 128 + (l15 ^ (r & 7)) * 8, inL + sg * 1024);
    }
    for (int sg = wv; sg < 32; sg += 4) {
        int r = sg * 4 + l4;
        gl2lds16(wt + (size_t)r * 128 + (l15 ^ (r & 7)) * 8, wL + sg * 1024);
    }
    __syncthreads();
    int wm = wv & 1, wn = wv >> 1;
    f32x4 acc[4][4];
#pragma unroll
    for (int m = 0; m < 4; ++m)
#pragma unroll
        for (int n = 0; n < 4; ++n) acc[m][n] = (f32x4)0.f;
    int kg = lane >> 4, pl = lane & 15;
#pragma unroll
    for (int ks = 0; ks < 4; ++ks) {
        bf16x8 a[4], b[4];
#pragma unroll
        for (int m = 0; m < 4; ++m) {
            int row = wm * 64 + m * 16 + pl;
            a[m] = *(const bf16x8*)(inL + (size_t)row * 256 +
                                    ((ks * 64 + kg * 16) ^ ((pl & 7) << 4)));
        }
#pragma unroll
        for (int n = 0; n < 4; ++n) {
            int row = wn * 64 + n * 16 + pl;
            b[n] = *(const bf16x8*)(wL + (size_t)row * 256 +
                                    ((ks * 64 + kg * 16) ^ ((pl & 7) << 4)));
        }
#pragma unroll
        for (int m = 0; m < 4; ++m)
#pragma unroll
            for (int n = 0; n < 4; ++n)
                acc[m][n] = __builtin_amdgcn_mfma_f32_16x16x32_bf16(a[m], b[n], acc[m][n], 0, 0, 0);
    }
    unsigned short* o = outp + ((size_t)fi * HW + p0) * 128;
#pragma unroll
    for (int n = 0; n < 4; ++n) {
        int f = wn * 64 + n * 16 + pl;
        float bs = bias[f];
        float s = 0.f, q = 0.f;
#pragma unroll
        for (int m = 0; m < 4; ++m)
#pragma unroll
            for (int r = 0; r < 4; ++r) {
                float v = gelu_f(acc[m][n][r] + bs);
                int x = wm * 64 + m * 16 + kg * 4 + r;
                o[(size_t)x * 128 + f] = bf16c(v);
                s += v;
                q += v * v;
            }
        s += __shfl_xor(s, 16); s += __shfl_xor(s, 32);
        q += __shfl_xor(q, 16); q += __shfl_xor(q, 32);
        if (kg == 0) { redS[wv][n * 16 + pl] = s; redQ[wv][n * 16 + pl] = q; }
    }
    __syncthreads();
    if (t < 128) {
        int wnn = t >> 6, j = t & 63;
        float s = redS[wnn * 2][j] + redS[wnn * 2 + 1][j];
        float q = redQ[wnn * 2][j] + redQ[wnn * 2 + 1][j];
        float* lp = lnpart + ((size_t)(fi * 32 + slab) * 128 + t) * 2;
        lp[0] = s;
        lp[1] = q;
    }
}

// ===========================================================================
// LN finalize (reduce 32 slab partials) + apply: y += LN(t2)*w + b. t2 bf16.
// ===========================================================================
__global__ __launch_bounds__(256) void k_lnapply2(const unsigned short* __restrict__ t2,
                                                  const float* __restrict__ lnpart,
                                                  const float* __restrict__ w,
                                                  const float* __restrict__ b,
                                                  float* __restrict__ y) {
    __shared__ float sm_m[128], sm_r[128];
    int blk = blockIdx.x;
    int fi = blk >> 5, p0 = (blk & 31) * 128;
    int t = threadIdx.x;
    if (t < 128) {
        float s = 0.f, q = 0.f;
        for (int sl = 0; sl < 32; ++sl) {
            const float* lp = lnpart + ((size_t)(fi * 32 + sl) * 128 + t) * 2;
            s += lp[0];
            q += lp[1];
        }
        float m = s * (1.f / 4096.f);
        float var = q * (1.f / 4096.f) - m * m;
        sm_m[t] = m;
        sm_r[t] = rsqrtf(var + 1e-5f);
    }
    __syncthreads();
    int f = t & 127, ph = t >> 7;
    for (int k = ph; k < 128; k += 2) {
        int p = p0 + k;
        size_t idx = ((size_t)fi * HW + p) * 128 + f;
        float v = bf2f(t2[idx]);
        y[idx] += (v - sm_m[f]) * sm_r[f] * w[p] + b[p];
    }
}

// ===========================================================================
// 1x1 cout (128->64), MFMA, A=weights -> channel-planar fp32 out. Swizzled.
// ===========================================================================
__global__ __launch_bounds__(256) void k_coutm(const float* __restrict__ yin,
                                               const unsigned short* __restrict__ wt,
                                               const float* __restrict__ bias,
                                               float* __restrict__ outp) {
    __shared__ __align__(16) unsigned char smm[49152];
    unsigned char* inL = smm;
    unsigned char* wL = smm + 32768;
    int blk = blockIdx.x;
    int fi = blk >> 5;
    int p0 = (blk & 31) * 128;
    int t = threadIdx.x, lane = t & 63, wv = t >> 6;
    int l4 = lane >> 4, l15 = lane & 15;
    for (int sg = wv; sg < 16; sg += 4) {
        int r = sg * 4 + l4;
        gl2lds16(wt + (size_t)r * 128 + (l15 ^ (r & 7)) * 8, wL + sg * 1024);
    }
    const float* src = yin + ((size_t)fi * HW + p0) * 128;
    for (int q = t; q < 4096; q += 256) {
        int pos = q >> 5, c4 = q & 31;
        float4 v = *(const float4*)(src + (size_t)q * 4);
        ushort4 h;
        h.x = bf16c(v.x); h.y = bf16c(v.y); h.z = bf16c(v.z); h.w = bf16c(v.w);
        *(ushort4*)(inL + (size_t)pos * 256 + ((c4 * 8) ^ ((pos & 7) << 4))) = h;
    }
    __syncthreads();
    int wm = wv & 1, wn = wv >> 1;
    f32x4 acc[2][4];
#pragma unroll
    for (int m = 0; m < 2; ++m)
#pragma unroll
        for (int n = 0; n < 4; ++n) acc[m][n] = (f32x4)0.f;
    int kg = lane >> 4, pl = lane & 15;
#pragma unroll
    for (int ks = 0; ks < 4; ++ks) {
        bf16x8 a[2], b[4];
#pragma unroll
        for (int m = 0; m < 2; ++m) {
            int row = wm * 32 + m * 16 + pl;
            a[m] = *(const bf16x8*)(wL + (size_t)row * 256 +
                                    ((ks * 64 + kg * 16) ^ ((pl & 7) << 4)));
        }
#pragma unroll
        for (int n = 0; n < 4; ++n) {
            int row = wn * 64 + n * 16 + pl;
            b[n] = *(const bf16x8*)(inL + (size_t)row * 256 +
                                    ((ks * 64 + kg * 16) ^ ((pl & 7) << 4)));
        }
#pragma unroll
        for (int m = 0; m < 2; ++m)
#pragma unroll
            for (int n = 0; n < 4; ++n)
                acc[m][n] = __builtin_amdgcn_mfma_f32_16x16x32_bf16(a[m], b[n], acc[m][n], 0, 0, 0);
    }
#pragma unroll
    for (int m = 0; m < 2; ++m)
#pragma unroll
        for (int n = 0; n < 4; ++n) {
            int pos = p0 + wn * 64 + n * 16 + pl;
#pragma unroll
            for (int r = 0; r < 4; ++r) {
                int c = wm * 32 + m * 16 + (lane >> 4) * 4 + r;
                outp[((size_t)fi * 64 + c) * HW + pos] = acc[m][n][r] + bias[c];
            }
        }
}

// ===========================================================================
extern "C" void kernel_launch(void* const* d_in, const int* in_sizes, int n_in,
                              void* d_out, int out_size, void* d_ws, size_t ws_size,
                              hipStream_t stream) {
    (void)in_sizes; (void)n_in; (void)out_size;
    const float* x_in  = (const float*)d_in[0];
    const float* pl    = (const float*)d_in[1];
    const float* pBw_r = (const float*)d_in[2];
    const float* pBw_i = (const float*)d_in[3];
    const float* pBb_r = (const float*)d_in[4];
    const float* pBb_i = (const float*)d_in[5];
    const float* pCw_r = (const float*)d_in[6];
    const float* pCw_i = (const float*)d_in[7];
    const float* pCb_r = (const float*)d_in[8];
    const float* pCb_i = (const float*)d_in[9];
    const float* lruw  = (const float*)d_in[10];
    const float* lrub  = (const float*)d_in[11];
    const float* cinw  = (const float*)d_in[12];
    const float* cinb  = (const float*)d_in[13];
    const float* h3w   = (const float*)d_in[14];
    const float* h3b   = (const float*)d_in[15];
    const float* h1w   = (const float*)d_in[16];
    const float* h1b   = (const float*)d_in[17];
    const float* hlnw  = (const float*)d_in[18];
    const float* hlnb  = (const float*)d_in[19];
    const float* coutw = (const float*)d_in[20];
    const float* coutb = (const float*)d_in[21];
    const float* flnw  = (const float*)d_in[22];
    const float* flnb  = (const float*)d_in[23];
    float* out = (float*)d_out;

    // --- adaptive chunk tier: FR = FFN frames/chunk, LB = LRU batches/chunk ---
    int FR = 8, LB = 1;
    {
        const int frs[6] = {64, 32, 16, 16, 8, 8};
        const int lbs[6] = {4, 4, 4, 2, 2, 1};
        for (int k = 0; k < 6; ++k) {
            size_t region = (size_t)lbs[k] * 33554432ULL;
            size_t ffn = (size_t)frs[k] * 5767168ULL;
            if (ffn > region) region = ffn;
            size_t needb = region + 1605632ULL + (size_t)frs[k] * 32768ULL + 65536ULL;
            if (needb <= ws_size) { FR = frs[k]; LB = lbs[k]; break; }
        }
    }
    size_t region = (size_t)LB * 33554432ULL;
    {
        size_t ffn = (size_t)FR * 5767168ULL;
        if (ffn > region) region = ffn;
    }
    unsigned char* ws = (unsigned char*)d_ws;
    // FFN-phase region layout (shares bytes with LRU X buffer):
    float2* Xb = (float2*)ws;                                           // LB*33.5 MB
    float* ybuf = (float*)ws;                                           // FR*2 MiB
    unsigned short* t2bf = (unsigned short*)(ws + (size_t)FR * 2097152); // FR*1 MiB
    unsigned short* tb   = (unsigned short*)(ws + (size_t)FR * 3145728); // FR*1 MiB
    unsigned short* xT   = (unsigned short*)(ws + (size_t)FR * 4194304); // FR*0.5 MiB
    float* cobuf         = (float*)(ws + (size_t)FR * 4718592);          // FR*1 MiB
    // weights / small
    unsigned char* wbase = ws + region;
    unsigned short* wb7  = (unsigned short*)(wbase);              //   802,816 B
    unsigned short* wb3  = (unsigned short*)(wbase + 802816);     //   589,824 B
    unsigned short* wb1  = (unsigned short*)(wbase + 1392640);    //    65,536 B
    unsigned short* wbco = (unsigned short*)(wbase + 1458176);    //    16,384 B
    unsigned short* dftT = (unsigned short*)(wbase + 1474560);    //    32,768 B
    unsigned short* lruW = (unsigned short*)(wbase + 1507328);    //    32,768 B
    float* gamT          = (float*)(wbase + 1540096);             //    16,384 B
    float* lnpart        = (float*)(wbase + 1556480);             // FR*32,768 B
    unsigned short* tcb = dftT;            // [fh][h] cos
    unsigned short* tsb = dftT + 4096;     // [fh][h] -sin
    unsigned short* tic = dftT + 8192;     // [h][fh] cos/64
    unsigned short* tis = dftT + 12288;    // [h][fh] -sin/64
    unsigned short* wBr = lruW;
    unsigned short* wBi = lruW + 4096;
    unsigned short* wCr = lruW + 8192;
    unsigned short* wCi = lruW + 12288;

    const int NCl = 4 / LB;       // LRU chunks
    const int NCf = 64 / FR;      // FFN chunks

    k_prepdft<<<64, 256, 0, stream>>>(dftT);

    for (int i = 0; i < NBLK; ++i) {
        const float* xsrc = (i == 0) ? x_in : out;

        // ---------------- ConvLRULayer (MFMA, half-domain DFT over h) -------
        k_preplru<<<80, 256, 0, stream>>>(pBw_r + (size_t)i * 4096,
                                          pBw_i + (size_t)i * 4096,
                                          pCw_r + (size_t)i * 4096,
                                          pCw_i + (size_t)i * 4096,
                                          pl + (size_t)i * 12288 + 8192, lruW, gamT);
        for (int cc = 0; cc < NCl; ++cc) {
            size_t boff = (size_t)cc * LB * 4194304;   // floats
            k_dfthm<<<LB * 256, 256, 0, stream>>>(xsrc + boff, Xb, tcb, tsb);
            k_cmixm<<<LB * 512, 256, 0, stream>>>(Xb, Xb, wBr, wBi, gamT,
                                                  pBb_r + (size_t)i * 64,
                                                  pBb_i + (size_t)i * 64, 1);
            k_scan2<<<LB * 1024, 256, 0, stream>>>(Xb, pl + (size_t)i * 12288);
            k_cmixm<<<LB * 512, 256, 0, stream>>>(Xb, Xb, wCr, wCi, nullptr,
                                                  nullptr, nullptr, 0);
            k_idfthm_ln<<<LB * 256, 256, 0, stream>>>(Xb, tic, tis,
                                                      pCb_r + (size_t)i * 64,
                                                      lruw + (size_t)i * 4096,
                                                      lrub + (size_t)i * 4096,
                                                      xsrc + boff, out + boff);
        }

        // ---------------- FFN weight prep ----------------
        k_prep7<<<1568, 256, 0, stream>>>(cinw + (size_t)i * 401408, wb7);
        k_prep3<<<1152, 256, 0, stream>>>(h3w + (size_t)i * 2 * 147456, wb3, 2);
        k_prepcvt<<<128, 256, 0, stream>>>(h1w + (size_t)i * 2 * 16384, wb1, 32768);
        k_prepcvt<<<32, 256, 0, stream>>>(coutw + (size_t)i * 8192, wbco, 8192);

        // ---------------- FeedForward (FR-frame chunks) ----------------
        for (int cc = 0; cc < NCf; ++cc) {
            float* xb = out + (size_t)cc * FR * 262144;
            k_t2p<<<FR * 64, 256, 0, stream>>>(xb, xT);
            k_conv7m<<<FR * 32, 256, 0, stream>>>(xT, wb7, cinb + (size_t)i * 128, ybuf);
            for (int j = 0; j < NHEAD; ++j) {
                k_conv3m<<<FR * 32, 256, 0, stream>>>(ybuf, wb3 + (size_t)j * 147456,
                                                      h3b + (size_t)(i * 2 + j) * 128, tb);
                k_fc128s<<<FR * 32, 256, 0, stream>>>(tb, wb1 + (size_t)j * 16384,
                                                      h1b + (size_t)(i * 2 + j) * 128,
                                                      t2bf, lnpart);
                k_lnapply2<<<FR * 32, 256, 0, stream>>>(t2bf, lnpart,
                                                        hlnw + (size_t)(i * 2 + j) * 4096,
                                                        hlnb + (size_t)(i * 2 + j) * 4096,
                                                        ybuf);
            }
            k_coutm<<<FR * 32, 256, 0, stream>>>(ybuf, wbco, coutb + (size_t)i * 64, cobuf);
            k_ln_res<<<FR * 64, 256, 0, stream>>>(cobuf, flnw + (size_t)i * 4096,
                                                  flnb + (size_t)i * 4096, xb);
        }
    }
}

// Round 7
// 2856.439 us; speedup vs baseline: 7.5509x; 1.0658x over previous
//
#include <hip/hip_runtime.h>
#include <math.h>

// Problem dims
static constexpr int Bd = 4, Ld = 16, Cd = 64, Hd = 64, Wd = 64, Fd = 128;
static constexpr int NBLK = 2, NHEAD = 2;
static constexpr int HW = 4096;                 // Hd*Wd
static constexpr float TWO_PI = 6.28318530717958647692f;

typedef __attribute__((ext_vector_type(8))) short bf16x8;
typedef __attribute__((ext_vector_type(4))) float f32x4;
typedef __attribute__((ext_vector_type(4))) unsigned int u32x4;

__device__ __forceinline__ float gelu_f(float v) {
    return 0.5f * v * (1.f + erff(v * 0.7071067811865476f));
}

__device__ __forceinline__ unsigned short bf16c(float f) {
    unsigned int u = __float_as_uint(f);
    unsigned int r = (u + 0x7fffu + ((u >> 16) & 1u)) >> 16;
    return (unsigned short)r;
}
__device__ __forceinline__ float bf2f(unsigned short u) {
    return __uint_as_float((unsigned int)u << 16);
}
__device__ __forceinline__ bf16x8 bneg(bf16x8 v) {
    u32x4 u = *(u32x4*)&v;
    u = u ^ 0x80008000u;
    return *(bf16x8*)&u;
}

// async global->LDS, 16 bytes per lane. lds dest = wave-uniform base + lane*16.
__device__ __forceinline__ void gl2lds16(const void* g, void* l) {
    __builtin_amdgcn_global_load_lds(
        (const __attribute__((address_space(1))) void*)g,
        (__attribute__((address_space(3))) void*)l, 16, 0, 0);
}

// ===========================================================================
// Prep: bf16 DFT twiddle tables (once per launch).
// ===========================================================================
__global__ void k_prepdft(unsigned short* __restrict__ o) {
    int idx = blockIdx.x * 256 + threadIdx.x;
    if (idx >= 16384) return;
    int sec = idx >> 12, j = idx & 4095;
    int a = j >> 6, b = j & 63;
    float ang = (TWO_PI / 64.f) * (float)((a * b) & 63);
    float sv, cv;
    __sincosf(ang, &sv, &cv);
    float v;
    if (sec == 0) v = cv;
    else if (sec == 1) v = -sv;
    else if (sec == 2) v = cv * (1.f / 64.f);
    else v = -sv * (1.f / 64.f);
    o[idx] = bf16c(v);
}

// ===========================================================================
// Prep per model-block: bf16 Bw/Cw (r,i) [o][c] + gammaT fp32 [fh][o].
// ===========================================================================
__global__ void k_preplru(const float* __restrict__ bwr, const float* __restrict__ bwi,
                          const float* __restrict__ cwr, const float* __restrict__ cwi,
                          const float* __restrict__ gl,
                          unsigned short* __restrict__ wout, float* __restrict__ gamT) {
    int idx = blockIdx.x * 256 + threadIdx.x;
    if (idx < 16384) {
        int sec = idx >> 12, j = idx & 4095;
        const float* s = (sec == 0) ? bwr : (sec == 1) ? bwi : (sec == 2) ? cwr : cwi;
        wout[idx] = bf16c(s[j]);
    } else if (idx < 20480) {
        int j = idx - 16384;
        int fh = j >> 6, o2 = j & 63;
        gamT[j] = __expf(gl[o2 * 64 + fh]);
    }
}

// ===========================================================================
// DFT over h, MFMA. x: [l][c][h][w] fp32 -> X: [l][w][fh][c] complex fp32.
// ===========================================================================
__global__ __launch_bounds__(256) void k_dfthm(const float* __restrict__ x,
                                               float2* __restrict__ X,
                                               const unsigned short* __restrict__ tcb,
                                               const unsigned short* __restrict__ tsb) {
    __shared__ __align__(16) unsigned char smm[49152];  // xpT 32K | tC 8K | tS 8K
    unsigned char* xpT = smm;
    unsigned char* tC = smm + 32768;
    unsigned char* tS = smm + 40960;
    int blk = blockIdx.x;
    int fi = blk >> 4;
    int w0 = (blk & 15) * 4;
    int t = threadIdx.x, lane = t & 63, wv = t >> 6;
    int pl = lane & 15, kg = lane >> 4;
    int l3 = lane >> 3, l7 = lane & 7;

    for (int q = 0; q < 2; ++q) {
        int sg = q * 4 + wv;
        gl2lds16(tcb + (size_t)(sg * 8 + l3) * 64 + (l7 ^ l3) * 8, tC + sg * 1024);
        gl2lds16(tsb + (size_t)(sg * 8 + l3) * 64 + (l7 ^ l3) * 8, tS + sg * 1024);
    }
    const float* xf = x + (size_t)fi * Cd * HW;
    int h = t & 63;
    for (int k = 0; k < 16; ++k) {
        int c = k * 4 + (t >> 6);
        float4 v = *(const float4*)(xf + (size_t)c * HW + h * 64 + w0);
        float vv[4] = {v.x, v.y, v.z, v.w};
#pragma unroll
        for (int q = 0; q < 4; ++q) {
            int pos = q * 64 + c;
            *(unsigned short*)(xpT + pos * 128 + ((h * 2) ^ ((c & 7) << 4))) = bf16c(vv[q]);
        }
    }
    __syncthreads();

    int w = w0 + wv;
    float2* Xw = X + (size_t)fi * 262144 + (size_t)w * 4096;
    for (int half = 0; half < 2; ++half) {
        f32x4 aR[2][4], aI[2][4];
#pragma unroll
        for (int mt = 0; mt < 2; ++mt)
#pragma unroll
            for (int nt = 0; nt < 4; ++nt) { aR[mt][nt] = (f32x4)0.f; aI[mt][nt] = (f32x4)0.f; }
#pragma unroll
        for (int ks = 0; ks < 2; ++ks) {
            int koff = (ks * 64 + kg * 16);
            bf16x8 ac[2], as_[2], b[4];
#pragma unroll
            for (int mt = 0; mt < 2; ++mt) {
                int row = half * 32 + mt * 16 + pl;
                int off = row * 128 + (koff ^ ((pl & 7) << 4));
                ac[mt] = *(const bf16x8*)(tC + off);
                as_[mt] = *(const bf16x8*)(tS + off);
            }
#pragma unroll
            for (int nt = 0; nt < 4; ++nt) {
                int pos = wv * 64 + nt * 16 + pl;
                b[nt] = *(const bf16x8*)(xpT + pos * 128 + (koff ^ ((pl & 7) << 4)));
            }
#pragma unroll
            for (int mt = 0; mt < 2; ++mt)
#pragma unroll
                for (int nt = 0; nt < 4; ++nt) {
                    aR[mt][nt] = __builtin_amdgcn_mfma_f32_16x16x32_bf16(ac[mt], b[nt], aR[mt][nt], 0, 0, 0);
                    aI[mt][nt] = __builtin_amdgcn_mfma_f32_16x16x32_bf16(as_[mt], b[nt], aI[mt][nt], 0, 0, 0);
                }
        }
#pragma unroll
        for (int mt = 0; mt < 2; ++mt)
#pragma unroll
            for (int nt = 0; nt < 4; ++nt) {
                int c = nt * 16 + pl;
#pragma unroll
                for (int r = 0; r < 4; ++r) {
                    int fh = half * 32 + mt * 16 + kg * 4 + r;
                    Xw[fh * 64 + c] = make_float2(aR[mt][nt][r], aI[mt][nt][r]);
                }
            }
    }
}

// ===========================================================================
// Complex channel mix, MFMA, in-place. X rows [pos][c] (pos = w*64+fh).
// ===========================================================================
__global__ __launch_bounds__(256) void k_cmixm(const float2* __restrict__ Xin,
                                               float2* __restrict__ Xout,
                                               const unsigned short* __restrict__ wr,
                                               const unsigned short* __restrict__ wi,
                                               const float* __restrict__ gamT,
                                               const float* __restrict__ br_g,
                                               const float* __restrict__ bi_g,
                                               int use_gamma) {
    __shared__ __align__(16) unsigned char smm[65536];
    unsigned char* inr = smm;
    unsigned char* ini = smm + 16384;
    unsigned char* wR = smm + 32768;
    unsigned char* wI = smm + 40960;
    float* gam = (float*)(smm + 49152);
    int blk = blockIdx.x;
    size_t R0 = (size_t)blk * 128;
    int t = threadIdx.x, lane = t & 63, wv = t >> 6;
    int pl = lane & 15, kg = lane >> 4;
    int l3 = lane >> 3, l7 = lane & 7;

    for (int k = 0; k < 16; ++k) {
        int j = k * 256 + t;
        int row = j >> 5, c2 = j & 31;
        float4 v = *(const float4*)((const float*)(Xin + (R0 + row) * 64) + c2 * 4);
        unsigned int rw = (unsigned int)bf16c(v.x) | ((unsigned int)bf16c(v.z) << 16);
        unsigned int iw = (unsigned int)bf16c(v.y) | ((unsigned int)bf16c(v.w) << 16);
        int off = row * 128 + ((c2 * 4) ^ ((row & 7) << 4));
        *(unsigned int*)(inr + off) = rw;
        *(unsigned int*)(ini + off) = iw;
    }
    for (int q = 0; q < 2; ++q) {
        int sg = q * 4 + wv;
        gl2lds16(wr + (size_t)(sg * 8 + l3) * 64 + (l7 ^ l3) * 8, wR + sg * 1024);
        gl2lds16(wi + (size_t)(sg * 8 + l3) * 64 + (l7 ^ l3) * 8, wI + sg * 1024);
    }
    if (use_gamma) {
        for (int j = t; j < 4096; j += 256) gam[j] = gamT[j];
    }
    __syncthreads();

    int posbase = wv * 32;
    f32x4 cR[2][4], cI[2][4];
#pragma unroll
    for (int mt = 0; mt < 2; ++mt)
#pragma unroll
        for (int nt = 0; nt < 4; ++nt) { cR[mt][nt] = (f32x4)0.f; cI[mt][nt] = (f32x4)0.f; }
#pragma unroll
    for (int ks = 0; ks < 2; ++ks) {
        int koff = ks * 64 + kg * 16;
        bf16x8 ar[2], ai[2], an[2], brf[4], bif[4];
#pragma unroll
        for (int mt = 0; mt < 2; ++mt) {
            int row = posbase + mt * 16 + pl;
            int off = row * 128 + (koff ^ ((pl & 7) << 4));
            ar[mt] = *(const bf16x8*)(inr + off);
            ai[mt] = *(const bf16x8*)(ini + off);
            an[mt] = bneg(ai[mt]);
        }
#pragma unroll
        for (int nt = 0; nt < 4; ++nt) {
            int o = nt * 16 + pl;
            int off = o * 128 + (koff ^ ((pl & 7) << 4));
            brf[nt] = *(const bf16x8*)(wR + off);
            bif[nt] = *(const bf16x8*)(wI + off);
        }
#pragma unroll
        for (int mt = 0; mt < 2; ++mt)
#pragma unroll
            for (int nt = 0; nt < 4; ++nt) {
                cR[mt][nt] = __builtin_amdgcn_mfma_f32_16x16x32_bf16(ar[mt], brf[nt], cR[mt][nt], 0, 0, 0);
                cR[mt][nt] = __builtin_amdgcn_mfma_f32_16x16x32_bf16(an[mt], bif[nt], cR[mt][nt], 0, 0, 0);
                cI[mt][nt] = __builtin_amdgcn_mfma_f32_16x16x32_bf16(ar[mt], bif[nt], cI[mt][nt], 0, 0, 0);
                cI[mt][nt] = __builtin_amdgcn_mfma_f32_16x16x32_bf16(ai[mt], brf[nt], cI[mt][nt], 0, 0, 0);
            }
    }
#pragma unroll
    for (int mt = 0; mt < 2; ++mt)
#pragma unroll
        for (int nt = 0; nt < 4; ++nt) {
            int o = nt * 16 + pl;
            float bR = 0.f, bI = 0.f;
            if (use_gamma) { bR = br_g[o]; bI = bi_g[o]; }
#pragma unroll
            for (int r = 0; r < 4; ++r) {
                int lrow = posbase + mt * 16 + kg * 4 + r;
                int prow = (blk & 31) * 128 + lrow;
                float vr = cR[mt][nt][r], vi = cI[mt][nt][r];
                if (use_gamma) {
                    if (prow < 64) { vr += bR; vi += bI; }
                    float g = gam[(prow & 63) * 64 + o];
                    vr *= g; vi *= g;
                }
                Xout[(R0 + lrow) * 64 + o] = make_float2(vr, vi);
            }
        }
}

// ===========================================================================
// Linear recurrence over L, layout [l][w][fh][c]. In-place, LB batches.
// ===========================================================================
__global__ __launch_bounds__(256) void k_scan2(float2* __restrict__ X,
                                               const float* __restrict__ pl) {
    int g = blockIdx.x * 256 + threadIdx.x;
    int c = g & 63;
    int fh = (g >> 6) & 63;
    int w = (g >> 12) & 63;
    int b = g >> 18;
    float nu = expf(pl[c * 64 + fh]);
    float th = expf(pl[4096 + c * 64 + fh]);
    float mag = expf(-nu);
    float sth, cth;
    sincosf(th, &sth, &cth);
    float lr = mag * cth, li = mag * sth;
    size_t base = (size_t)b * 16 * 262144 + (size_t)w * 4096 + fh * 64 + c;
    float2 acc = X[base];
    for (int tt = 1; tt < Ld; ++tt) {
        size_t idx = base + (size_t)tt * 262144;
        float2 v = X[idx];
        float nr = lr * acc.x - li * acc.y + v.x;
        float ni = lr * acc.y + li * acc.x + v.y;
        acc = make_float2(nr, ni);
        X[idx] = acc;
    }
}

// ===========================================================================
// Inverse DFT over h (Re only), MFMA + Cb + LayerNorm(H,W) + residual.
// ===========================================================================
__global__ __launch_bounds__(256) void k_idfthm_ln(const float2* __restrict__ X,
                                                   const unsigned short* __restrict__ tic,
                                                   const unsigned short* __restrict__ tis,
                                                   const float* __restrict__ cbr,
                                                   const float* __restrict__ lnw,
                                                   const float* __restrict__ lnb,
                                                   const float* __restrict__ xprev,
                                                   float* __restrict__ xout) {
    __shared__ __align__(16) unsigned char smm[81920];
    unsigned char* SrT = smm;
    unsigned char* SiT = smm + 32768;
    unsigned char* tC = smm + 65536;
    unsigned char* tS = smm + 73728;
    float* y4 = (float*)smm;
    int blk = blockIdx.x;
    int fi = blk >> 4;
    int c0 = (blk & 15) * 4;
    int t = threadIdx.x, lane = t & 63, wv = t >> 6;
    int pl = lane & 15, kg = lane >> 4;
    int l3 = lane >> 3, l7 = lane & 7;

    for (int q = 0; q < 2; ++q) {
        int sg = q * 4 + wv;
        gl2lds16(tic + (size_t)(sg * 8 + l3) * 64 + (l7 ^ l3) * 8, tC + sg * 1024);
        gl2lds16(tis + (size_t)(sg * 8 + l3) * 64 + (l7 ^ l3) * 8, tS + sg * 1024);
    }
    const float* Xf = (const float*)(X + (size_t)fi * 262144);
    int fh = t & 63;
    for (int k = 0; k < 16; ++k) {
        int w = k * 4 + (t >> 6);
        const float* p = Xf + ((size_t)w * 4096 + fh * 64 + c0) * 2;
        float4 v0 = *(const float4*)(p);
        float4 v1 = *(const float4*)(p + 4);
        float rr[4] = {v0.x, v0.z, v1.x, v1.z};
        float ii[4] = {v0.y, v0.w, v1.y, v1.w};
#pragma unroll
        for (int cj = 0; cj < 4; ++cj) {
            int pos2 = w * 4 + cj;
            int off = pos2 * 128 + ((fh * 2) ^ ((pos2 & 7) << 4));
            *(unsigned short*)(SrT + off) = bf16c(rr[cj]);
            *(unsigned short*)(SiT + off) = bf16c(ii[cj]);
        }
    }
    __syncthreads();

    f32x4 y[4][4];
#pragma unroll
    for (int mt = 0; mt < 4; ++mt)
#pragma unroll
        for (int nt = 0; nt < 4; ++nt) y[mt][nt] = (f32x4)0.f;
#pragma unroll
    for (int ks = 0; ks < 2; ++ks) {
        int koff = ks * 64 + kg * 16;
        bf16x8 ac[4], as_[4], brf[4], bif[4];
#pragma unroll
        for (int mt = 0; mt < 4; ++mt) {
            int row = mt * 16 + pl;
            int off = row * 128 + (koff ^ ((pl & 7) << 4));
            ac[mt] = *(const bf16x8*)(tC + off);
            as_[mt] = *(const bf16x8*)(tS + off);
        }
#pragma unroll
        for (int nt = 0; nt < 4; ++nt) {
            int pos2 = wv * 64 + nt * 16 + pl;
            int off = pos2 * 128 + (koff ^ ((pl & 7) << 4));
            brf[nt] = *(const bf16x8*)(SrT + off);
            bif[nt] = *(const bf16x8*)(SiT + off);
        }
#pragma unroll
        for (int mt = 0; mt < 4; ++mt)
#pragma unroll
            for (int nt = 0; nt < 4; ++nt) {
                y[mt][nt] = __builtin_amdgcn_mfma_f32_16x16x32_bf16(ac[mt], brf[nt], y[mt][nt], 0, 0, 0);
                y[mt][nt] = __builtin_amdgcn_mfma_f32_16x16x32_bf16(as_[mt], bif[nt], y[mt][nt], 0, 0, 0);
            }
    }
    __syncthreads();

    float cb4[4];
#pragma unroll
    for (int cj = 0; cj < 4; ++cj) cb4[cj] = cbr[c0 + cj];
#pragma unroll
    for (int mt = 0; mt < 4; ++mt)
#pragma unroll
        for (int nt = 0; nt < 4; ++nt) {
            int pos2 = wv * 64 + nt * 16 + pl;
            int w = pos2 >> 2, cj = pos2 & 3;
#pragma unroll
            for (int r = 0; r < 4; ++r) {
                int h = mt * 16 + kg * 4 + r;
                y4[cj * 4232 + h * 66 + w] = y[mt][nt][r] + cb4[cj];
            }
        }
    __syncthreads();

    int w = lane;
    const float* yp = y4 + wv * 4232;
    float s = 0.f, q = 0.f;
    for (int h = 0; h < 64; ++h) {
        float v = yp[h * 66 + w];
        s += v;
        q += v * v;
    }
#pragma unroll
    for (int off = 32; off; off >>= 1) {
        s += __shfl_xor(s, off);
        q += __shfl_xor(q, off);
    }
    float m = s * (1.f / 4096.f);
    float var = q * (1.f / 4096.f) - m * m;
    float rs = rsqrtf(var + 1e-5f);
    int c = c0 + wv;
    const float* xp = xprev + ((size_t)fi * Cd + c) * HW;
    float* xo = xout + ((size_t)fi * Cd + c) * HW;
    for (int h = 0; h < 64; ++h) {
        int p = h * 64 + w;
        xo[p] = (yp[h * 66 + w] - m) * rs * lnw[p] + lnb[p] + xp[p];
    }
}

// ===========================================================================
// LN(H,W) + residual accumulate, channel-planar (final ffn_ln)
// ===========================================================================
__global__ __launch_bounds__(256) void k_ln_res(const float* __restrict__ t_in,
                                                const float* __restrict__ w,
                                                const float* __restrict__ b,
                                                float* __restrict__ dst) {
    __shared__ float red[8];
    int fr = blockIdx.x;
    const float* src = t_in + (size_t)fr * HW;
    float* d = dst + (size_t)fr * HW;
    int t = threadIdx.x;
    float vals[16];
    float s = 0.f, sq = 0.f;
#pragma unroll
    for (int j = 0; j < 16; ++j) {
        float v = src[t + 256 * j];
        vals[j] = v;
        s += v;
        sq += v * v;
    }
    for (int off = 32; off; off >>= 1) {
        s += __shfl_down(s, off);
        sq += __shfl_down(sq, off);
    }
    int wid = t >> 6;
    if ((t & 63) == 0) { red[wid] = s; red[4 + wid] = sq; }
    __syncthreads();
    s = red[0] + red[1] + red[2] + red[3];
    sq = red[4] + red[5] + red[6] + red[7];
    float m = s * (1.f / 4096.f);
    float var = sq * (1.f / 4096.f) - m * m;
    float rs = rsqrtf(var + 1e-5f);
#pragma unroll
    for (int j = 0; j < 16; ++j) {
        int p = t + 256 * j;
        d[p] += (vals[j] - m) * rs * w[p] + b[p];
    }
}

// ===========================================================================
// Weight prep (fp32 -> bf16, MFMA-friendly layouts)
// ===========================================================================
__global__ void k_prep7(const float* __restrict__ w, unsigned short* __restrict__ o) {
    int idx = blockIdx.x * 256 + threadIdx.x;     // tap*8192 + f*64 + c
    if (idx < 49 * 128 * 64) {
        int tap = idx >> 13, rem = idx & 8191, f = rem >> 6, c = rem & 63;
        o[idx] = bf16c(w[(size_t)(f * 64 + c) * 49 + tap]);
    }
}
__global__ void k_prep3(const float* __restrict__ w, unsigned short* __restrict__ o,
                        int nh) {
    int idx = blockIdx.x * 256 + threadIdx.x;
    if (idx < nh * 147456) {
        int head = idx / 147456;
        int rem = idx - head * 147456;
        int tap = rem >> 14, r2 = rem & 16383, f = r2 >> 7, c = r2 & 127;
        o[idx] = bf16c(w[(size_t)head * 147456 + (size_t)(f * 128 + c) * 9 + tap]);
    }
}
__global__ void k_prepcvt(const float* __restrict__ w, unsigned short* __restrict__ o, int n) {
    int idx = blockIdx.x * 256 + threadIdx.x;
    if (idx < n) o[idx] = bf16c(w[idx]);
}

// Channel-planar fp32 -> position-major bf16  ([c][HW] -> [pos][64])
__global__ __launch_bounds__(256) void k_t2p(const float* __restrict__ x,
                                             unsigned short* __restrict__ xT) {
    __shared__ float tile[64][65];
    int blk = blockIdx.x;
    int f = blk >> 6;
    int p0 = (blk & 63) * 64;
    int t = threadIdx.x;
    const float* src = x + (size_t)f * Cd * HW;
    for (int j = t; j < 4096; j += 256) {
        int c = j >> 6, p = j & 63;
        tile[c][p] = src[(size_t)c * HW + p0 + p];
    }
    __syncthreads();
    unsigned short* dst = xT + ((size_t)f * HW + p0) * 64;
    for (int j = t; j < 4096; j += 256) {
        int p = j >> 6, c = j & 63;
        dst[(size_t)p * 64 + c] = bf16c(tile[c][p]);
    }
}

// ===========================================================================
// 7x7 conv, MFMA, XOR-swizzled LDS. 8 waves, 4 output rows/block.
// Grid FR*16 x 512 threads. LDS = inT 10*70*128 (89600) + 2*16384 = 122368.
// ===========================================================================
__global__ __launch_bounds__(512) void k_conv7m(const unsigned short* __restrict__ xT,
                                                const unsigned short* __restrict__ wb,
                                                const float* __restrict__ bias,
                                                float* __restrict__ yout) {
    __shared__ __align__(16) unsigned char smm[122368];
    unsigned char* inT = smm;
    unsigned char* wt0 = smm + 89600;
    int blk = blockIdx.x;
    int fi = blk >> 4;
    int y0 = (blk & 15) * 4;
    int t = threadIdx.x, lane = t & 63, wv = t >> 6;
    int l3 = lane >> 3, l7 = lane & 7;

    const unsigned short* xf = xT + (size_t)fi * HW * 64;
    float4 z4 = make_float4(0.f, 0.f, 0.f, 0.f);
    int ksw_in = l7 ^ ((3 + l3) & 7);           // xp&7 = (3 + l3)&7
    for (int idx = wv; idx < 80; idx += 8) {
        int r = idx >> 3, sg = idx & 7;
        int srow = y0 + r - 3;
        unsigned char* dst = inT + r * 8960 + 3 * 128 + sg * 1024;
        if (srow >= 0 && srow < 64) {
            gl2lds16(xf + (size_t)srow * 4096 + (sg * 8 + l3) * 64 + ksw_in * 8, dst);
        } else {
            *(float4*)(dst + lane * 16) = z4;
        }
    }
    // zero x-pads (full rows xp 0..2, 67..69)
    if (t < 480) {
        int r = t / 48, k = t % 48;
        int xp = (k < 24) ? (k >> 3) : 67 + ((k - 24) >> 3);
        *(float4*)(inT + r * 8960 + xp * 128 + (k & 7) * 16) = z4;
    }
    int ksw_w = l7 ^ l3;
    for (int q = 0; q < 2; ++q) {
        int sg = q * 8 + wv;
        int f = sg * 8 + l3;
        gl2lds16(wb + (size_t)f * 64 + ksw_w * 8, wt0 + sg * 1024);
    }
    __syncthreads();

    int wm = wv & 3, wn = wv >> 2;
    f32x4 acc[4][4];
#pragma unroll
    for (int m = 0; m < 4; ++m)
#pragma unroll
        for (int n = 0; n < 4; ++n) acc[m][n] = (f32x4)0.f;
    int kg = lane >> 4, pl = lane & 15;
    int cur = 0;
    for (int tap = 0; tap < 49; ++tap) {
        if (tap + 1 < 49) {
            const unsigned short* g = wb + (size_t)(tap + 1) * 8192;
            unsigned char* wdst = wt0 + (cur ^ 1) * 16384;
            for (int q = 0; q < 2; ++q) {
                int sg = q * 8 + wv;
                int f = sg * 8 + l3;
                gl2lds16(g + (size_t)f * 64 + ksw_w * 8, wdst + sg * 1024);
            }
        }
        unsigned char* wcur = wt0 + cur * 16384;
        int ky = tap / 7, kx = tap % 7;
        int rbase = (wm + ky) * 8960;
#pragma unroll
        for (int ks = 0; ks < 2; ++ks) {
            bf16x8 a[4], b[4];
#pragma unroll
            for (int m = 0; m < 4; ++m) {
                int xp = m * 16 + pl + kx;
                a[m] = *(const bf16x8*)(inT + rbase + xp * 128 +
                                        (((ks * 4 + kg) ^ (xp & 7)) << 4));
            }
#pragma unroll
            for (int n = 0; n < 4; ++n) {
                int row = wn * 64 + n * 16 + pl;
                b[n] = *(const bf16x8*)(wcur + row * 128 +
                                        (((ks * 4 + kg) ^ (pl & 7)) << 4));
            }
#pragma unroll
            for (int m = 0; m < 4; ++m)
#pragma unroll
                for (int n = 0; n < 4; ++n)
                    acc[m][n] = __builtin_amdgcn_mfma_f32_16x16x32_bf16(a[m], b[n], acc[m][n], 0, 0, 0);
        }
        __syncthreads();
        cur ^= 1;
    }
    float* yo = yout + ((size_t)fi * HW + (size_t)(y0 + wm) * 64) * 128;
#pragma unroll
    for (int m = 0; m < 4; ++m)
#pragma unroll
        for (int n = 0; n < 4; ++n) {
            int f = wn * 64 + n * 16 + pl;
            float bs = bias[f];
#pragma unroll
            for (int r = 0; r < 4; ++r) {
                int x = m * 16 + kg * 4 + r;
                yo[(size_t)x * 128 + f] = gelu_f(acc[m][n][r] + bs);
            }
        }
}

// ===========================================================================
// FUSED 3x3 conv + 1x1 (h1) + gelu + LN partials. 4 waves, 2 rows/block.
// After the tap loop the block holds t[128 pos][128 f] in accs; it is written
// to (dead) inT LDS as bf16, W1 staged alongside, then the fc GEMM runs
// in-kernel. Outputs: t2 bf16 (global) + lnpart. Replaces conv3m + fc128s.
// ===========================================================================
__global__ __launch_bounds__(256) void k_conv3f(const float* __restrict__ yin,
                                                const unsigned short* __restrict__ wb,
                                                const float* __restrict__ bias3,
                                                const unsigned short* __restrict__ w1,
                                                const float* __restrict__ bias1,
                                                unsigned short* __restrict__ outp2,
                                                float* __restrict__ lnpart) {
    __shared__ __align__(16) unsigned char smm[133120];   // inT 67584 + wt 65536
    __shared__ float redS[4][64], redQ[4][64];
    unsigned char* inT = smm;
    unsigned char* wt0 = smm + 67584;
    int blk = blockIdx.x;
    int fi = blk >> 5;
    int y0 = (blk & 31) * 2;
    int t = threadIdx.x, lane = t & 63, wv = t >> 6;
    int l4 = lane >> 4, l15 = lane & 15;
    const float* yf = yin + (size_t)fi * HW * 128;
    float4 z4 = make_float4(0.f, 0.f, 0.f, 0.f);
    for (int r = 0; r < 4; ++r) {
        int srow = y0 + r - 1;
        bool valid = (srow >= 0 && srow < 64);
        const float* rsrc = yf + (size_t)(valid ? srow : 0) * 64 * 128;
        for (int q = t; q < 2048; q += 256) {
            int x = q >> 5, c4 = q & 31;
            int xp = x + 1;
            float4 v = valid ? *(const float4*)(rsrc + (size_t)x * 128 + c4 * 4) : z4;
            ushort4 h;
            h.x = bf16c(v.x); h.y = bf16c(v.y); h.z = bf16c(v.z); h.w = bf16c(v.w);
            *(ushort4*)(inT + (size_t)(r * 66 + xp) * 256 +
                        ((c4 * 8) ^ ((xp & 7) << 4))) = h;
        }
    }
    for (int j = t; j < 128; j += 256) {
        int r = j >> 5, k = j & 31;
        int xp = (k < 16) ? 0 : 65;
        *(float4*)(inT + (size_t)(r * 66 + xp) * 256 + (k & 15) * 16) = z4;
    }
    for (int sg = wv; sg < 32; sg += 4) {
        int f = sg * 4 + l4;
        gl2lds16(wb + (size_t)f * 128 + (l15 ^ (f & 7)) * 8, wt0 + sg * 1024);
    }
    __syncthreads();

    int wm = wv & 1, wn = wv >> 1;
    f32x4 acc[4][4];
#pragma unroll
    for (int m = 0; m < 4; ++m)
#pragma unroll
        for (int n = 0; n < 4; ++n) acc[m][n] = (f32x4)0.f;
    int kg = lane >> 4, pl = lane & 15;
    int cur = 0;
    for (int tap = 0; tap < 9; ++tap) {
        if (tap + 1 < 9) {
            const unsigned short* g = wb + (size_t)(tap + 1) * 16384;
            unsigned char* wdst = wt0 + (cur ^ 1) * 32768;
            for (int sg = wv; sg < 32; sg += 4) {
                int f = sg * 4 + l4;
                gl2lds16(g + (size_t)f * 128 + (l15 ^ (f & 7)) * 8, wdst + sg * 1024);
            }
        }
        unsigned char* wcur = wt0 + cur * 32768;
        int ky = tap / 3, kx = tap % 3;
        int rbase = (wm + ky) * 16896;
#pragma unroll
        for (int ks = 0; ks < 4; ++ks) {
            bf16x8 a[4], b[4];
#pragma unroll
            for (int m = 0; m < 4; ++m) {
                int xp = m * 16 + pl + kx;
                a[m] = *(const bf16x8*)(inT + rbase + (size_t)xp * 256 +
                                        ((ks * 64 + kg * 16) ^ ((xp & 7) << 4)));
            }
#pragma unroll
            for (int n = 0; n < 4; ++n) {
                int row = wn * 64 + n * 16 + pl;
                b[n] = *(const bf16x8*)(wcur + (size_t)row * 256 +
                                        ((ks * 64 + kg * 16) ^ ((pl & 7) << 4)));
            }
#pragma unroll
            for (int m = 0; m < 4; ++m)
#pragma unroll
                for (int n = 0; n < 4; ++n)
                    acc[m][n] = __builtin_amdgcn_mfma_f32_16x16x32_bf16(a[m], b[n], acc[m][n], 0, 0, 0);
        }
        __syncthreads();
        cur ^= 1;
    }

    // ---- fused 1x1: t -> LDS (inT region is dead), stage W1, GEMM ----
    unsigned char* tL = smm;              // [128 pos][128 f] bf16, swz
    unsigned char* w1L = smm + 32768;     // [128 o][128 f] bf16, swz
#pragma unroll
    for (int m = 0; m < 4; ++m)
#pragma unroll
        for (int n = 0; n < 4; ++n) {
            int f = wn * 64 + n * 16 + pl;
            float bs = bias3[f];
#pragma unroll
            for (int r = 0; r < 4; ++r) {
                int pos = wm * 64 + m * 16 + kg * 4 + r;
                *(unsigned short*)(tL + pos * 256 +
                    ((((f >> 3) ^ (pos & 7)) << 4) | ((f & 7) * 2))) =
                    bf16c(gelu_f(acc[m][n][r] + bs));
            }
        }
    for (int sg = wv; sg < 32; sg += 4) {
        int r = sg * 4 + l4;
        gl2lds16(w1 + (size_t)r * 128 + (l15 ^ (r & 7)) * 8, w1L + sg * 1024);
    }
    __syncthreads();

    f32x4 fa[4][4];
#pragma unroll
    for (int m = 0; m < 4; ++m)
#pragma unroll
        for (int n = 0; n < 4; ++n) fa[m][n] = (f32x4)0.f;
#pragma unroll
    for (int ks = 0; ks < 4; ++ks) {
        bf16x8 a[4], b[4];
#pragma unroll
        for (int m = 0; m < 4; ++m) {
            int row = wm * 64 + m * 16 + pl;
            a[m] = *(const bf16x8*)(tL + (size_t)row * 256 +
                                    ((ks * 64 + kg * 16) ^ ((pl & 7) << 4)));
        }
#pragma unroll
        for (int n = 0; n < 4; ++n) {
            int row = wn * 64 + n * 16 + pl;
            b[n] = *(const bf16x8*)(w1L + (size_t)row * 256 +
                                    ((ks * 64 + kg * 16) ^ ((pl & 7) << 4)));
        }
#pragma unroll
        for (int m = 0; m < 4; ++m)
#pragma unroll
            for (int n = 0; n < 4; ++n)
                fa[m][n] = __builtin_amdgcn_mfma_f32_16x16x32_bf16(a[m], b[n], fa[m][n], 0, 0, 0);
    }
    int slab = blk & 31;
    int p0 = slab * 128;
    unsigned short* o = outp2 + ((size_t)fi * HW + p0) * 128;
#pragma unroll
    for (int n = 0; n < 4; ++n) {
        int f = wn * 64 + n * 16 + pl;
        float bs = bias1[f];
        float s = 0.f, q = 0.f;
#pragma unroll
        for (int m = 0; m < 4; ++m)
#pragma unroll
            for (int r = 0; r < 4; ++r) {
                float v = gelu_f(fa[m][n][r] + bs);
                int x = wm * 64 + m * 16 + kg * 4 + r;
                o[(size_t)x * 128 + f] = bf16c(v);
                s += v;
                q += v * v;
            }
        s += __shfl_xor(s, 16); s += __shfl_xor(s, 32);
        q += __shfl_xor(q, 16); q += __shfl_xor(q, 32);
        if (kg == 0) { redS[wv][n * 16 + pl] = s; redQ[wv][n * 16 + pl] = q; }
    }
    __syncthreads();
    if (t < 128) {
        int wnn = t >> 6, j = t & 63;
        float s = redS[wnn * 2][j] + redS[wnn * 2 + 1][j];
        float q = redQ[wnn * 2][j] + redQ[wnn * 2 + 1][j];
        float* lp = lnpart + ((size_t)(fi * 32 + slab) * 128 + t) * 2;
        lp[0] = s;
        lp[1] = q;
    }
}

// ===========================================================================
// LN finalize (reduce 32 slab partials) + apply: y += LN(t2)*w + b. t2 bf16.
// ===========================================================================
__global__ __launch_bounds__(256) void k_lnapply2(const unsigned short* __restrict__ t2,
                                                  const float* __restrict__ lnpart,
                                                  const float* __restrict__ w,
                                                  const float* __restrict__ b,
                                                  float* __restrict__ y) {
    __shared__ float sm_m[128], sm_r[128];
    int blk = blockIdx.x;
    int fi = blk >> 5, p0 = (blk & 31) * 128;
    int t = threadIdx.x;
    if (t < 128) {
        float s = 0.f, q = 0.f;
        for (int sl = 0; sl < 32; ++sl) {
            const float* lp = lnpart + ((size_t)(fi * 32 + sl) * 128 + t) * 2;
            s += lp[0];
            q += lp[1];
        }
        float m = s * (1.f / 4096.f);
        float var = q * (1.f / 4096.f) - m * m;
        sm_m[t] = m;
        sm_r[t] = rsqrtf(var + 1e-5f);
    }
    __syncthreads();
    int f = t & 127, ph = t >> 7;
    for (int k = ph; k < 128; k += 2) {
        int p = p0 + k;
        size_t idx = ((size_t)fi * HW + p) * 128 + f;
        float v = bf2f(t2[idx]);
        y[idx] += (v - sm_m[f]) * sm_r[f] * w[p] + b[p];
    }
}

// ===========================================================================
// 1x1 cout (128->64), MFMA, A=weights -> channel-planar fp32 out. Swizzled.
// ===========================================================================
__global__ __launch_bounds__(256) void k_coutm(const float* __restrict__ yin,
                                               const unsigned short* __restrict__ wt,
                                               const float* __restrict__ bias,
                                               float* __restrict__ outp) {
    __shared__ __align__(16) unsigned char smm[49152];
    unsigned char* inL = smm;
    unsigned char* wL = smm + 32768;
    int blk = blockIdx.x;
    int fi = blk >> 5;
    int p0 = (blk & 31) * 128;
    int t = threadIdx.x, lane = t & 63, wv = t >> 6;
    int l4 = lane >> 4, l15 = lane & 15;
    for (int sg = wv; sg < 16; sg += 4) {
        int r = sg * 4 + l4;
        gl2lds16(wt + (size_t)r * 128 + (l15 ^ (r & 7)) * 8, wL + sg * 1024);
    }
    const float* src = yin + ((size_t)fi * HW + p0) * 128;
    for (int q = t; q < 4096; q += 256) {
        int pos = q >> 5, c4 = q & 31;
        float4 v = *(const float4*)(src + (size_t)q * 4);
        ushort4 h;
        h.x = bf16c(v.x); h.y = bf16c(v.y); h.z = bf16c(v.z); h.w = bf16c(v.w);
        *(ushort4*)(inL + (size_t)pos * 256 + ((c4 * 8) ^ ((pos & 7) << 4))) = h;
    }
    __syncthreads();
    int wm = wv & 1, wn = wv >> 1;
    f32x4 acc[2][4];
#pragma unroll
    for (int m = 0; m < 2; ++m)
#pragma unroll
        for (int n = 0; n < 4; ++n) acc[m][n] = (f32x4)0.f;
    int kg = lane >> 4, pl = lane & 15;
#pragma unroll
    for (int ks = 0; ks < 4; ++ks) {
        bf16x8 a[2], b[4];
#pragma unroll
        for (int m = 0; m < 2; ++m) {
            int row = wm * 32 + m * 16 + pl;
            a[m] = *(const bf16x8*)(wL + (size_t)row * 256 +
                                    ((ks * 64 + kg * 16) ^ ((pl & 7) << 4)));
        }
#pragma unroll
        for (int n = 0; n < 4; ++n) {
            int row = wn * 64 + n * 16 + pl;
            b[n] = *(const bf16x8*)(inL + (size_t)row * 256 +
                                    ((ks * 64 + kg * 16) ^ ((pl & 7) << 4)));
        }
#pragma unroll
        for (int m = 0; m < 2; ++m)
#pragma unroll
            for (int n = 0; n < 4; ++n)
                acc[m][n] = __builtin_amdgcn_mfma_f32_16x16x32_bf16(a[m], b[n], acc[m][n], 0, 0, 0);
    }
#pragma unroll
    for (int m = 0; m < 2; ++m)
#pragma unroll
        for (int n = 0; n < 4; ++n) {
            int pos = p0 + wn * 64 + n * 16 + pl;
#pragma unroll
            for (int r = 0; r < 4; ++r) {
                int c = wm * 32 + m * 16 + (lane >> 4) * 4 + r;
                outp[((size_t)fi * 64 + c) * HW + pos] = acc[m][n][r] + bias[c];
            }
        }
}

// ===========================================================================
extern "C" void kernel_launch(void* const* d_in, const int* in_sizes, int n_in,
                              void* d_out, int out_size, void* d_ws, size_t ws_size,
                              hipStream_t stream) {
    (void)in_sizes; (void)n_in; (void)out_size;
    const float* x_in  = (const float*)d_in[0];
    const float* pl    = (const float*)d_in[1];
    const float* pBw_r = (const float*)d_in[2];
    const float* pBw_i = (const float*)d_in[3];
    const float* pBb_r = (const float*)d_in[4];
    const float* pBb_i = (const float*)d_in[5];
    const float* pCw_r = (const float*)d_in[6];
    const float* pCw_i = (const float*)d_in[7];
    const float* pCb_r = (const float*)d_in[8];
    const float* pCb_i = (const float*)d_in[9];
    const float* lruw  = (const float*)d_in[10];
    const float* lrub  = (const float*)d_in[11];
    const float* cinw  = (const float*)d_in[12];
    const float* cinb  = (const float*)d_in[13];
    const float* h3w   = (const float*)d_in[14];
    const float* h3b   = (const float*)d_in[15];
    const float* h1w   = (const float*)d_in[16];
    const float* h1b   = (const float*)d_in[17];
    const float* hlnw  = (const float*)d_in[18];
    const float* hlnb  = (const float*)d_in[19];
    const float* coutw = (const float*)d_in[20];
    const float* coutb = (const float*)d_in[21];
    const float* flnw  = (const float*)d_in[22];
    const float* flnb  = (const float*)d_in[23];
    float* out = (float*)d_out;

    // --- adaptive chunk tier: FR = FFN frames/chunk, LB = LRU batches/chunk ---
    int FR = 8, LB = 1;
    {
        const int frs[6] = {64, 32, 16, 16, 8, 8};
        const int lbs[6] = {4, 4, 4, 2, 2, 1};
        for (int k = 0; k < 6; ++k) {
            size_t region = (size_t)lbs[k] * 33554432ULL;
            size_t ffn = (size_t)frs[k] * 5767168ULL;
            if (ffn > region) region = ffn;
            size_t needb = region + 1605632ULL + (size_t)frs[k] * 32768ULL + 65536ULL;
            if (needb <= ws_size) { FR = frs[k]; LB = lbs[k]; break; }
        }
    }
    size_t region = (size_t)LB * 33554432ULL;
    {
        size_t ffn = (size_t)FR * 5767168ULL;
        if (ffn > region) region = ffn;
    }
    unsigned char* ws = (unsigned char*)d_ws;
    float2* Xb = (float2*)ws;                                           // LB*33.5 MB
    float* ybuf = (float*)ws;                                           // FR*2 MiB
    unsigned short* t2bf = (unsigned short*)(ws + (size_t)FR * 2097152); // FR*1 MiB
    unsigned short* xT   = (unsigned short*)(ws + (size_t)FR * 4194304); // FR*0.5 MiB
    float* cobuf         = (float*)(ws + (size_t)FR * 4718592);          // FR*1 MiB
    unsigned char* wbase = ws + region;
    unsigned short* wb7  = (unsigned short*)(wbase);              //   802,816 B
    unsigned short* wb3  = (unsigned short*)(wbase + 802816);     //   589,824 B
    unsigned short* wb1  = (unsigned short*)(wbase + 1392640);    //    65,536 B
    unsigned short* wbco = (unsigned short*)(wbase + 1458176);    //    16,384 B
    unsigned short* dftT = (unsigned short*)(wbase + 1474560);    //    32,768 B
    unsigned short* lruW = (unsigned short*)(wbase + 1507328);    //    32,768 B
    float* gamT          = (float*)(wbase + 1540096);             //    16,384 B
    float* lnpart        = (float*)(wbase + 1556480);             // FR*32,768 B
    unsigned short* tcb = dftT;
    unsigned short* tsb = dftT + 4096;
    unsigned short* tic = dftT + 8192;
    unsigned short* tis = dftT + 12288;
    unsigned short* wBr = lruW;
    unsigned short* wBi = lruW + 4096;
    unsigned short* wCr = lruW + 8192;
    unsigned short* wCi = lruW + 12288;

    const int NCl = 4 / LB;
    const int NCf = 64 / FR;

    k_prepdft<<<64, 256, 0, stream>>>(dftT);

    for (int i = 0; i < NBLK; ++i) {
        const float* xsrc = (i == 0) ? x_in : out;

        // ---------------- ConvLRULayer (MFMA, half-domain DFT over h) -------
        k_preplru<<<80, 256, 0, stream>>>(pBw_r + (size_t)i * 4096,
                                          pBw_i + (size_t)i * 4096,
                                          pCw_r + (size_t)i * 4096,
                                          pCw_i + (size_t)i * 4096,
                                          pl + (size_t)i * 12288 + 8192, lruW, gamT);
        for (int cc = 0; cc < NCl; ++cc) {
            size_t boff = (size_t)cc * LB * 4194304;
            k_dfthm<<<LB * 256, 256, 0, stream>>>(xsrc + boff, Xb, tcb, tsb);
            k_cmixm<<<LB * 512, 256, 0, stream>>>(Xb, Xb, wBr, wBi, gamT,
                                                  pBb_r + (size_t)i * 64,
                                                  pBb_i + (size_t)i * 64, 1);
            k_scan2<<<LB * 1024, 256, 0, stream>>>(Xb, pl + (size_t)i * 12288);
            k_cmixm<<<LB * 512, 256, 0, stream>>>(Xb, Xb, wCr, wCi, nullptr,
                                                  nullptr, nullptr, 0);
            k_idfthm_ln<<<LB * 256, 256, 0, stream>>>(Xb, tic, tis,
                                                      pCb_r + (size_t)i * 64,
                                                      lruw + (size_t)i * 4096,
                                                      lrub + (size_t)i * 4096,
                                                      xsrc + boff, out + boff);
        }

        // ---------------- FFN weight prep ----------------
        k_prep7<<<1568, 256, 0, stream>>>(cinw + (size_t)i * 401408, wb7);
        k_prep3<<<1152, 256, 0, stream>>>(h3w + (size_t)i * 2 * 147456, wb3, 2);
        k_prepcvt<<<128, 256, 0, stream>>>(h1w + (size_t)i * 2 * 16384, wb1, 32768);
        k_prepcvt<<<32, 256, 0, stream>>>(coutw + (size_t)i * 8192, wbco, 8192);

        // ---------------- FeedForward (FR-frame chunks) ----------------
        for (int cc = 0; cc < NCf; ++cc) {
            float* xb = out + (size_t)cc * FR * 262144;
            k_t2p<<<FR * 64, 256, 0, stream>>>(xb, xT);
            k_conv7m<<<FR * 16, 512, 0, stream>>>(xT, wb7, cinb + (size_t)i * 128, ybuf);
            for (int j = 0; j < NHEAD; ++j) {
                k_conv3f<<<FR * 32, 256, 0, stream>>>(ybuf, wb3 + (size_t)j * 147456,
                                                      h3b + (size_t)(i * 2 + j) * 128,
                                                      wb1 + (size_t)j * 16384,
                                                      h1b + (size_t)(i * 2 + j) * 128,
                                                      t2bf, lnpart);
                k_lnapply2<<<FR * 32, 256, 0, stream>>>(t2bf, lnpart,
                                                        hlnw + (size_t)(i * 2 + j) * 4096,
                                                        hlnb + (size_t)(i * 2 + j) * 4096,
                                                        ybuf);
            }
            k_coutm<<<FR * 32, 256, 0, stream>>>(ybuf, wbco, coutb + (size_t)i * 64, cobuf);
            k_ln_res<<<FR * 64, 256, 0, stream>>>(cobuf, flnw + (size_t)i * 4096,
                                                  flnb + (size_t)i * 4096, xb);
        }
    }
}

// Round 8
// 2035.151 us; speedup vs baseline: 10.5981x; 1.4036x over previous
//
#include <hip/hip_runtime.h>
#include <math.h>

// Problem dims
static constexpr int Bd = 4, Ld = 16, Cd = 64, Hd = 64, Wd = 64, Fd = 128;
static constexpr int NBLK = 2, NHEAD = 2;
static constexpr int HW = 4096;                 // Hd*Wd
static constexpr float TWO_PI = 6.28318530717958647692f;

typedef __attribute__((ext_vector_type(8))) short bf16x8;
typedef __attribute__((ext_vector_type(4))) float f32x4;
typedef __attribute__((ext_vector_type(4))) unsigned int u32x4;

__device__ __forceinline__ float gelu_f(float v) {
    return 0.5f * v * (1.f + erff(v * 0.7071067811865476f));
}

__device__ __forceinline__ unsigned short bf16c(float f) {
    unsigned int u = __float_as_uint(f);
    unsigned int r = (u + 0x7fffu + ((u >> 16) & 1u)) >> 16;
    return (unsigned short)r;
}
__device__ __forceinline__ float bf2f(unsigned short u) {
    return __uint_as_float((unsigned int)u << 16);
}
__device__ __forceinline__ bf16x8 bneg(bf16x8 v) {
    u32x4 u = *(u32x4*)&v;
    u = u ^ 0x80008000u;
    return *(bf16x8*)&u;
}

// async global->LDS, 16 bytes per lane. lds dest = wave-uniform base + lane*16.
__device__ __forceinline__ void gl2lds16(const void* g, void* l) {
    __builtin_amdgcn_global_load_lds(
        (const __attribute__((address_space(1))) void*)g,
        (__attribute__((address_space(3))) void*)l, 16, 0, 0);
}

// ===========================================================================
// Prep: bf16 DFT twiddle tables (once per launch).
// ===========================================================================
__global__ void k_prepdft(unsigned short* __restrict__ o) {
    int idx = blockIdx.x * 256 + threadIdx.x;
    if (idx >= 16384) return;
    int sec = idx >> 12, j = idx & 4095;
    int a = j >> 6, b = j & 63;
    float ang = (TWO_PI / 64.f) * (float)((a * b) & 63);
    float sv, cv;
    __sincosf(ang, &sv, &cv);
    float v;
    if (sec == 0) v = cv;
    else if (sec == 1) v = -sv;
    else if (sec == 2) v = cv * (1.f / 64.f);
    else v = -sv * (1.f / 64.f);
    o[idx] = bf16c(v);
}

// ===========================================================================
// Prep per model-block: bf16 Bw/Cw (r,i) [o][c] + gammaT fp32 [fh][o].
// ===========================================================================
__global__ void k_preplru(const float* __restrict__ bwr, const float* __restrict__ bwi,
                          const float* __restrict__ cwr, const float* __restrict__ cwi,
                          const float* __restrict__ gl,
                          unsigned short* __restrict__ wout, float* __restrict__ gamT) {
    int idx = blockIdx.x * 256 + threadIdx.x;
    if (idx < 16384) {
        int sec = idx >> 12, j = idx & 4095;
        const float* s = (sec == 0) ? bwr : (sec == 1) ? bwi : (sec == 2) ? cwr : cwi;
        wout[idx] = bf16c(s[j]);
    } else if (idx < 20480) {
        int j = idx - 16384;
        int fh = j >> 6, o2 = j & 63;
        gamT[j] = __expf(gl[o2 * 64 + fh]);
    }
}

// ===========================================================================
// DFT over h, MFMA. x: [l][c][h][w] fp32 -> X: [l][w][fh][c] complex fp32.
// ===========================================================================
__global__ __launch_bounds__(256) void k_dfthm(const float* __restrict__ x,
                                               float2* __restrict__ X,
                                               const unsigned short* __restrict__ tcb,
                                               const unsigned short* __restrict__ tsb) {
    __shared__ __align__(16) unsigned char smm[49152];  // xpT 32K | tC 8K | tS 8K
    unsigned char* xpT = smm;
    unsigned char* tC = smm + 32768;
    unsigned char* tS = smm + 40960;
    int blk = blockIdx.x;
    int fi = blk >> 4;
    int w0 = (blk & 15) * 4;
    int t = threadIdx.x, lane = t & 63, wv = t >> 6;
    int pl = lane & 15, kg = lane >> 4;
    int l3 = lane >> 3, l7 = lane & 7;

    for (int q = 0; q < 2; ++q) {
        int sg = q * 4 + wv;
        gl2lds16(tcb + (size_t)(sg * 8 + l3) * 64 + (l7 ^ l3) * 8, tC + sg * 1024);
        gl2lds16(tsb + (size_t)(sg * 8 + l3) * 64 + (l7 ^ l3) * 8, tS + sg * 1024);
    }
    const float* xf = x + (size_t)fi * Cd * HW;
    int h = t & 63;
    for (int k = 0; k < 16; ++k) {
        int c = k * 4 + (t >> 6);
        float4 v = *(const float4*)(xf + (size_t)c * HW + h * 64 + w0);
        float vv[4] = {v.x, v.y, v.z, v.w};
#pragma unroll
        for (int q = 0; q < 4; ++q) {
            int pos = q * 64 + c;
            *(unsigned short*)(xpT + pos * 128 + ((h * 2) ^ ((c & 7) << 4))) = bf16c(vv[q]);
        }
    }
    __syncthreads();

    int w = w0 + wv;
    float2* Xw = X + (size_t)fi * 262144 + (size_t)w * 4096;
    for (int half = 0; half < 2; ++half) {
        f32x4 aR[2][4], aI[2][4];
#pragma unroll
        for (int mt = 0; mt < 2; ++mt)
#pragma unroll
            for (int nt = 0; nt < 4; ++nt) { aR[mt][nt] = (f32x4)0.f; aI[mt][nt] = (f32x4)0.f; }
#pragma unroll
        for (int ks = 0; ks < 2; ++ks) {
            int koff = (ks * 64 + kg * 16);
            bf16x8 ac[2], as_[2], b[4];
#pragma unroll
            for (int mt = 0; mt < 2; ++mt) {
                int row = half * 32 + mt * 16 + pl;
                int off = row * 128 + (koff ^ ((pl & 7) << 4));
                ac[mt] = *(const bf16x8*)(tC + off);
                as_[mt] = *(const bf16x8*)(tS + off);
            }
#pragma unroll
            for (int nt = 0; nt < 4; ++nt) {
                int pos = wv * 64 + nt * 16 + pl;
                b[nt] = *(const bf16x8*)(xpT + pos * 128 + (koff ^ ((pl & 7) << 4)));
            }
#pragma unroll
            for (int mt = 0; mt < 2; ++mt)
#pragma unroll
                for (int nt = 0; nt < 4; ++nt) {
                    aR[mt][nt] = __builtin_amdgcn_mfma_f32_16x16x32_bf16(ac[mt], b[nt], aR[mt][nt], 0, 0, 0);
                    aI[mt][nt] = __builtin_amdgcn_mfma_f32_16x16x32_bf16(as_[mt], b[nt], aI[mt][nt], 0, 0, 0);
                }
        }
#pragma unroll
        for (int mt = 0; mt < 2; ++mt)
#pragma unroll
            for (int nt = 0; nt < 4; ++nt) {
                int c = nt * 16 + pl;
#pragma unroll
                for (int r = 0; r < 4; ++r) {
                    int fh = half * 32 + mt * 16 + kg * 4 + r;
                    Xw[fh * 64 + c] = make_float2(aR[mt][nt][r], aI[mt][nt][r]);
                }
            }
    }
}

// ===========================================================================
// Complex channel mix, MFMA, in-place. X rows [pos][c] (pos = w*64+fh).
// ===========================================================================
__global__ __launch_bounds__(256) void k_cmixm(const float2* __restrict__ Xin,
                                               float2* __restrict__ Xout,
                                               const unsigned short* __restrict__ wr,
                                               const unsigned short* __restrict__ wi,
                                               const float* __restrict__ gamT,
                                               const float* __restrict__ br_g,
                                               const float* __restrict__ bi_g,
                                               int use_gamma) {
    __shared__ __align__(16) unsigned char smm[65536];
    unsigned char* inr = smm;
    unsigned char* ini = smm + 16384;
    unsigned char* wR = smm + 32768;
    unsigned char* wI = smm + 40960;
    float* gam = (float*)(smm + 49152);
    int blk = blockIdx.x;
    size_t R0 = (size_t)blk * 128;
    int t = threadIdx.x, lane = t & 63, wv = t >> 6;
    int pl = lane & 15, kg = lane >> 4;
    int l3 = lane >> 3, l7 = lane & 7;

    for (int k = 0; k < 16; ++k) {
        int j = k * 256 + t;
        int row = j >> 5, c2 = j & 31;
        float4 v = *(const float4*)((const float*)(Xin + (R0 + row) * 64) + c2 * 4);
        unsigned int rw = (unsigned int)bf16c(v.x) | ((unsigned int)bf16c(v.z) << 16);
        unsigned int iw = (unsigned int)bf16c(v.y) | ((unsigned int)bf16c(v.w) << 16);
        int off = row * 128 + ((c2 * 4) ^ ((row & 7) << 4));
        *(unsigned int*)(inr + off) = rw;
        *(unsigned int*)(ini + off) = iw;
    }
    for (int q = 0; q < 2; ++q) {
        int sg = q * 4 + wv;
        gl2lds16(wr + (size_t)(sg * 8 + l3) * 64 + (l7 ^ l3) * 8, wR + sg * 1024);
        gl2lds16(wi + (size_t)(sg * 8 + l3) * 64 + (l7 ^ l3) * 8, wI + sg * 1024);
    }
    if (use_gamma) {
        for (int j = t; j < 4096; j += 256) gam[j] = gamT[j];
    }
    __syncthreads();

    int posbase = wv * 32;
    f32x4 cR[2][4], cI[2][4];
#pragma unroll
    for (int mt = 0; mt < 2; ++mt)
#pragma unroll
        for (int nt = 0; nt < 4; ++nt) { cR[mt][nt] = (f32x4)0.f; cI[mt][nt] = (f32x4)0.f; }
#pragma unroll
    for (int ks = 0; ks < 2; ++ks) {
        int koff = ks * 64 + kg * 16;
        bf16x8 ar[2], ai[2], an[2], brf[4], bif[4];
#pragma unroll
        for (int mt = 0; mt < 2; ++mt) {
            int row = posbase + mt * 16 + pl;
            int off = row * 128 + (koff ^ ((pl & 7) << 4));
            ar[mt] = *(const bf16x8*)(inr + off);
            ai[mt] = *(const bf16x8*)(ini + off);
            an[mt] = bneg(ai[mt]);
        }
#pragma unroll
        for (int nt = 0; nt < 4; ++nt) {
            int o = nt * 16 + pl;
            int off = o * 128 + (koff ^ ((pl & 7) << 4));
            brf[nt] = *(const bf16x8*)(wR + off);
            bif[nt] = *(const bf16x8*)(wI + off);
        }
#pragma unroll
        for (int mt = 0; mt < 2; ++mt)
#pragma unroll
            for (int nt = 0; nt < 4; ++nt) {
                cR[mt][nt] = __builtin_amdgcn_mfma_f32_16x16x32_bf16(ar[mt], brf[nt], cR[mt][nt], 0, 0, 0);
                cR[mt][nt] = __builtin_amdgcn_mfma_f32_16x16x32_bf16(an[mt], bif[nt], cR[mt][nt], 0, 0, 0);
                cI[mt][nt] = __builtin_amdgcn_mfma_f32_16x16x32_bf16(ar[mt], bif[nt], cI[mt][nt], 0, 0, 0);
                cI[mt][nt] = __builtin_amdgcn_mfma_f32_16x16x32_bf16(ai[mt], brf[nt], cI[mt][nt], 0, 0, 0);
            }
    }
#pragma unroll
    for (int mt = 0; mt < 2; ++mt)
#pragma unroll
        for (int nt = 0; nt < 4; ++nt) {
            int o = nt * 16 + pl;
            float bR = 0.f, bI = 0.f;
            if (use_gamma) { bR = br_g[o]; bI = bi_g[o]; }
#pragma unroll
            for (int r = 0; r < 4; ++r) {
                int lrow = posbase + mt * 16 + kg * 4 + r;
                int prow = (blk & 31) * 128 + lrow;
                float vr = cR[mt][nt][r], vi = cI[mt][nt][r];
                if (use_gamma) {
                    if (prow < 64) { vr += bR; vi += bI; }
                    float g = gam[(prow & 63) * 64 + o];
                    vr *= g; vi *= g;
                }
                Xout[(R0 + lrow) * 64 + o] = make_float2(vr, vi);
            }
        }
}

// ===========================================================================
// Linear recurrence over L, layout [l][w][fh][c]. In-place, LB batches.
// ===========================================================================
__global__ __launch_bounds__(256) void k_scan2(float2* __restrict__ X,
                                               const float* __restrict__ pl) {
    int g = blockIdx.x * 256 + threadIdx.x;
    int c = g & 63;
    int fh = (g >> 6) & 63;
    int w = (g >> 12) & 63;
    int b = g >> 18;
    float nu = expf(pl[c * 64 + fh]);
    float th = expf(pl[4096 + c * 64 + fh]);
    float mag = expf(-nu);
    float sth, cth;
    sincosf(th, &sth, &cth);
    float lr = mag * cth, li = mag * sth;
    size_t base = (size_t)b * 16 * 262144 + (size_t)w * 4096 + fh * 64 + c;
    float2 acc = X[base];
    for (int tt = 1; tt < Ld; ++tt) {
        size_t idx = base + (size_t)tt * 262144;
        float2 v = X[idx];
        float nr = lr * acc.x - li * acc.y + v.x;
        float ni = lr * acc.y + li * acc.x + v.y;
        acc = make_float2(nr, ni);
        X[idx] = acc;
    }
}

// ===========================================================================
// Inverse DFT over h (Re only), MFMA + Cb + LayerNorm(H,W) + residual.
// ===========================================================================
__global__ __launch_bounds__(256) void k_idfthm_ln(const float2* __restrict__ X,
                                                   const unsigned short* __restrict__ tic,
                                                   const unsigned short* __restrict__ tis,
                                                   const float* __restrict__ cbr,
                                                   const float* __restrict__ lnw,
                                                   const float* __restrict__ lnb,
                                                   const float* __restrict__ xprev,
                                                   float* __restrict__ xout) {
    __shared__ __align__(16) unsigned char smm[81920];
    unsigned char* SrT = smm;
    unsigned char* SiT = smm + 32768;
    unsigned char* tC = smm + 65536;
    unsigned char* tS = smm + 73728;
    float* y4 = (float*)smm;
    int blk = blockIdx.x;
    int fi = blk >> 4;
    int c0 = (blk & 15) * 4;
    int t = threadIdx.x, lane = t & 63, wv = t >> 6;
    int pl = lane & 15, kg = lane >> 4;
    int l3 = lane >> 3, l7 = lane & 7;

    for (int q = 0; q < 2; ++q) {
        int sg = q * 4 + wv;
        gl2lds16(tic + (size_t)(sg * 8 + l3) * 64 + (l7 ^ l3) * 8, tC + sg * 1024);
        gl2lds16(tis + (size_t)(sg * 8 + l3) * 64 + (l7 ^ l3) * 8, tS + sg * 1024);
    }
    const float* Xf = (const float*)(X + (size_t)fi * 262144);
    int fh = t & 63;
    for (int k = 0; k < 16; ++k) {
        int w = k * 4 + (t >> 6);
        const float* p = Xf + ((size_t)w * 4096 + fh * 64 + c0) * 2;
        float4 v0 = *(const float4*)(p);
        float4 v1 = *(const float4*)(p + 4);
        float rr[4] = {v0.x, v0.z, v1.x, v1.z};
        float ii[4] = {v0.y, v0.w, v1.y, v1.w};
#pragma unroll
        for (int cj = 0; cj < 4; ++cj) {
            int pos2 = w * 4 + cj;
            int off = pos2 * 128 + ((fh * 2) ^ ((pos2 & 7) << 4));
            *(unsigned short*)(SrT + off) = bf16c(rr[cj]);
            *(unsigned short*)(SiT + off) = bf16c(ii[cj]);
        }
    }
    __syncthreads();

    f32x4 y[4][4];
#pragma unroll
    for (int mt = 0; mt < 4; ++mt)
#pragma unroll
        for (int nt = 0; nt < 4; ++nt) y[mt][nt] = (f32x4)0.f;
#pragma unroll
    for (int ks = 0; ks < 2; ++ks) {
        int koff = ks * 64 + kg * 16;
        bf16x8 ac[4], as_[4], brf[4], bif[4];
#pragma unroll
        for (int mt = 0; mt < 4; ++mt) {
            int row = mt * 16 + pl;
            int off = row * 128 + (koff ^ ((pl & 7) << 4));
            ac[mt] = *(const bf16x8*)(tC + off);
            as_[mt] = *(const bf16x8*)(tS + off);
        }
#pragma unroll
        for (int nt = 0; nt < 4; ++nt) {
            int pos2 = wv * 64 + nt * 16 + pl;
            int off = pos2 * 128 + (koff ^ ((pl & 7) << 4));
            brf[nt] = *(const bf16x8*)(SrT + off);
            bif[nt] = *(const bf16x8*)(SiT + off);
        }
#pragma unroll
        for (int mt = 0; mt < 4; ++mt)
#pragma unroll
            for (int nt = 0; nt < 4; ++nt) {
                y[mt][nt] = __builtin_amdgcn_mfma_f32_16x16x32_bf16(ac[mt], brf[nt], y[mt][nt], 0, 0, 0);
                y[mt][nt] = __builtin_amdgcn_mfma_f32_16x16x32_bf16(as_[mt], bif[nt], y[mt][nt], 0, 0, 0);
            }
    }
    __syncthreads();

    float cb4[4];
#pragma unroll
    for (int cj = 0; cj < 4; ++cj) cb4[cj] = cbr[c0 + cj];
#pragma unroll
    for (int mt = 0; mt < 4; ++mt)
#pragma unroll
        for (int nt = 0; nt < 4; ++nt) {
            int pos2 = wv * 64 + nt * 16 + pl;
            int w = pos2 >> 2, cj = pos2 & 3;
#pragma unroll
            for (int r = 0; r < 4; ++r) {
                int h = mt * 16 + kg * 4 + r;
                y4[cj * 4232 + h * 66 + w] = y[mt][nt][r] + cb4[cj];
            }
        }
    __syncthreads();

    int w = lane;
    const float* yp = y4 + wv * 4232;
    float s = 0.f, q = 0.f;
    for (int h = 0; h < 64; ++h) {
        float v = yp[h * 66 + w];
        s += v;
        q += v * v;
    }
#pragma unroll
    for (int off = 32; off; off >>= 1) {
        s += __shfl_xor(s, off);
        q += __shfl_xor(q, off);
    }
    float m = s * (1.f / 4096.f);
    float var = q * (1.f / 4096.f) - m * m;
    float rs = rsqrtf(var + 1e-5f);
    int c = c0 + wv;
    const float* xp = xprev + ((size_t)fi * Cd + c) * HW;
    float* xo = xout + ((size_t)fi * Cd + c) * HW;
    for (int h = 0; h < 64; ++h) {
        int p = h * 64 + w;
        xo[p] = (yp[h * 66 + w] - m) * rs * lnw[p] + lnb[p] + xp[p];
    }
}

// ===========================================================================
// LN(H,W) + residual accumulate, channel-planar (final ffn_ln). cobuf bf16.
// ===========================================================================
__global__ __launch_bounds__(256) void k_ln_res(const unsigned short* __restrict__ t_in,
                                                const float* __restrict__ w,
                                                const float* __restrict__ b,
                                                float* __restrict__ dst) {
    __shared__ float red[8];
    int fr = blockIdx.x;
    const unsigned short* src = t_in + (size_t)fr * HW;
    float* d = dst + (size_t)fr * HW;
    int t = threadIdx.x;
    float vals[16];
    float s = 0.f, sq = 0.f;
#pragma unroll
    for (int j = 0; j < 16; ++j) {
        float v = bf2f(src[t + 256 * j]);
        vals[j] = v;
        s += v;
        sq += v * v;
    }
    for (int off = 32; off; off >>= 1) {
        s += __shfl_down(s, off);
        sq += __shfl_down(sq, off);
    }
    int wid = t >> 6;
    if ((t & 63) == 0) { red[wid] = s; red[4 + wid] = sq; }
    __syncthreads();
    s = red[0] + red[1] + red[2] + red[3];
    sq = red[4] + red[5] + red[6] + red[7];
    float m = s * (1.f / 4096.f);
    float var = sq * (1.f / 4096.f) - m * m;
    float rs = rsqrtf(var + 1e-5f);
#pragma unroll
    for (int j = 0; j < 16; ++j) {
        int p = t + 256 * j;
        d[p] += (vals[j] - m) * rs * w[p] + b[p];
    }
}

// ===========================================================================
// Weight prep (fp32 -> bf16, MFMA-friendly layouts)
// ===========================================================================
__global__ void k_prep7(const float* __restrict__ w, unsigned short* __restrict__ o) {
    int idx = blockIdx.x * 256 + threadIdx.x;     // tap*8192 + f*64 + c
    if (idx < 49 * 128 * 64) {
        int tap = idx >> 13, rem = idx & 8191, f = rem >> 6, c = rem & 63;
        o[idx] = bf16c(w[(size_t)(f * 64 + c) * 49 + tap]);
    }
}
__global__ void k_prep3(const float* __restrict__ w, unsigned short* __restrict__ o,
                        int nh) {
    int idx = blockIdx.x * 256 + threadIdx.x;
    if (idx < nh * 147456) {
        int head = idx / 147456;
        int rem = idx - head * 147456;
        int tap = rem >> 14, r2 = rem & 16383, f = r2 >> 7, c = r2 & 127;
        o[idx] = bf16c(w[(size_t)head * 147456 + (size_t)(f * 128 + c) * 9 + tap]);
    }
}
__global__ void k_prepcvt(const float* __restrict__ w, unsigned short* __restrict__ o, int n) {
    int idx = blockIdx.x * 256 + threadIdx.x;
    if (idx < n) o[idx] = bf16c(w[idx]);
}

// Channel-planar fp32 -> position-major bf16  ([c][HW] -> [pos][64])
__global__ __launch_bounds__(256) void k_t2p(const float* __restrict__ x,
                                             unsigned short* __restrict__ xT) {
    __shared__ float tile[64][65];
    int blk = blockIdx.x;
    int f = blk >> 6;
    int p0 = (blk & 63) * 64;
    int t = threadIdx.x;
    const float* src = x + (size_t)f * Cd * HW;
    for (int j = t; j < 4096; j += 256) {
        int c = j >> 6, p = j & 63;
        tile[c][p] = src[(size_t)c * HW + p0 + p];
    }
    __syncthreads();
    unsigned short* dst = xT + ((size_t)f * HW + p0) * 64;
    for (int j = t; j < 4096; j += 256) {
        int p = j >> 6, c = j & 63;
        dst[(size_t)p * 64 + c] = bf16c(tile[c][p]);
    }
}

// ===========================================================================
// 7x7 conv, MFMA, XOR-swizzled LDS. 8 waves, 4 output rows/block. y out bf16.
// ===========================================================================
__global__ __launch_bounds__(512) void k_conv7m(const unsigned short* __restrict__ xT,
                                                const unsigned short* __restrict__ wb,
                                                const float* __restrict__ bias,
                                                unsigned short* __restrict__ yout) {
    __shared__ __align__(16) unsigned char smm[122368];
    unsigned char* inT = smm;
    unsigned char* wt0 = smm + 89600;
    int blk = blockIdx.x;
    int fi = blk >> 4;
    int y0 = (blk & 15) * 4;
    int t = threadIdx.x, lane = t & 63, wv = t >> 6;
    int l3 = lane >> 3, l7 = lane & 7;

    const unsigned short* xf = xT + (size_t)fi * HW * 64;
    float4 z4 = make_float4(0.f, 0.f, 0.f, 0.f);
    int ksw_in = l7 ^ ((3 + l3) & 7);
    for (int idx = wv; idx < 80; idx += 8) {
        int r = idx >> 3, sg = idx & 7;
        int srow = y0 + r - 3;
        unsigned char* dst = inT + r * 8960 + 3 * 128 + sg * 1024;
        if (srow >= 0 && srow < 64) {
            gl2lds16(xf + (size_t)srow * 4096 + (sg * 8 + l3) * 64 + ksw_in * 8, dst);
        } else {
            *(float4*)(dst + lane * 16) = z4;
        }
    }
    if (t < 480) {
        int r = t / 48, k = t % 48;
        int xp = (k < 24) ? (k >> 3) : 67 + ((k - 24) >> 3);
        *(float4*)(inT + r * 8960 + xp * 128 + (k & 7) * 16) = z4;
    }
    int ksw_w = l7 ^ l3;
    for (int q = 0; q < 2; ++q) {
        int sg = q * 8 + wv;
        int f = sg * 8 + l3;
        gl2lds16(wb + (size_t)f * 64 + ksw_w * 8, wt0 + sg * 1024);
    }
    __syncthreads();

    int wm = wv & 3, wn = wv >> 2;
    f32x4 acc[4][4];
#pragma unroll
    for (int m = 0; m < 4; ++m)
#pragma unroll
        for (int n = 0; n < 4; ++n) acc[m][n] = (f32x4)0.f;
    int kg = lane >> 4, pl = lane & 15;
    int cur = 0;
    for (int tap = 0; tap < 49; ++tap) {
        if (tap + 1 < 49) {
            const unsigned short* g = wb + (size_t)(tap + 1) * 8192;
            unsigned char* wdst = wt0 + (cur ^ 1) * 16384;
            for (int q = 0; q < 2; ++q) {
                int sg = q * 8 + wv;
                int f = sg * 8 + l3;
                gl2lds16(g + (size_t)f * 64 + ksw_w * 8, wdst + sg * 1024);
            }
        }
        unsigned char* wcur = wt0 + cur * 16384;
        int ky = tap / 7, kx = tap % 7;
        int rbase = (wm + ky) * 8960;
#pragma unroll
        for (int ks = 0; ks < 2; ++ks) {
            bf16x8 a[4], b[4];
#pragma unroll
            for (int m = 0; m < 4; ++m) {
                int xp = m * 16 + pl + kx;
                a[m] = *(const bf16x8*)(inT + rbase + xp * 128 +
                                        (((ks * 4 + kg) ^ (xp & 7)) << 4));
            }
#pragma unroll
            for (int n = 0; n < 4; ++n) {
                int row = wn * 64 + n * 16 + pl;
                b[n] = *(const bf16x8*)(wcur + row * 128 +
                                        (((ks * 4 + kg) ^ (pl & 7)) << 4));
            }
#pragma unroll
            for (int m = 0; m < 4; ++m)
#pragma unroll
                for (int n = 0; n < 4; ++n)
                    acc[m][n] = __builtin_amdgcn_mfma_f32_16x16x32_bf16(a[m], b[n], acc[m][n], 0, 0, 0);
        }
        __syncthreads();
        cur ^= 1;
    }
    unsigned short* yo = yout + ((size_t)fi * HW + (size_t)(y0 + wm) * 64) * 128;
#pragma unroll
    for (int m = 0; m < 4; ++m)
#pragma unroll
        for (int n = 0; n < 4; ++n) {
            int f = wn * 64 + n * 16 + pl;
            float bs = bias[f];
#pragma unroll
            for (int r = 0; r < 4; ++r) {
                int x = m * 16 + kg * 4 + r;
                yo[(size_t)x * 128 + f] = bf16c(gelu_f(acc[m][n][r] + bs));
            }
        }
}

// ===========================================================================
// FUSED 3x3 conv + 1x1 (h1) + gelu + LN partials. 8 waves, 4 rows/block.
// y input is bf16 (staged via DMA); weights single-buffered with T14
// register prefetch. Outputs: t2 bf16 + lnpart (16 slabs of 256 pos).
// ===========================================================================
__global__ __launch_bounds__(512) void k_conv3f(const unsigned short* __restrict__ yin,
                                                const unsigned short* __restrict__ wb,
                                                const float* __restrict__ bias3,
                                                const unsigned short* __restrict__ w1,
                                                const float* __restrict__ bias1,
                                                unsigned short* __restrict__ outp2,
                                                float* __restrict__ lnpart) {
    __shared__ __align__(16) unsigned char smm[134144];   // inT 6*66*256 | wL 32768
    __shared__ float redS[8][64], redQ[8][64];
    unsigned char* inT = smm;
    unsigned char* wL = smm + 101376;
    int blk = blockIdx.x;
    int fi = blk >> 4;
    int y0 = (blk & 15) * 4;
    int t = threadIdx.x, lane = t & 63, wv = t >> 6;
    int l4 = lane >> 4, l15 = lane & 15;
    const unsigned short* yf = yin + (size_t)fi * HW * 128;
    float4 z4 = make_float4(0.f, 0.f, 0.f, 0.f);
    // stage 6 input rows (y0-1 .. y0+4), xp 1..64 via DMA (pre-swizzled src)
    for (int seg = wv; seg < 96; seg += 8) {
        int r = seg >> 4, xs = seg & 15;
        int srow = y0 + r - 1;
        int xp = 1 + xs * 4 + l4;
        unsigned char* dst = inT + r * 16896 + (size_t)(1 + xs * 4) * 256;
        if (srow >= 0 && srow < 64) {
            int gsrc = l15 ^ (xp & 7);
            gl2lds16(yf + ((size_t)(srow * 64 + xp - 1) * 128 + gsrc * 8), dst);
        } else {
            *(float4*)(dst + lane * 16) = z4;
        }
    }
    // x-edge zeros (xp 0, 65): 6 rows * 2 * 16 granules
    if (t < 192) {
        int r = t / 32, k = t & 31;
        int xp = (k < 16) ? 0 : 65;
        *(float4*)(inT + r * 16896 + xp * 256 + (k & 15) * 16) = z4;
    }
    // weights tap 0
    for (int sg = wv; sg < 32; sg += 8) {
        int f = sg * 4 + l4;
        gl2lds16(wb + (size_t)f * 128 + (l15 ^ (f & 7)) * 8, wL + sg * 1024);
    }
    __syncthreads();

    int wm = wv & 3, wn = wv >> 2;
    f32x4 acc[4][4];
#pragma unroll
    for (int m = 0; m < 4; ++m)
#pragma unroll
        for (int n = 0; n < 4; ++n) acc[m][n] = (f32x4)0.f;
    int kg = lane >> 4, pl = lane & 15;
    int fw = t >> 2, qw = t & 3;      // reg-prefetch mapping: f row, quarter
    u32x4 rg[4];
    for (int tap = 0; tap < 9; ++tap) {
        if (tap < 8) {
            const u32x4* src = (const u32x4*)(wb + (size_t)(tap + 1) * 16384 +
                                              (size_t)fw * 128 + qw * 32);
#pragma unroll
            for (int j = 0; j < 4; ++j) rg[j] = src[j];
        }
        int ky = tap / 3, kx = tap % 3;
        int rbase = (wm + ky) * 16896;
#pragma unroll
        for (int ks = 0; ks < 4; ++ks) {
            bf16x8 a[4], b[4];
#pragma unroll
            for (int m = 0; m < 4; ++m) {
                int xp = m * 16 + pl + kx;
                a[m] = *(const bf16x8*)(inT + rbase + (size_t)xp * 256 +
                                        ((ks * 64 + kg * 16) ^ ((xp & 7) << 4)));
            }
#pragma unroll
            for (int n = 0; n < 4; ++n) {
                int row = wn * 64 + n * 16 + pl;
                b[n] = *(const bf16x8*)(wL + (size_t)row * 256 +
                                        ((ks * 64 + kg * 16) ^ ((pl & 7) << 4)));
            }
#pragma unroll
            for (int m = 0; m < 4; ++m)
#pragma unroll
                for (int n = 0; n < 4; ++n)
                    acc[m][n] = __builtin_amdgcn_mfma_f32_16x16x32_bf16(a[m], b[n], acc[m][n], 0, 0, 0);
        }
        __syncthreads();
        if (tap < 8) {
#pragma unroll
            for (int j = 0; j < 4; ++j)
                *(u32x4*)(wL + (size_t)fw * 256 + (((qw * 4 + j) ^ (fw & 7)) << 4)) = rg[j];
        }
        __syncthreads();
    }

    // ---- fused 1x1: t -> LDS (inT region dead), stage W1, GEMM ----
    unsigned char* tL = smm;              // [256 pos][128 f] bf16, swz
    unsigned char* w1L = smm + 65536;     // [128 o][128 f] bf16, swz
#pragma unroll
    for (int m = 0; m < 4; ++m)
#pragma unroll
        for (int n = 0; n < 4; ++n) {
            int f = wn * 64 + n * 16 + pl;
            float bs = bias3[f];
#pragma unroll
            for (int r = 0; r < 4; ++r) {
                int pos = wm * 64 + m * 16 + kg * 4 + r;
                *(unsigned short*)(tL + (size_t)pos * 256 +
                    ((((f >> 3) ^ (pos & 7)) << 4) | ((f & 7) * 2))) =
                    bf16c(gelu_f(acc[m][n][r] + bs));
            }
        }
    for (int sg = wv; sg < 32; sg += 8) {
        int rr = sg * 4 + l4;
        gl2lds16(w1 + (size_t)rr * 128 + (l15 ^ (rr & 7)) * 8, w1L + sg * 1024);
    }
    __syncthreads();

    f32x4 fa[4][4];
#pragma unroll
    for (int m = 0; m < 4; ++m)
#pragma unroll
        for (int n = 0; n < 4; ++n) fa[m][n] = (f32x4)0.f;
#pragma unroll
    for (int ks = 0; ks < 4; ++ks) {
        bf16x8 a[4], b[4];
#pragma unroll
        for (int m = 0; m < 4; ++m) {
            int row = wm * 64 + m * 16 + pl;
            a[m] = *(const bf16x8*)(tL + (size_t)row * 256 +
                                    ((ks * 64 + kg * 16) ^ ((pl & 7) << 4)));
        }
#pragma unroll
        for (int n = 0; n < 4; ++n) {
            int row = wn * 64 + n * 16 + pl;
            b[n] = *(const bf16x8*)(w1L + (size_t)row * 256 +
                                    ((ks * 64 + kg * 16) ^ ((pl & 7) << 4)));
        }
#pragma unroll
        for (int m = 0; m < 4; ++m)
#pragma unroll
            for (int n = 0; n < 4; ++n)
                fa[m][n] = __builtin_amdgcn_mfma_f32_16x16x32_bf16(a[m], b[n], fa[m][n], 0, 0, 0);
    }
    int slab = blk & 15;
    int p0 = slab * 256;
    unsigned short* o = outp2 + ((size_t)fi * HW + p0) * 128;
#pragma unroll
    for (int n = 0; n < 4; ++n) {
        int f = wn * 64 + n * 16 + pl;
        float bs = bias1[f];
        float s = 0.f, q = 0.f;
#pragma unroll
        for (int m = 0; m < 4; ++m)
#pragma unroll
            for (int r = 0; r < 4; ++r) {
                float v = gelu_f(fa[m][n][r] + bs);
                int x = wm * 64 + m * 16 + kg * 4 + r;
                o[(size_t)x * 128 + f] = bf16c(v);
                s += v;
                q += v * v;
            }
        s += __shfl_xor(s, 16); s += __shfl_xor(s, 32);
        q += __shfl_xor(q, 16); q += __shfl_xor(q, 32);
        if (kg == 0) { redS[wv][n * 16 + pl] = s; redQ[wv][n * 16 + pl] = q; }
    }
    __syncthreads();
    if (t < 128) {
        int wh = t >> 6, j = t & 63;
        float s = redS[wh * 4][j] + redS[wh * 4 + 1][j] + redS[wh * 4 + 2][j] + redS[wh * 4 + 3][j];
        float q = redQ[wh * 4][j] + redQ[wh * 4 + 1][j] + redQ[wh * 4 + 2][j] + redQ[wh * 4 + 3][j];
        float* lp = lnpart + ((size_t)(fi * 16 + slab) * 128 + t) * 2;
        lp[0] = s;
        lp[1] = q;
    }
}

// ===========================================================================
// LN finalize (16 slab partials) + apply: y += LN(t2)*w + b. t2, y bf16.
// ===========================================================================
__global__ __launch_bounds__(256) void k_lnapply2(const unsigned short* __restrict__ t2,
                                                  const float* __restrict__ lnpart,
                                                  const float* __restrict__ w,
                                                  const float* __restrict__ b,
                                                  unsigned short* __restrict__ y) {
    __shared__ float sm_m[128], sm_r[128];
    int blk = blockIdx.x;
    int fi = blk >> 5, p0 = (blk & 31) * 128;
    int t = threadIdx.x;
    if (t < 128) {
        float s = 0.f, q = 0.f;
        for (int sl = 0; sl < 16; ++sl) {
            const float* lp = lnpart + ((size_t)(fi * 16 + sl) * 128 + t) * 2;
            s += lp[0];
            q += lp[1];
        }
        float m = s * (1.f / 4096.f);
        float var = q * (1.f / 4096.f) - m * m;
        sm_m[t] = m;
        sm_r[t] = rsqrtf(var + 1e-5f);
    }
    __syncthreads();
    int f = t & 127, ph = t >> 7;
    for (int k = ph; k < 128; k += 2) {
        int p = p0 + k;
        size_t idx = ((size_t)fi * HW + p) * 128 + f;
        float v = bf2f(t2[idx]);
        float yv = bf2f(y[idx]);
        y[idx] = bf16c(yv + (v - sm_m[f]) * sm_r[f] * w[p] + b[p]);
    }
}

// ===========================================================================
// 1x1 cout (128->64), MFMA, A=weights -> channel-planar bf16 out. y bf16 in.
// ===========================================================================
__global__ __launch_bounds__(256) void k_coutm(const unsigned short* __restrict__ yin,
                                               const unsigned short* __restrict__ wt,
                                               const float* __restrict__ bias,
                                               unsigned short* __restrict__ outp) {
    __shared__ __align__(16) unsigned char smm[49152];
    unsigned char* inL = smm;
    unsigned char* wL = smm + 32768;
    int blk = blockIdx.x;
    int fi = blk >> 5;
    int p0 = (blk & 31) * 128;
    int t = threadIdx.x, lane = t & 63, wv = t >> 6;
    int l4 = lane >> 4, l15 = lane & 15;
    for (int sg = wv; sg < 16; sg += 4) {
        int r = sg * 4 + l4;
        gl2lds16(wt + (size_t)r * 128 + (l15 ^ (r & 7)) * 8, wL + sg * 1024);
    }
    const unsigned short* yb = yin + (size_t)fi * HW * 128;
    for (int sg = wv; sg < 32; sg += 4) {
        int pos = sg * 4 + l4;
        gl2lds16(yb + ((size_t)(p0 + pos) * 128 + (l15 ^ (pos & 7)) * 8), inL + sg * 1024);
    }
    __syncthreads();
    int wm = wv & 1, wn = wv >> 1;
    f32x4 acc[2][4];
#pragma unroll
    for (int m = 0; m < 2; ++m)
#pragma unroll
        for (int n = 0; n < 4; ++n) acc[m][n] = (f32x4)0.f;
    int kg = lane >> 4, pl = lane & 15;
#pragma unroll
    for (int ks = 0; ks < 4; ++ks) {
        bf16x8 a[2], b[4];
#pragma unroll
        for (int m = 0; m < 2; ++m) {
            int row = wm * 32 + m * 16 + pl;
            a[m] = *(const bf16x8*)(wL + (size_t)row * 256 +
                                    ((ks * 64 + kg * 16) ^ ((pl & 7) << 4)));
        }
#pragma unroll
        for (int n = 0; n < 4; ++n) {
            int row = wn * 64 + n * 16 + pl;
            b[n] = *(const bf16x8*)(inL + (size_t)row * 256 +
                                    ((ks * 64 + kg * 16) ^ ((pl & 7) << 4)));
        }
#pragma unroll
        for (int m = 0; m < 2; ++m)
#pragma unroll
            for (int n = 0; n < 4; ++n)
                acc[m][n] = __builtin_amdgcn_mfma_f32_16x16x32_bf16(a[m], b[n], acc[m][n], 0, 0, 0);
    }
#pragma unroll
    for (int m = 0; m < 2; ++m)
#pragma unroll
        for (int n = 0; n < 4; ++n) {
            int pos = p0 + wn * 64 + n * 16 + pl;
#pragma unroll
            for (int r = 0; r < 4; ++r) {
                int c = wm * 32 + m * 16 + (lane >> 4) * 4 + r;
                outp[((size_t)fi * 64 + c) * HW + pos] = bf16c(acc[m][n][r] + bias[c]);
            }
        }
}

// ===========================================================================
extern "C" void kernel_launch(void* const* d_in, const int* in_sizes, int n_in,
                              void* d_out, int out_size, void* d_ws, size_t ws_size,
                              hipStream_t stream) {
    (void)in_sizes; (void)n_in; (void)out_size;
    const float* x_in  = (const float*)d_in[0];
    const float* pl    = (const float*)d_in[1];
    const float* pBw_r = (const float*)d_in[2];
    const float* pBw_i = (const float*)d_in[3];
    const float* pBb_r = (const float*)d_in[4];
    const float* pBb_i = (const float*)d_in[5];
    const float* pCw_r = (const float*)d_in[6];
    const float* pCw_i = (const float*)d_in[7];
    const float* pCb_r = (const float*)d_in[8];
    const float* pCb_i = (const float*)d_in[9];
    const float* lruw  = (const float*)d_in[10];
    const float* lrub  = (const float*)d_in[11];
    const float* cinw  = (const float*)d_in[12];
    const float* cinb  = (const float*)d_in[13];
    const float* h3w   = (const float*)d_in[14];
    const float* h3b   = (const float*)d_in[15];
    const float* h1w   = (const float*)d_in[16];
    const float* h1b   = (const float*)d_in[17];
    const float* hlnw  = (const float*)d_in[18];
    const float* hlnb  = (const float*)d_in[19];
    const float* coutw = (const float*)d_in[20];
    const float* coutb = (const float*)d_in[21];
    const float* flnw  = (const float*)d_in[22];
    const float* flnb  = (const float*)d_in[23];
    float* out = (float*)d_out;

    // --- adaptive chunk tier (FFN buffers now 3 MiB/frame) ---
    int FR = 8, LB = 1;
    {
        const int frs[6] = {64, 32, 16, 16, 8, 8};
        const int lbs[6] = {4, 4, 4, 2, 2, 1};
        for (int k = 0; k < 6; ++k) {
            size_t region = (size_t)lbs[k] * 33554432ULL;
            size_t ffn = (size_t)frs[k] * 3145728ULL;
            if (ffn > region) region = ffn;
            size_t needb = region + 1605632ULL + (size_t)frs[k] * 32768ULL + 65536ULL;
            if (needb <= ws_size) { FR = frs[k]; LB = lbs[k]; break; }
        }
    }
    size_t region = (size_t)LB * 33554432ULL;
    {
        size_t ffn = (size_t)FR * 3145728ULL;
        if (ffn > region) region = ffn;
    }
    unsigned char* ws = (unsigned char*)d_ws;
    float2* Xb = (float2*)ws;                                            // LB*33.5 MB
    unsigned short* ybuf = (unsigned short*)ws;                          // FR*1 MiB
    unsigned short* t2bf = (unsigned short*)(ws + (size_t)FR * 1048576); // FR*1 MiB
    unsigned short* xT   = (unsigned short*)(ws + (size_t)FR * 2097152); // FR*0.5 MiB
    unsigned short* cobuf = (unsigned short*)(ws + (size_t)FR * 2621440);// FR*0.5 MiB
    unsigned char* wbase = ws + region;
    unsigned short* wb7  = (unsigned short*)(wbase);              //   802,816 B
    unsigned short* wb3  = (unsigned short*)(wbase + 802816);     //   589,824 B
    unsigned short* wb1  = (unsigned short*)(wbase + 1392640);    //    65,536 B
    unsigned short* wbco = (unsigned short*)(wbase + 1458176);    //    16,384 B
    unsigned short* dftT = (unsigned short*)(wbase + 1474560);    //    32,768 B
    unsigned short* lruW = (unsigned short*)(wbase + 1507328);    //    32,768 B
    float* gamT          = (float*)(wbase + 1540096);             //    16,384 B
    float* lnpart        = (float*)(wbase + 1556480);             // FR*32,768 B
    unsigned short* tcb = dftT;
    unsigned short* tsb = dftT + 4096;
    unsigned short* tic = dftT + 8192;
    unsigned short* tis = dftT + 12288;
    unsigned short* wBr = lruW;
    unsigned short* wBi = lruW + 4096;
    unsigned short* wCr = lruW + 8192;
    unsigned short* wCi = lruW + 12288;

    const int NCl = 4 / LB;
    const int NCf = 64 / FR;

    k_prepdft<<<64, 256, 0, stream>>>(dftT);

    for (int i = 0; i < NBLK; ++i) {
        const float* xsrc = (i == 0) ? x_in : out;

        // ---------------- ConvLRULayer (MFMA, half-domain DFT over h) -------
        k_preplru<<<80, 256, 0, stream>>>(pBw_r + (size_t)i * 4096,
                                          pBw_i + (size_t)i * 4096,
                                          pCw_r + (size_t)i * 4096,
                                          pCw_i + (size_t)i * 4096,
                                          pl + (size_t)i * 12288 + 8192, lruW, gamT);
        for (int cc = 0; cc < NCl; ++cc) {
            size_t boff = (size_t)cc * LB * 4194304;
            k_dfthm<<<LB * 256, 256, 0, stream>>>(xsrc + boff, Xb, tcb, tsb);
            k_cmixm<<<LB * 512, 256, 0, stream>>>(Xb, Xb, wBr, wBi, gamT,
                                                  pBb_r + (size_t)i * 64,
                                                  pBb_i + (size_t)i * 64, 1);
            k_scan2<<<LB * 1024, 256, 0, stream>>>(Xb, pl + (size_t)i * 12288);
            k_cmixm<<<LB * 512, 256, 0, stream>>>(Xb, Xb, wCr, wCi, nullptr,
                                                  nullptr, nullptr, 0);
            k_idfthm_ln<<<LB * 256, 256, 0, stream>>>(Xb, tic, tis,
                                                      pCb_r + (size_t)i * 64,
                                                      lruw + (size_t)i * 4096,
                                                      lrub + (size_t)i * 4096,
                                                      xsrc + boff, out + boff);
        }

        // ---------------- FFN weight prep ----------------
        k_prep7<<<1568, 256, 0, stream>>>(cinw + (size_t)i * 401408, wb7);
        k_prep3<<<1152, 256, 0, stream>>>(h3w + (size_t)i * 2 * 147456, wb3, 2);
        k_prepcvt<<<128, 256, 0, stream>>>(h1w + (size_t)i * 2 * 16384, wb1, 32768);
        k_prepcvt<<<32, 256, 0, stream>>>(coutw + (size_t)i * 8192, wbco, 8192);

        // ---------------- FeedForward (FR-frame chunks) ----------------
        for (int cc = 0; cc < NCf; ++cc) {
            float* xb = out + (size_t)cc * FR * 262144;
            k_t2p<<<FR * 64, 256, 0, stream>>>(xb, xT);
            k_conv7m<<<FR * 16, 512, 0, stream>>>(xT, wb7, cinb + (size_t)i * 128, ybuf);
            for (int j = 0; j < NHEAD; ++j) {
                k_conv3f<<<FR * 16, 512, 0, stream>>>(ybuf, wb3 + (size_t)j * 147456,
                                                      h3b + (size_t)(i * 2 + j) * 128,
                                                      wb1 + (size_t)j * 16384,
                                                      h1b + (size_t)(i * 2 + j) * 128,
                                                      t2bf, lnpart);
                k_lnapply2<<<FR * 32, 256, 0, stream>>>(t2bf, lnpart,
                                                        hlnw + (size_t)(i * 2 + j) * 4096,
                                                        hlnb + (size_t)(i * 2 + j) * 4096,
                                                        ybuf);
            }
            k_coutm<<<FR * 32, 256, 0, stream>>>(ybuf, wbco, coutb + (size_t)i * 64, cobuf);
            k_ln_res<<<FR * 64, 256, 0, stream>>>(cobuf, flnw + (size_t)i * 4096,
                                                  flnb + (size_t)i * 4096, xb);
        }
    }
}